// Round 4
// baseline (1020.285 us; speedup 1.0000x reference)
//
#include <hip/hip_runtime.h>

typedef __attribute__((ext_vector_type(8))) __bf16 bf16x8;
typedef __attribute__((ext_vector_type(4))) float floatx4;

#define NN 16384
#define EPS 1e-5f

__device__ __forceinline__ unsigned short f2b(float f) {
  unsigned u = __float_as_uint(f);
  u += 0x7fffu + ((u >> 16) & 1u);
  return (unsigned short)(u >> 16);
}
__device__ __forceinline__ float b2f(unsigned short u) {
  return __uint_as_float(((unsigned)u) << 16);
}

// kept for harness symbol expectations; never launched
__global__ void RoboNodeEncoder_88424786690347_kernel() {}

// ---------------------------------------------------------------- zero init
__global__ __launch_bounds__(256) void zero_u32(unsigned* __restrict__ p, int n) {
  int i = blockIdx.x * blockDim.x + threadIdx.x;
  if (i < n) p[i] = 0u;
}

// -------------------------------------------------------- f32 -> bf16 copy
__global__ __launch_bounds__(256) void convert_f32_b16(const float* __restrict__ in,
                                                       unsigned short* __restrict__ out, int n) {
  int i = blockIdx.x * blockDim.x + threadIdx.x;
  if (i < n) out[i] = f2b(in[i]);
}

// --------------------------------------------------- f32 -> bf16 transpose
__global__ __launch_bounds__(256) void transpose_f32_b16(const float* __restrict__ in,
                                                         unsigned short* __restrict__ out,
                                                         int R, int C) {
  __shared__ float t[32][33];
  int bx = blockIdx.x * 32, by = blockIdx.y * 32;
  int x = threadIdx.x, y = threadIdx.y;
#pragma unroll
  for (int i = 0; i < 32; i += 8) t[y + i][x] = in[(size_t)(by + y + i) * C + bx + x];
  __syncthreads();
#pragma unroll
  for (int i = 0; i < 32; i += 8) out[(size_t)(bx + y + i) * R + by + x] = f2b(t[x][y + i]);
}

// ------------------- prep: fold LN of the point MLP into closed-form consts
// h = x@w1+b1 is affine in (x0,x1,x2,1) => LN mean/var are linear/quadratic
// forms. G[a][k] = (w1[a][k]-mean_k) * g1[k]  (a=3 is b1 column);
// Mq[0..3] = diag cov, Mq[4..9] = 2*off-diag cov of centered columns.
__global__ void prep_pointnet(const float* __restrict__ w1, const float* __restrict__ b1,
                              const float* __restrict__ g1,
                              float* __restrict__ G, float* __restrict__ Mq) {
  int k = threadIdx.x;  // 64 threads
  float c[4] = {w1[k], w1[64 + k], w1[128 + k], b1[k]};
#pragma unroll
  for (int a = 0; a < 4; a++) {
    float s = c[a];
#pragma unroll
    for (int off = 32; off > 0; off >>= 1) s += __shfl_xor(s, off, 64);
    c[a] -= s * (1.f / 64.f);
  }
  float g = g1[k];
#pragma unroll
  for (int a = 0; a < 4; a++) G[a * 64 + k] = c[a] * g;
  const int AA[10] = {0, 1, 2, 3, 0, 0, 0, 1, 1, 2};
  const int BB[10] = {0, 1, 2, 3, 1, 2, 3, 2, 3, 3};
#pragma unroll
  for (int t = 0; t < 10; t++) {
    float s = c[AA[t]] * c[BB[t]];
#pragma unroll
    for (int off = 32; off > 0; off >>= 1) s += __shfl_xor(s, off, 64);
    s *= (1.f / 64.f);
    if (t >= 4) s *= 2.f;
    if (k == 0) Mq[t] = s;
  }
}

// --------------------- point branch: folded-LN MLP + MFMA 64x64 + scatter-max
// lane = point: hn[k] via G/Mq (no shuffles); pack bf16 -> wave-private LDS
// [64pts][72] tile; 32x mfma_16x16x32_bf16 per 64 points (B-frags = w2^T in
// regs); epilogue: +b2, ordered-u32 encode, load-test, atomicMax on win.
__global__ __launch_bounds__(256) void point_mlp_mfma(
    const float* __restrict__ x, const int* __restrict__ idx, int P,
    const float* __restrict__ G, const float* __restrict__ Mq,
    const float* __restrict__ be1, const float* __restrict__ w2,
    const float* __restrict__ b2, unsigned* __restrict__ xgU) {
  __shared__ __align__(16) unsigned short w2t[64 * 64];   // 8 KB, block-shared
  __shared__ __align__(16) unsigned short hs[4][64 * 72]; // 9 KB / wave
  __shared__ int idxs[4][64];
  int tid = threadIdx.x;
  int lane = tid & 63, w = tid >> 6;
  int lr = lane & 15, quad = lane >> 4;

  // stage w2^T as bf16: w2t[n][k] = w2[k*64+n]
  for (int e = tid; e < 4096; e += 256) {
    int n = e >> 6, k = e & 63;
    w2t[n * 64 + k] = f2b(w2[k * 64 + n]);
  }
  __syncthreads();

  bf16x8 bfr[4][2];
#pragma unroll
  for (int j = 0; j < 4; j++)
#pragma unroll
    for (int s = 0; s < 2; s++)
      bfr[j][s] = *reinterpret_cast<const bf16x8*>(&w2t[(j * 16 + lr) * 64 + s * 32 + quad * 8]);
  float b2v[4];
#pragma unroll
  for (int j = 0; j < 4; j++) b2v[j] = b2[j * 16 + lr];

  float M00 = Mq[0], M11 = Mq[1], M22 = Mq[2], M33 = Mq[3];
  float T01 = Mq[4], T02 = Mq[5], T03 = Mq[6], T12 = Mq[7], T13 = Mq[8], T23 = Mq[9];

  unsigned short* hrow = &hs[w][0];
  int gw = blockIdx.x * 4 + w;
  int nw = gridDim.x * 4;
  for (int pb = gw * 64; pb < P; pb += nw * 64) {
    int p = pb + lane;
    if (p >= P) p = P - 1;  // duplicate tail point: harmless under max
    float x0 = x[3 * p], x1 = x[3 * p + 1], x2 = x[3 * p + 2];
    idxs[w][lane] = idx[p];
    float var = M33 + x0 * fmaf(M00, x0, fmaf(T01, x1, fmaf(T02, x2, T03)))
                    + x1 * fmaf(M11, x1, fmaf(T12, x2, T13))
                    + x2 * fmaf(M22, x2, T23);
    float rstd = rsqrtf(var + EPS);
    uint4 stg;
#pragma unroll
    for (int k = 0; k < 64; k += 2) {
      float s0 = fmaf(x0, G[k],     fmaf(x1, G[64 + k],     fmaf(x2, G[128 + k],     G[192 + k])));
      float s1 = fmaf(x0, G[k + 1], fmaf(x1, G[64 + k + 1], fmaf(x2, G[128 + k + 1], G[192 + k + 1])));
      float y0 = fmaxf(fmaf(s0, rstd, be1[k]), 0.f);
      float y1 = fmaxf(fmaf(s1, rstd, be1[k + 1]), 0.f);
      unsigned pk = (unsigned)f2b(y0) | ((unsigned)f2b(y1) << 16);
      int ph = (k >> 1) & 3;
      if (ph == 0) stg.x = pk;
      else if (ph == 1) stg.y = pk;
      else if (ph == 2) stg.z = pk;
      else {
        stg.w = pk;
        *reinterpret_cast<uint4*>(&hrow[lane * 72 + (k & ~7)]) = stg;  // 144B row stride: 16B-aligned
      }
    }
    asm volatile("s_waitcnt lgkmcnt(0)" ::: "memory");
    floatx4 acc[4][4] = {};
#pragma unroll
    for (int i = 0; i < 4; i++) {
      bf16x8 a0 = *reinterpret_cast<const bf16x8*>(&hrow[(i * 16 + lr) * 72 + quad * 8]);
      bf16x8 a1 = *reinterpret_cast<const bf16x8*>(&hrow[(i * 16 + lr) * 72 + 32 + quad * 8]);
#pragma unroll
      for (int j = 0; j < 4; j++) {
        acc[i][j] = __builtin_amdgcn_mfma_f32_16x16x32_bf16(a0, bfr[j][0], acc[i][j], 0, 0, 0);
        acc[i][j] = __builtin_amdgcn_mfma_f32_16x16x32_bf16(a1, bfr[j][1], acc[i][j], 0, 0, 0);
      }
    }
#pragma unroll
    for (int i = 0; i < 4; i++) {
      int nd[4];
#pragma unroll
      for (int r = 0; r < 4; r++) nd[r] = idxs[w][i * 16 + quad * 4 + r];
#pragma unroll
      for (int j = 0; j < 4; j++) {
#pragma unroll
        for (int r = 0; r < 4; r++) {
          float val = acc[i][j][r] + b2v[j];
          unsigned u = __float_as_uint(val);
          unsigned ord = (u & 0x80000000u) ? ~u : (u | 0x80000000u);
          unsigned* slot = &xgU[(size_t)nd[r] * 64 + j * 16 + lr];
          unsigned cur = *(volatile unsigned*)slot;  // stale-smaller is benign
          if (ord > cur) atomicMax(slot, ord);
        }
      }
    }
  }
}

// ------------------------------------------------------- decode max -> bf16
__global__ __launch_bounds__(256) void finalize_xg(const unsigned* __restrict__ xgU,
                                                   unsigned short* __restrict__ xgB, int n) {
  int i = blockIdx.x * blockDim.x + threadIdx.x;
  if (i >= n) return;
  unsigned u = xgU[i];
  float f;
  if (u == 0u) f = 0.0f;  // empty segment
  else if (u & 0x80000000u) f = __uint_as_float(u ^ 0x80000000u);
  else f = __uint_as_float(~u);
  xgB[i] = f2b(f);
}

// ------------------------------------------------------------- MFMA GEMM
// C[m, colOff+n] = bf16( sum_k A[m,k]*BT[n,k] + bias[n] ), bias (f32) nullable.
__global__ __launch_bounds__(256) void gemm_bt(
    const unsigned short* __restrict__ A, int lda,
    const unsigned short* __restrict__ BT, int ldb,
    const float* __restrict__ bias,
    unsigned short* __restrict__ C, int ldc, int colOff, int K) {
  __shared__ __align__(16) unsigned short As[128 * 32];
  __shared__ __align__(16) unsigned short Bs[128 * 32];
  int tid = threadIdx.x;
  int m0 = blockIdx.y * 128, n0 = blockIdx.x * 128;
  int lane = tid & 63, w = tid >> 6;
  int wm = (w >> 1) * 64, wn = (w & 1) * 64;
  int lr = lane & 15, quad = lane >> 4;
  floatx4 acc[4][4] = {};

  for (int k0 = 0; k0 < K; k0 += 32) {
    __syncthreads();
#pragma unroll
    for (int s = 0; s < 2; s++) {
      int cc = tid + s * 256;
      int row = cc >> 2, kc = (cc & 3) << 3;
      *reinterpret_cast<uint4*>(&As[row * 32 + kc]) =
          *reinterpret_cast<const uint4*>(&A[(size_t)(m0 + row) * lda + k0 + kc]);
      *reinterpret_cast<uint4*>(&Bs[row * 32 + kc]) =
          *reinterpret_cast<const uint4*>(&BT[(size_t)(n0 + row) * ldb + k0 + kc]);
    }
    __syncthreads();
    bf16x8 a[4], b[4];
#pragma unroll
    for (int i = 0; i < 4; i++)
      a[i] = *reinterpret_cast<const bf16x8*>(&As[(wm + i * 16 + lr) * 32 + quad * 8]);
#pragma unroll
    for (int j = 0; j < 4; j++)
      b[j] = *reinterpret_cast<const bf16x8*>(&Bs[(wn + j * 16 + lr) * 32 + quad * 8]);
#pragma unroll
    for (int i = 0; i < 4; i++)
#pragma unroll
      for (int j = 0; j < 4; j++)
        acc[i][j] = __builtin_amdgcn_mfma_f32_16x16x32_bf16(a[i], b[j], acc[i][j], 0, 0, 0);
  }
#pragma unroll
  for (int j = 0; j < 4; j++) {
    int gcol = n0 + wn + j * 16 + lr;
    float bv = bias ? bias[gcol] : 0.0f;
#pragma unroll
    for (int i = 0; i < 4; i++) {
#pragma unroll
      for (int r = 0; r < 4; r++) {
        int grow = m0 + wm + i * 16 + quad * 4 + r;
        C[(size_t)grow * ldc + colOff + gcol] = f2b(acc[i][j][r] + bv);
      }
    }
  }
}

// ----------------------- fused final GEMM: virtual K=2048 over 3 A sources
__global__ __launch_bounds__(256) void gemm_fuse3(
    const unsigned short* __restrict__ A0, const unsigned short* __restrict__ A1,
    const float* __restrict__ A2f, const unsigned short* __restrict__ BT,
    const float* __restrict__ bias, unsigned short* __restrict__ C) {
  __shared__ __align__(16) unsigned short As[128 * 32];
  __shared__ __align__(16) unsigned short Bs[128 * 32];
  int tid = threadIdx.x;
  int m0 = blockIdx.y * 128, n0 = blockIdx.x * 128;
  int lane = tid & 63, w = tid >> 6;
  int wm = (w >> 1) * 64, wn = (w & 1) * 64;
  int lr = lane & 15, quad = lane >> 4;
  floatx4 acc[4][4] = {};

  for (int k0 = 0; k0 < 2048; k0 += 32) {
    __syncthreads();
    if (k0 < 1536) {
      const unsigned short* Ap = (k0 < 768) ? A0 : A1;
      int kk = (k0 < 768) ? k0 : (k0 - 768);
#pragma unroll
      for (int s = 0; s < 2; s++) {
        int cc = tid + s * 256;
        int row = cc >> 2, kc = (cc & 3) << 3;
        *reinterpret_cast<uint4*>(&As[row * 32 + kc]) =
            *reinterpret_cast<const uint4*>(&Ap[(size_t)(m0 + row) * 768 + kk + kc]);
      }
    } else {
      int kk = k0 - 1536;
#pragma unroll
      for (int s = 0; s < 2; s++) {
        int cc = tid + s * 256;
        int row = cc >> 2, kc = (cc & 3) << 3;
        const float* src = &A2f[(size_t)(m0 + row) * 512 + kk + kc];
        float4 fa = *reinterpret_cast<const float4*>(src);
        float4 fb = *reinterpret_cast<const float4*>(src + 4);
        uint4 pk;
        pk.x = (unsigned)f2b(fa.x) | ((unsigned)f2b(fa.y) << 16);
        pk.y = (unsigned)f2b(fa.z) | ((unsigned)f2b(fa.w) << 16);
        pk.z = (unsigned)f2b(fb.x) | ((unsigned)f2b(fb.y) << 16);
        pk.w = (unsigned)f2b(fb.z) | ((unsigned)f2b(fb.w) << 16);
        *reinterpret_cast<uint4*>(&As[row * 32 + kc]) = pk;
      }
    }
#pragma unroll
    for (int s = 0; s < 2; s++) {
      int cc = tid + s * 256;
      int row = cc >> 2, kc = (cc & 3) << 3;
      *reinterpret_cast<uint4*>(&Bs[row * 32 + kc]) =
          *reinterpret_cast<const uint4*>(&BT[(size_t)(n0 + row) * 2048 + k0 + kc]);
    }
    __syncthreads();
    bf16x8 a[4], b[4];
#pragma unroll
    for (int i = 0; i < 4; i++)
      a[i] = *reinterpret_cast<const bf16x8*>(&As[(wm + i * 16 + lr) * 32 + quad * 8]);
#pragma unroll
    for (int j = 0; j < 4; j++)
      b[j] = *reinterpret_cast<const bf16x8*>(&Bs[(wn + j * 16 + lr) * 32 + quad * 8]);
#pragma unroll
    for (int i = 0; i < 4; i++)
#pragma unroll
      for (int j = 0; j < 4; j++)
        acc[i][j] = __builtin_amdgcn_mfma_f32_16x16x32_bf16(a[i], b[j], acc[i][j], 0, 0, 0);
  }
#pragma unroll
  for (int j = 0; j < 4; j++) {
    int gcol = n0 + wn + j * 16 + lr;
    float bv = bias[gcol];
#pragma unroll
    for (int i = 0; i < 4; i++) {
#pragma unroll
      for (int r = 0; r < 4; r++) {
        int grow = m0 + wm + i * 16 + quad * 4 + r;
        C[(size_t)grow * 768 + gcol] = f2b(acc[i][j][r] + bv);
      }
    }
  }
}

// ------------- fold all upstream biases into the fusion bias (f32 in/out)
__global__ __launch_bounds__(256) void fuse_bias(
    const float* __restrict__ fus_b, const float* __restrict__ fus_w,
    const float* __restrict__ pb4, const float* __restrict__ ab4,
    const float* __restrict__ semb, float* __restrict__ bias_tot) {
  int c = blockIdx.x;  // 768
  int tid = threadIdx.x;
  float s = 0.f;
  for (int j = tid; j < 768; j += 256) {
    s = fmaf(pb4[j],  fus_w[(size_t)j * 768 + c], s);
    s = fmaf(ab4[j],  fus_w[(size_t)(768 + j) * 768 + c], s);
    s = fmaf(semb[j], fus_w[(size_t)(1536 + j) * 768 + c], s);
  }
#pragma unroll
  for (int off = 32; off > 0; off >>= 1) s += __shfl_xor(s, off, 64);
  __shared__ float sm[4];
  if ((tid & 63) == 0) sm[tid >> 6] = s;
  __syncthreads();
  if (tid == 0) bias_tot[c] = sm[0] + sm[1] + sm[2] + sm[3] + fus_b[c];
}

// ------------------------------------- rowwise LN(768)+ReLU, bf16 in/bf16 out
__global__ __launch_bounds__(256) void ln_relu_768_b16(
    const unsigned short* __restrict__ X, const float* __restrict__ g,
    const float* __restrict__ be, unsigned short* __restrict__ Y) {
  int row = blockIdx.x, tid = threadIdx.x;
  size_t base = (size_t)row * 768;
  float xv[3];
#pragma unroll
  for (int i = 0; i < 3; i++) xv[i] = b2f(X[base + tid + i * 256]);
  float s = xv[0] + xv[1] + xv[2];
  float q = xv[0] * xv[0] + xv[1] * xv[1] + xv[2] * xv[2];
#pragma unroll
  for (int off = 32; off > 0; off >>= 1) {
    s += __shfl_xor(s, off, 64);
    q += __shfl_xor(q, off, 64);
  }
  __shared__ float ss[4], qq[4];
  int w = tid >> 6, lane = tid & 63;
  if (lane == 0) { ss[w] = s; qq[w] = q; }
  __syncthreads();
  s = ss[0] + ss[1] + ss[2] + ss[3];
  q = qq[0] + qq[1] + qq[2] + qq[3];
  float m = s * (1.0f / 768.0f);
  float v = fmaf(-m, m, q * (1.0f / 768.0f));
  float rstd = rsqrtf(v + EPS);
#pragma unroll
  for (int i = 0; i < 3; i++) {
    int c = tid + i * 256;
    float y = (xv[i] - m) * rstd * g[c] + be[c];
    Y[base + c] = f2b(fmaxf(y, 0.0f));
  }
}

// ------------------------------------- rowwise LN(768)+ReLU, bf16 in/f32 out
__global__ __launch_bounds__(256) void ln_relu_768_f32(
    const unsigned short* __restrict__ X, const float* __restrict__ g,
    const float* __restrict__ be, float* __restrict__ Y) {
  int row = blockIdx.x, tid = threadIdx.x;
  size_t base = (size_t)row * 768;
  float xv[3];
#pragma unroll
  for (int i = 0; i < 3; i++) xv[i] = b2f(X[base + tid + i * 256]);
  float s = xv[0] + xv[1] + xv[2];
  float q = xv[0] * xv[0] + xv[1] * xv[1] + xv[2] * xv[2];
#pragma unroll
  for (int off = 32; off > 0; off >>= 1) {
    s += __shfl_xor(s, off, 64);
    q += __shfl_xor(q, off, 64);
  }
  __shared__ float ss[4], qq[4];
  int w = tid >> 6, lane = tid & 63;
  if (lane == 0) { ss[w] = s; qq[w] = q; }
  __syncthreads();
  s = ss[0] + ss[1] + ss[2] + ss[3];
  q = qq[0] + qq[1] + qq[2] + qq[3];
  float m = s * (1.0f / 768.0f);
  float v = fmaf(-m, m, q * (1.0f / 768.0f));
  float rstd = rsqrtf(v + EPS);
#pragma unroll
  for (int i = 0; i < 3; i++) {
    int c = tid + i * 256;
    float y = (xv[i] - m) * rstd * g[c] + be[c];
    Y[base + c] = fmaxf(y, 0.0f);
  }
}

extern "C" void kernel_launch(void* const* d_in, const int* in_sizes, int n_in,
                              void* d_out, int out_size, void* d_ws, size_t ws_size,
                              hipStream_t stream) {
  typedef const float* cf;
  cf x_pos = (cf)d_in[0];
  const int* pos_idx = (const int*)d_in[1];
  cf x_aff = (cf)d_in[2];
  const int* aff_idx = (const int*)d_in[3];
  cf x_sem = (cf)d_in[4];
  cf pw1 = (cf)d_in[6],  pb1 = (cf)d_in[7],  pg1 = (cf)d_in[8],  pbe1 = (cf)d_in[9];
  cf pw2 = (cf)d_in[10], pb2 = (cf)d_in[11];
  cf pw3 = (cf)d_in[12], pb3 = (cf)d_in[13], pg2 = (cf)d_in[14], pbe2 = (cf)d_in[15];
  cf pw4 = (cf)d_in[16], pb4 = (cf)d_in[17];
  cf aw1 = (cf)d_in[18], ab1 = (cf)d_in[19], ag1 = (cf)d_in[20], abe1 = (cf)d_in[21];
  cf aw2 = (cf)d_in[22], ab2 = (cf)d_in[23];
  cf aw3 = (cf)d_in[24], ab3 = (cf)d_in[25], ag2 = (cf)d_in[26], abe2 = (cf)d_in[27];
  cf aw4 = (cf)d_in[28], ab4 = (cf)d_in[29];
  cf semw = (cf)d_in[30], semb = (cf)d_in[31];
  cf fusw = (cf)d_in[32], fusb = (cf)d_in[33], fusg = (cf)d_in[34], fusbe = (cf)d_in[35];

  int P = in_sizes[0] / 3;

  char* wsb = (char*)d_ws;
  size_t off = 0;
  auto carve = [&](size_t bytes) -> void* {
    void* p = wsb + off;
    off = (off + bytes + 255) & ~(size_t)255;
    return p;
  };
  unsigned* xgU = (unsigned*)carve((size_t)2 * NN * 64 * 4);
  unsigned* xgU_pos = xgU;
  unsigned* xgU_aff = xgU + (size_t)NN * 64;
  unsigned short* xgB = (unsigned short*)carve((size_t)2 * NN * 64 * 2);
  unsigned short* xgB_pos = xgB;
  unsigned short* xgB_aff = xgB + (size_t)NN * 64;
  unsigned short* t_pos = (unsigned short*)carve((size_t)NN * 768 * 2);
  unsigned short* t_aff = (unsigned short*)carve((size_t)NN * 768 * 2);
  unsigned short* F     = (unsigned short*)carve((size_t)NN * 768 * 2);
  unsigned short* w3T_pos = (unsigned short*)carve((size_t)768 * 64 * 2);
  unsigned short* w3T_aff = (unsigned short*)carve((size_t)768 * 64 * 2);
  unsigned short* fusT  = (unsigned short*)carve((size_t)768 * 2304 * 2);
  unsigned short* pw4B  = (unsigned short*)carve((size_t)768 * 768 * 2);
  unsigned short* aw4B  = (unsigned short*)carve((size_t)768 * 768 * 2);
  unsigned short* semwB = (unsigned short*)carve((size_t)512 * 768 * 2);
  unsigned short* BTcat = (unsigned short*)carve((size_t)768 * 2048 * 2);
  float* bias_tot = (float*)carve((size_t)768 * 4);
  float* G_pos = (float*)carve((size_t)256 * 4);
  float* M_pos = (float*)carve((size_t)16 * 4);
  float* G_aff = (float*)carve((size_t)256 * 4);
  float* M_aff = (float*)carve((size_t)16 * 4);

  int nz = 2 * NN * 64;
  zero_u32<<<(nz + 255) / 256, 256, 0, stream>>>(xgU, nz);

  // weight prep
  dim3 tb(32, 8);
  transpose_f32_b16<<<dim3(24, 2),  tb, 0, stream>>>(pw3, w3T_pos, 64, 768);
  transpose_f32_b16<<<dim3(24, 2),  tb, 0, stream>>>(aw3, w3T_aff, 64, 768);
  transpose_f32_b16<<<dim3(24, 72), tb, 0, stream>>>(fusw, fusT, 2304, 768);
  convert_f32_b16<<<(768 * 768 + 255) / 256, 256, 0, stream>>>(pw4, pw4B, 768 * 768);
  convert_f32_b16<<<(768 * 768 + 255) / 256, 256, 0, stream>>>(aw4, aw4B, 768 * 768);
  convert_f32_b16<<<(512 * 768 + 255) / 256, 256, 0, stream>>>(semw, semwB, 512 * 768);
  prep_pointnet<<<1, 64, 0, stream>>>(pw1, pb1, pg1, G_pos, M_pos);
  prep_pointnet<<<1, 64, 0, stream>>>(aw1, ab1, ag1, G_aff, M_aff);

  // weight folds into BTcat
  gemm_bt<<<dim3(6, 6), 256, 0, stream>>>(fusT,        2304, pw4B,  768, nullptr, BTcat, 2048, 0,    768);
  gemm_bt<<<dim3(6, 6), 256, 0, stream>>>(fusT + 768,  2304, aw4B,  768, nullptr, BTcat, 2048, 768,  768);
  gemm_bt<<<dim3(4, 6), 256, 0, stream>>>(fusT + 1536, 2304, semwB, 768, nullptr, BTcat, 2048, 1536, 768);
  fuse_bias<<<768, 256, 0, stream>>>(fusb, fusw, pb4, ab4, semb, bias_tot);

  // point branches (MFMA-ized)
  point_mlp_mfma<<<2048, 256, 0, stream>>>(x_pos, pos_idx, P, G_pos, M_pos, pbe1, pw2, pb2, xgU_pos);
  point_mlp_mfma<<<2048, 256, 0, stream>>>(x_aff, aff_idx, P, G_aff, M_aff, abe1, aw2, ab2, xgU_aff);
  finalize_xg<<<(nz + 255) / 256, 256, 0, stream>>>(xgU, xgB, nz);

  // mlp2 first linear + LN + ReLU
  gemm_bt<<<dim3(6, NN / 128), 256, 0, stream>>>(xgB_pos, 64, w3T_pos, 64, pb3, t_pos, 768, 0, 64);
  gemm_bt<<<dim3(6, NN / 128), 256, 0, stream>>>(xgB_aff, 64, w3T_aff, 64, ab3, t_aff, 768, 0, 64);
  ln_relu_768_b16<<<NN, 256, 0, stream>>>(t_pos, pg2, pbe2, t_pos);
  ln_relu_768_b16<<<NN, 256, 0, stream>>>(t_aff, ag2, abe2, t_aff);

  // fused final GEMM + LN -> f32 out
  gemm_fuse3<<<dim3(6, NN / 128), 256, 0, stream>>>(t_pos, t_aff, x_sem, BTcat, bias_tot, F);
  ln_relu_768_f32<<<NN, 256, 0, stream>>>(F, fusg, fusbe, (float*)d_out);
}

// Round 5
// 857.493 us; speedup vs baseline: 1.1898x; 1.1898x over previous
//
#include <hip/hip_runtime.h>

typedef __attribute__((ext_vector_type(8))) __bf16 bf16x8;
typedef __attribute__((ext_vector_type(4))) float floatx4;

#define NN 16384
#define EPS 1e-5f
#define NEG_HUGE -3.402823466e38f

__device__ __forceinline__ unsigned short f2b(float f) {
  unsigned u = __float_as_uint(f);
  u += 0x7fffu + ((u >> 16) & 1u);
  return (unsigned short)(u >> 16);
}
__device__ __forceinline__ float b2f(unsigned short u) {
  return __uint_as_float(((unsigned)u) << 16);
}

// kept for harness symbol expectations; never launched
__global__ void RoboNodeEncoder_88424786690347_kernel() {}

// ---------------------------------------------------------------- zero init
__global__ __launch_bounds__(256) void zero_u32(unsigned* __restrict__ p, int n) {
  int i = blockIdx.x * blockDim.x + threadIdx.x;
  if (i < n) p[i] = 0u;
}

// -------------------------------------------------------- f32 -> bf16 copy
__global__ __launch_bounds__(256) void convert_f32_b16(const float* __restrict__ in,
                                                       unsigned short* __restrict__ out, int n) {
  int i = blockIdx.x * blockDim.x + threadIdx.x;
  if (i < n) out[i] = f2b(in[i]);
}

// --------------------------------------------------- f32 -> bf16 transpose
__global__ __launch_bounds__(256) void transpose_f32_b16(const float* __restrict__ in,
                                                         unsigned short* __restrict__ out,
                                                         int R, int C) {
  __shared__ float t[32][33];
  int bx = blockIdx.x * 32, by = blockIdx.y * 32;
  int x = threadIdx.x, y = threadIdx.y;
#pragma unroll
  for (int i = 0; i < 32; i += 8) t[y + i][x] = in[(size_t)(by + y + i) * C + bx + x];
  __syncthreads();
#pragma unroll
  for (int i = 0; i < 32; i += 8) out[(size_t)(bx + y + i) * R + by + x] = f2b(t[x][y + i]);
}

// ------------------- prep: fold LN of the point MLP into closed-form consts
__global__ void prep_pointnet(const float* __restrict__ w1, const float* __restrict__ b1,
                              const float* __restrict__ g1,
                              float* __restrict__ G, float* __restrict__ Mq) {
  int k = threadIdx.x;  // 64 threads
  float c[4] = {w1[k], w1[64 + k], w1[128 + k], b1[k]};
#pragma unroll
  for (int a = 0; a < 4; a++) {
    float s = c[a];
#pragma unroll
    for (int off = 32; off > 0; off >>= 1) s += __shfl_xor(s, off, 64);
    c[a] -= s * (1.f / 64.f);
  }
  float g = g1[k];
#pragma unroll
  for (int a = 0; a < 4; a++) G[a * 64 + k] = c[a] * g;
  const int AA[10] = {0, 1, 2, 3, 0, 0, 0, 1, 1, 2};
  const int BB[10] = {0, 1, 2, 3, 1, 2, 3, 2, 3, 3};
#pragma unroll
  for (int t = 0; t < 10; t++) {
    float s = c[AA[t]] * c[BB[t]];
#pragma unroll
    for (int off = 32; off > 0; off >>= 1) s += __shfl_xor(s, off, 64);
    s *= (1.f / 64.f);
    if (t >= 4) s *= 2.f;
    if (k == 0) Mq[t] = s;
  }
}

// ------------------------------------------------------------- histogram
__global__ __launch_bounds__(256) void hist_idx(const int* __restrict__ idx, int P,
                                                unsigned* __restrict__ cnt) {
  int stride = gridDim.x * blockDim.x;
  for (int i = blockIdx.x * blockDim.x + threadIdx.x; i < P; i += stride)
    atomicAdd(&cnt[idx[i]], 1u);
}

// ---------------------- exclusive scan of 16384 counters (one block, 1024 thr)
__global__ __launch_bounds__(1024) void scan16k(const unsigned* __restrict__ cnt,
                                                unsigned* __restrict__ offs,
                                                unsigned* __restrict__ cursor) {
  __shared__ unsigned ps[1024];
  int t = threadIdx.x;
  unsigned v[16];
  unsigned s = 0;
#pragma unroll
  for (int i = 0; i < 16; i++) { v[i] = cnt[t * 16 + i]; s += v[i]; }
  ps[t] = s;
  __syncthreads();
  for (int off = 1; off < 1024; off <<= 1) {
    unsigned add = (t >= off) ? ps[t - off] : 0u;
    __syncthreads();
    ps[t] += add;
    __syncthreads();
  }
  unsigned base = (t > 0) ? ps[t - 1] : 0u;
#pragma unroll
  for (int i = 0; i < 16; i++) {
    offs[t * 16 + i] = base;
    cursor[t * 16 + i] = base;
    base += v[i];
  }
  if (t == 1023) offs[16384] = base;
}

// ------------------------------------------- scatter points into node order
__global__ __launch_bounds__(256) void scatter_points(const float* __restrict__ x,
                                                      const int* __restrict__ idx, int P,
                                                      unsigned* __restrict__ cursor,
                                                      float4* __restrict__ sorted) {
  int stride = gridDim.x * blockDim.x;
  for (int i = blockIdx.x * blockDim.x + threadIdx.x; i < P; i += stride) {
    int nd = idx[i];
    unsigned pos = atomicAdd(&cursor[nd], 1u);
    float4 v;
    v.x = x[3 * i]; v.y = x[3 * i + 1]; v.z = x[3 * i + 2]; v.w = 0.f;
    sorted[pos] = v;
  }
}

// ----------------- per-node: folded-LN MLP + MFMA 64x64 + in-register max
// wave per node; reads the node's sorted points densely; one coalesced
// 64x bf16 write per node, zero atomics.
__global__ __launch_bounds__(256) void node_mlp_max(
    const float4* __restrict__ sorted, const unsigned* __restrict__ offs,
    const float* __restrict__ G, const float* __restrict__ Mq,
    const float* __restrict__ be1, const float* __restrict__ w2,
    const float* __restrict__ b2, unsigned short* __restrict__ xgB) {
  __shared__ __align__(16) unsigned short w2t[64 * 64];   // 8 KB
  __shared__ __align__(16) unsigned short hs[4][64 * 72]; // 9 KB / wave
  int tid = threadIdx.x;
  int lane = tid & 63, w = tid >> 6;
  int lr = lane & 15, quad = lane >> 4;

  for (int e = tid; e < 4096; e += 256) {
    int n = e >> 6, k = e & 63;
    w2t[n * 64 + k] = f2b(w2[k * 64 + n]);
  }
  __syncthreads();

  bf16x8 bfr[4][2];
#pragma unroll
  for (int j = 0; j < 4; j++)
#pragma unroll
    for (int s = 0; s < 2; s++)
      bfr[j][s] = *reinterpret_cast<const bf16x8*>(&w2t[(j * 16 + lr) * 64 + s * 32 + quad * 8]);

  float M00 = Mq[0], M11 = Mq[1], M22 = Mq[2], M33 = Mq[3];
  float T01 = Mq[4], T02 = Mq[5], T03 = Mq[6], T12 = Mq[7], T13 = Mq[8], T23 = Mq[9];

  unsigned short* hrow = &hs[w][0];
  int gw = blockIdx.x * 4 + w;
  int nwv = gridDim.x * 4;
  for (int node = gw; node < NN; node += nwv) {
    unsigned seg0 = offs[node], seg1 = offs[node + 1];
    int cnt = (int)(seg1 - seg0);
    if (cnt == 0) { xgB[(size_t)node * 64 + lane] = 0; continue; }

    float lmax[4] = {NEG_HUGE, NEG_HUGE, NEG_HUGE, NEG_HUGE};
    for (int t0 = 0; t0 < cnt; t0 += 64) {
      int rem = cnt - t0;
      int tc = rem < 64 ? rem : 64;
      int pi = t0 + lane;
      if (pi >= cnt) pi = cnt - 1;  // clamped load; masked out below
      float4 xv = sorted[seg0 + pi];
      float x0 = xv.x, x1 = xv.y, x2 = xv.z;
      float var = M33 + x0 * fmaf(M00, x0, fmaf(T01, x1, fmaf(T02, x2, T03)))
                      + x1 * fmaf(M11, x1, fmaf(T12, x2, T13))
                      + x2 * fmaf(M22, x2, T23);
      float rstd = rsqrtf(var + EPS);
      uint4 stg;
#pragma unroll
      for (int k = 0; k < 64; k += 2) {
        float s0 = fmaf(x0, G[k],     fmaf(x1, G[64 + k],     fmaf(x2, G[128 + k],     G[192 + k])));
        float s1 = fmaf(x0, G[k + 1], fmaf(x1, G[64 + k + 1], fmaf(x2, G[128 + k + 1], G[192 + k + 1])));
        float y0 = fmaxf(fmaf(s0, rstd, be1[k]), 0.f);
        float y1 = fmaxf(fmaf(s1, rstd, be1[k + 1]), 0.f);
        unsigned pk = (unsigned)f2b(y0) | ((unsigned)f2b(y1) << 16);
        int ph = (k >> 1) & 3;
        if (ph == 0) stg.x = pk;
        else if (ph == 1) stg.y = pk;
        else if (ph == 2) stg.z = pk;
        else {
          stg.w = pk;
          *reinterpret_cast<uint4*>(&hrow[lane * 72 + (k & ~7)]) = stg;
        }
      }
      asm volatile("s_waitcnt lgkmcnt(0)" ::: "memory");
      floatx4 acc[4][4] = {};
#pragma unroll
      for (int i = 0; i < 4; i++) {
        bf16x8 a0 = *reinterpret_cast<const bf16x8*>(&hrow[(i * 16 + lr) * 72 + quad * 8]);
        bf16x8 a1 = *reinterpret_cast<const bf16x8*>(&hrow[(i * 16 + lr) * 72 + 32 + quad * 8]);
#pragma unroll
        for (int j = 0; j < 4; j++) {
          acc[i][j] = __builtin_amdgcn_mfma_f32_16x16x32_bf16(a0, bfr[j][0], acc[i][j], 0, 0, 0);
          acc[i][j] = __builtin_amdgcn_mfma_f32_16x16x32_bf16(a1, bfr[j][1], acc[i][j], 0, 0, 0);
        }
      }
      // masked running max over rows (row = point-in-tile = i*16+quad*4+r)
#pragma unroll
      for (int i = 0; i < 4; i++) {
#pragma unroll
        for (int r = 0; r < 4; r++) {
          int prow = i * 16 + quad * 4 + r;
          bool ok = prow < tc;
#pragma unroll
          for (int j = 0; j < 4; j++) {
            float v = acc[i][j][r];
            lmax[j] = ok ? fmaxf(lmax[j], v) : lmax[j];
          }
        }
      }
    }
    // cross-quad reduce: lanes sharing lr hold disjoint row sets
#pragma unroll
    for (int j = 0; j < 4; j++) {
      lmax[j] = fmaxf(lmax[j], __shfl_xor(lmax[j], 16, 64));
      lmax[j] = fmaxf(lmax[j], __shfl_xor(lmax[j], 32, 64));
    }
    // col = j*16+lr; pick j = quad so col == lane; bias after max (monotone)
    float out = lmax[quad] + b2[lane];
    xgB[(size_t)node * 64 + lane] = f2b(out);
  }
}

// ------------------------------------------------------------- MFMA GEMM
// C[m, colOff+n] = bf16( sum_k A[m,k]*BT[n,k] + bias[n] ), bias (f32) nullable.
__global__ __launch_bounds__(256) void gemm_bt(
    const unsigned short* __restrict__ A, int lda,
    const unsigned short* __restrict__ BT, int ldb,
    const float* __restrict__ bias,
    unsigned short* __restrict__ C, int ldc, int colOff, int K) {
  __shared__ __align__(16) unsigned short As[128 * 32];
  __shared__ __align__(16) unsigned short Bs[128 * 32];
  int tid = threadIdx.x;
  int m0 = blockIdx.y * 128, n0 = blockIdx.x * 128;
  int lane = tid & 63, w = tid >> 6;
  int wm = (w >> 1) * 64, wn = (w & 1) * 64;
  int lr = lane & 15, quad = lane >> 4;
  floatx4 acc[4][4] = {};

  for (int k0 = 0; k0 < K; k0 += 32) {
    __syncthreads();
#pragma unroll
    for (int s = 0; s < 2; s++) {
      int cc = tid + s * 256;
      int row = cc >> 2, kc = (cc & 3) << 3;
      *reinterpret_cast<uint4*>(&As[row * 32 + kc]) =
          *reinterpret_cast<const uint4*>(&A[(size_t)(m0 + row) * lda + k0 + kc]);
      *reinterpret_cast<uint4*>(&Bs[row * 32 + kc]) =
          *reinterpret_cast<const uint4*>(&BT[(size_t)(n0 + row) * ldb + k0 + kc]);
    }
    __syncthreads();
    bf16x8 a[4], b[4];
#pragma unroll
    for (int i = 0; i < 4; i++)
      a[i] = *reinterpret_cast<const bf16x8*>(&As[(wm + i * 16 + lr) * 32 + quad * 8]);
#pragma unroll
    for (int j = 0; j < 4; j++)
      b[j] = *reinterpret_cast<const bf16x8*>(&Bs[(wn + j * 16 + lr) * 32 + quad * 8]);
#pragma unroll
    for (int i = 0; i < 4; i++)
#pragma unroll
      for (int j = 0; j < 4; j++)
        acc[i][j] = __builtin_amdgcn_mfma_f32_16x16x32_bf16(a[i], b[j], acc[i][j], 0, 0, 0);
  }
#pragma unroll
  for (int j = 0; j < 4; j++) {
    int gcol = n0 + wn + j * 16 + lr;
    float bv = bias ? bias[gcol] : 0.0f;
#pragma unroll
    for (int i = 0; i < 4; i++) {
#pragma unroll
      for (int r = 0; r < 4; r++) {
        int grow = m0 + wm + i * 16 + quad * 4 + r;
        C[(size_t)grow * ldc + colOff + gcol] = f2b(acc[i][j][r] + bv);
      }
    }
  }
}

// ----------------------- fused final GEMM: virtual K=2048 over 3 A sources
__global__ __launch_bounds__(256) void gemm_fuse3(
    const unsigned short* __restrict__ A0, const unsigned short* __restrict__ A1,
    const float* __restrict__ A2f, const unsigned short* __restrict__ BT,
    const float* __restrict__ bias, unsigned short* __restrict__ C) {
  __shared__ __align__(16) unsigned short As[128 * 32];
  __shared__ __align__(16) unsigned short Bs[128 * 32];
  int tid = threadIdx.x;
  int m0 = blockIdx.y * 128, n0 = blockIdx.x * 128;
  int lane = tid & 63, w = tid >> 6;
  int wm = (w >> 1) * 64, wn = (w & 1) * 64;
  int lr = lane & 15, quad = lane >> 4;
  floatx4 acc[4][4] = {};

  for (int k0 = 0; k0 < 2048; k0 += 32) {
    __syncthreads();
    if (k0 < 1536) {
      const unsigned short* Ap = (k0 < 768) ? A0 : A1;
      int kk = (k0 < 768) ? k0 : (k0 - 768);
#pragma unroll
      for (int s = 0; s < 2; s++) {
        int cc = tid + s * 256;
        int row = cc >> 2, kc = (cc & 3) << 3;
        *reinterpret_cast<uint4*>(&As[row * 32 + kc]) =
            *reinterpret_cast<const uint4*>(&Ap[(size_t)(m0 + row) * 768 + kk + kc]);
      }
    } else {
      int kk = k0 - 1536;
#pragma unroll
      for (int s = 0; s < 2; s++) {
        int cc = tid + s * 256;
        int row = cc >> 2, kc = (cc & 3) << 3;
        const float* src = &A2f[(size_t)(m0 + row) * 512 + kk + kc];
        float4 fa = *reinterpret_cast<const float4*>(src);
        float4 fb = *reinterpret_cast<const float4*>(src + 4);
        uint4 pk;
        pk.x = (unsigned)f2b(fa.x) | ((unsigned)f2b(fa.y) << 16);
        pk.y = (unsigned)f2b(fa.z) | ((unsigned)f2b(fa.w) << 16);
        pk.z = (unsigned)f2b(fb.x) | ((unsigned)f2b(fb.y) << 16);
        pk.w = (unsigned)f2b(fb.z) | ((unsigned)f2b(fb.w) << 16);
        *reinterpret_cast<uint4*>(&As[row * 32 + kc]) = pk;
      }
    }
#pragma unroll
    for (int s = 0; s < 2; s++) {
      int cc = tid + s * 256;
      int row = cc >> 2, kc = (cc & 3) << 3;
      *reinterpret_cast<uint4*>(&Bs[row * 32 + kc]) =
          *reinterpret_cast<const uint4*>(&BT[(size_t)(n0 + row) * 2048 + k0 + kc]);
    }
    __syncthreads();
    bf16x8 a[4], b[4];
#pragma unroll
    for (int i = 0; i < 4; i++)
      a[i] = *reinterpret_cast<const bf16x8*>(&As[(wm + i * 16 + lr) * 32 + quad * 8]);
#pragma unroll
    for (int j = 0; j < 4; j++)
      b[j] = *reinterpret_cast<const bf16x8*>(&Bs[(wn + j * 16 + lr) * 32 + quad * 8]);
#pragma unroll
    for (int i = 0; i < 4; i++)
#pragma unroll
      for (int j = 0; j < 4; j++)
        acc[i][j] = __builtin_amdgcn_mfma_f32_16x16x32_bf16(a[i], b[j], acc[i][j], 0, 0, 0);
  }
#pragma unroll
  for (int j = 0; j < 4; j++) {
    int gcol = n0 + wn + j * 16 + lr;
    float bv = bias[gcol];
#pragma unroll
    for (int i = 0; i < 4; i++) {
#pragma unroll
      for (int r = 0; r < 4; r++) {
        int grow = m0 + wm + i * 16 + quad * 4 + r;
        C[(size_t)grow * 768 + gcol] = f2b(acc[i][j][r] + bv);
      }
    }
  }
}

// ------------- fold all upstream biases into the fusion bias (f32 in/out)
__global__ __launch_bounds__(256) void fuse_bias(
    const float* __restrict__ fus_b, const float* __restrict__ fus_w,
    const float* __restrict__ pb4, const float* __restrict__ ab4,
    const float* __restrict__ semb, float* __restrict__ bias_tot) {
  int c = blockIdx.x;  // 768
  int tid = threadIdx.x;
  float s = 0.f;
  for (int j = tid; j < 768; j += 256) {
    s = fmaf(pb4[j],  fus_w[(size_t)j * 768 + c], s);
    s = fmaf(ab4[j],  fus_w[(size_t)(768 + j) * 768 + c], s);
    s = fmaf(semb[j], fus_w[(size_t)(1536 + j) * 768 + c], s);
  }
#pragma unroll
  for (int off = 32; off > 0; off >>= 1) s += __shfl_xor(s, off, 64);
  __shared__ float sm[4];
  if ((tid & 63) == 0) sm[tid >> 6] = s;
  __syncthreads();
  if (tid == 0) bias_tot[c] = sm[0] + sm[1] + sm[2] + sm[3] + fus_b[c];
}

// ------------------------------------- rowwise LN(768)+ReLU, bf16 in/bf16 out
__global__ __launch_bounds__(256) void ln_relu_768_b16(
    const unsigned short* __restrict__ X, const float* __restrict__ g,
    const float* __restrict__ be, unsigned short* __restrict__ Y) {
  int row = blockIdx.x, tid = threadIdx.x;
  size_t base = (size_t)row * 768;
  float xv[3];
#pragma unroll
  for (int i = 0; i < 3; i++) xv[i] = b2f(X[base + tid + i * 256]);
  float s = xv[0] + xv[1] + xv[2];
  float q = xv[0] * xv[0] + xv[1] * xv[1] + xv[2] * xv[2];
#pragma unroll
  for (int off = 32; off > 0; off >>= 1) {
    s += __shfl_xor(s, off, 64);
    q += __shfl_xor(q, off, 64);
  }
  __shared__ float ss[4], qq[4];
  int w = tid >> 6, lane = tid & 63;
  if (lane == 0) { ss[w] = s; qq[w] = q; }
  __syncthreads();
  s = ss[0] + ss[1] + ss[2] + ss[3];
  q = qq[0] + qq[1] + qq[2] + qq[3];
  float m = s * (1.0f / 768.0f);
  float v = fmaf(-m, m, q * (1.0f / 768.0f));
  float rstd = rsqrtf(v + EPS);
#pragma unroll
  for (int i = 0; i < 3; i++) {
    int c = tid + i * 256;
    float y = (xv[i] - m) * rstd * g[c] + be[c];
    Y[base + c] = f2b(fmaxf(y, 0.0f));
  }
}

// ------------------------------------- rowwise LN(768)+ReLU, bf16 in/f32 out
__global__ __launch_bounds__(256) void ln_relu_768_f32(
    const unsigned short* __restrict__ X, const float* __restrict__ g,
    const float* __restrict__ be, float* __restrict__ Y) {
  int row = blockIdx.x, tid = threadIdx.x;
  size_t base = (size_t)row * 768;
  float xv[3];
#pragma unroll
  for (int i = 0; i < 3; i++) xv[i] = b2f(X[base + tid + i * 256]);
  float s = xv[0] + xv[1] + xv[2];
  float q = xv[0] * xv[0] + xv[1] * xv[1] + xv[2] * xv[2];
#pragma unroll
  for (int off = 32; off > 0; off >>= 1) {
    s += __shfl_xor(s, off, 64);
    q += __shfl_xor(q, off, 64);
  }
  __shared__ float ss[4], qq[4];
  int w = tid >> 6, lane = tid & 63;
  if (lane == 0) { ss[w] = s; qq[w] = q; }
  __syncthreads();
  s = ss[0] + ss[1] + ss[2] + ss[3];
  q = qq[0] + qq[1] + qq[2] + qq[3];
  float m = s * (1.0f / 768.0f);
  float v = fmaf(-m, m, q * (1.0f / 768.0f));
  float rstd = rsqrtf(v + EPS);
#pragma unroll
  for (int i = 0; i < 3; i++) {
    int c = tid + i * 256;
    float y = (xv[i] - m) * rstd * g[c] + be[c];
    Y[base + c] = fmaxf(y, 0.0f);
  }
}

extern "C" void kernel_launch(void* const* d_in, const int* in_sizes, int n_in,
                              void* d_out, int out_size, void* d_ws, size_t ws_size,
                              hipStream_t stream) {
  typedef const float* cf;
  cf x_pos = (cf)d_in[0];
  const int* pos_idx = (const int*)d_in[1];
  cf x_aff = (cf)d_in[2];
  const int* aff_idx = (const int*)d_in[3];
  cf x_sem = (cf)d_in[4];
  cf pw1 = (cf)d_in[6],  pb1 = (cf)d_in[7],  pg1 = (cf)d_in[8],  pbe1 = (cf)d_in[9];
  cf pw2 = (cf)d_in[10], pb2 = (cf)d_in[11];
  cf pw3 = (cf)d_in[12], pb3 = (cf)d_in[13], pg2 = (cf)d_in[14], pbe2 = (cf)d_in[15];
  cf pw4 = (cf)d_in[16], pb4 = (cf)d_in[17];
  cf aw1 = (cf)d_in[18], ab1 = (cf)d_in[19], ag1 = (cf)d_in[20], abe1 = (cf)d_in[21];
  cf aw2 = (cf)d_in[22], ab2 = (cf)d_in[23];
  cf aw3 = (cf)d_in[24], ab3 = (cf)d_in[25], ag2 = (cf)d_in[26], abe2 = (cf)d_in[27];
  cf aw4 = (cf)d_in[28], ab4 = (cf)d_in[29];
  cf semw = (cf)d_in[30], semb = (cf)d_in[31];
  cf fusw = (cf)d_in[32], fusb = (cf)d_in[33], fusg = (cf)d_in[34], fusbe = (cf)d_in[35];

  int P = in_sizes[0] / 3;

  char* wsb = (char*)d_ws;
  size_t off = 0;
  auto carve = [&](size_t bytes) -> void* {
    void* p = wsb + off;
    off = (off + bytes + 255) & ~(size_t)255;
    return p;
  };
  unsigned short* xgB = (unsigned short*)carve((size_t)2 * NN * 64 * 2);  // 4 MiB
  unsigned short* xgB_pos = xgB;
  unsigned short* xgB_aff = xgB + (size_t)NN * 64;
  unsigned short* t_pos = (unsigned short*)carve((size_t)NN * 768 * 2);   // 24 MiB
  unsigned short* t_aff = (unsigned short*)carve((size_t)NN * 768 * 2);   // 24 MiB
  float4* sorted_pos = (float4*)carve((size_t)P * 16);                    // 16 MiB
  float4* sorted_aff = (float4*)carve((size_t)P * 16);                    // 16 MiB
  unsigned short* F = (unsigned short*)sorted_pos;  // alias: dead before gemm_fuse3
  unsigned short* w3T_pos = (unsigned short*)carve((size_t)768 * 64 * 2);
  unsigned short* w3T_aff = (unsigned short*)carve((size_t)768 * 64 * 2);
  unsigned short* fusT  = (unsigned short*)carve((size_t)768 * 2304 * 2);
  unsigned short* pw4B  = (unsigned short*)carve((size_t)768 * 768 * 2);
  unsigned short* aw4B  = (unsigned short*)carve((size_t)768 * 768 * 2);
  unsigned short* semwB = (unsigned short*)carve((size_t)512 * 768 * 2);
  unsigned short* BTcat = (unsigned short*)carve((size_t)768 * 2048 * 2);
  float* bias_tot = (float*)carve((size_t)768 * 4);
  float* G_pos = (float*)carve((size_t)256 * 4);
  float* M_pos = (float*)carve((size_t)16 * 4);
  float* G_aff = (float*)carve((size_t)256 * 4);
  float* M_aff = (float*)carve((size_t)16 * 4);
  unsigned* cnt_pos = (unsigned*)carve((size_t)NN * 4);
  unsigned* cnt_aff = (unsigned*)carve((size_t)NN * 4);
  unsigned* offs_pos = (unsigned*)carve((size_t)(NN + 2) * 4);
  unsigned* offs_aff = (unsigned*)carve((size_t)(NN + 2) * 4);
  unsigned* cur_pos = (unsigned*)carve((size_t)NN * 4);
  unsigned* cur_aff = (unsigned*)carve((size_t)NN * 4);
  // total ~92 MiB

  // zero both histograms (cnt_pos, cnt_aff contiguous)
  zero_u32<<<(2 * NN + 255) / 256, 256, 0, stream>>>(cnt_pos, 2 * NN);

  // weight prep
  dim3 tb(32, 8);
  transpose_f32_b16<<<dim3(24, 2),  tb, 0, stream>>>(pw3, w3T_pos, 64, 768);
  transpose_f32_b16<<<dim3(24, 2),  tb, 0, stream>>>(aw3, w3T_aff, 64, 768);
  transpose_f32_b16<<<dim3(24, 72), tb, 0, stream>>>(fusw, fusT, 2304, 768);
  convert_f32_b16<<<(768 * 768 + 255) / 256, 256, 0, stream>>>(pw4, pw4B, 768 * 768);
  convert_f32_b16<<<(768 * 768 + 255) / 256, 256, 0, stream>>>(aw4, aw4B, 768 * 768);
  convert_f32_b16<<<(512 * 768 + 255) / 256, 256, 0, stream>>>(semw, semwB, 512 * 768);
  prep_pointnet<<<1, 64, 0, stream>>>(pw1, pb1, pg1, G_pos, M_pos);
  prep_pointnet<<<1, 64, 0, stream>>>(aw1, ab1, ag1, G_aff, M_aff);

  // weight folds into BTcat
  gemm_bt<<<dim3(6, 6), 256, 0, stream>>>(fusT,        2304, pw4B,  768, nullptr, BTcat, 2048, 0,    768);
  gemm_bt<<<dim3(6, 6), 256, 0, stream>>>(fusT + 768,  2304, aw4B,  768, nullptr, BTcat, 2048, 768,  768);
  gemm_bt<<<dim3(4, 6), 256, 0, stream>>>(fusT + 1536, 2304, semwB, 768, nullptr, BTcat, 2048, 1536, 768);
  fuse_bias<<<768, 256, 0, stream>>>(fusb, fusw, pb4, ab4, semb, bias_tot);

  // counting sort by node, then per-node MFMA reduce (both branches)
  hist_idx<<<2048, 256, 0, stream>>>(pos_idx, P, cnt_pos);
  hist_idx<<<2048, 256, 0, stream>>>(aff_idx, P, cnt_aff);
  scan16k<<<1, 1024, 0, stream>>>(cnt_pos, offs_pos, cur_pos);
  scan16k<<<1, 1024, 0, stream>>>(cnt_aff, offs_aff, cur_aff);
  scatter_points<<<2048, 256, 0, stream>>>(x_pos, pos_idx, P, cur_pos, sorted_pos);
  scatter_points<<<2048, 256, 0, stream>>>(x_aff, aff_idx, P, cur_aff, sorted_aff);
  node_mlp_max<<<2048, 256, 0, stream>>>(sorted_pos, offs_pos, G_pos, M_pos, pbe1, pw2, pb2, xgB_pos);
  node_mlp_max<<<2048, 256, 0, stream>>>(sorted_aff, offs_aff, G_aff, M_aff, abe1, aw2, ab2, xgB_aff);

  // mlp2 first linear + LN + ReLU
  gemm_bt<<<dim3(6, NN / 128), 256, 0, stream>>>(xgB_pos, 64, w3T_pos, 64, pb3, t_pos, 768, 0, 64);
  gemm_bt<<<dim3(6, NN / 128), 256, 0, stream>>>(xgB_aff, 64, w3T_aff, 64, ab3, t_aff, 768, 0, 64);
  ln_relu_768_b16<<<NN, 256, 0, stream>>>(t_pos, pg2, pbe2, t_pos);
  ln_relu_768_b16<<<NN, 256, 0, stream>>>(t_aff, ag2, abe2, t_aff);

  // fused final GEMM + LN -> f32 out  (F aliases sorted_pos, dead by now)
  gemm_fuse3<<<dim3(6, NN / 128), 256, 0, stream>>>(t_pos, t_aff, x_sem, BTcat, bias_tot, F);
  ln_relu_768_f32<<<NN, 256, 0, stream>>>(F, fusg, fusbe, (float*)d_out);
}

// Round 6
// 830.019 us; speedup vs baseline: 1.2292x; 1.0331x over previous
//
#include <hip/hip_runtime.h>

typedef __attribute__((ext_vector_type(8))) __bf16 bf16x8;
typedef __attribute__((ext_vector_type(4))) float floatx4;

#define NN 16384
#define EPS 1e-5f
#define NEG_HUGE -3.402823466e38f

__device__ __forceinline__ unsigned short f2b(float f) {
  unsigned u = __float_as_uint(f);
  u += 0x7fffu + ((u >> 16) & 1u);
  return (unsigned short)(u >> 16);
}
__device__ __forceinline__ float b2f(unsigned short u) {
  return __uint_as_float(((unsigned)u) << 16);
}

// kept for harness symbol expectations; never launched
__global__ void RoboNodeEncoder_88424786690347_kernel() {}

// ---------------------------------------------------------------- zero init
__global__ __launch_bounds__(256) void zero_u32(unsigned* __restrict__ p, int n) {
  int i = blockIdx.x * blockDim.x + threadIdx.x;
  if (i < n) p[i] = 0u;
}

// --------------------------- merged f32->bf16 casts (3 sources, contiguous dst)
__global__ __launch_bounds__(256) void convert3(const float* __restrict__ a, int na,
                                                const float* __restrict__ b, int nb,
                                                const float* __restrict__ c, int nc,
                                                unsigned short* __restrict__ out) {
  int i = blockIdx.x * 256 + threadIdx.x;
  int total = na + nb + nc;
  if (i >= total) return;
  float v;
  if (i < na) v = a[i];
  else if (i < na + nb) v = b[i - na];
  else v = c[i - na - nb];
  out[i] = f2b(v);
}

// --------------------------------------------------- f32 -> bf16 transpose
__global__ __launch_bounds__(256) void transpose_f32_b16(const float* __restrict__ in,
                                                         unsigned short* __restrict__ out,
                                                         int R, int C) {
  __shared__ float t[32][33];
  int bx = blockIdx.x * 32, by = blockIdx.y * 32;
  int x = threadIdx.x, y = threadIdx.y;
#pragma unroll
  for (int i = 0; i < 32; i += 8) t[y + i][x] = in[(size_t)(by + y + i) * C + bx + x];
  __syncthreads();
#pragma unroll
  for (int i = 0; i < 32; i += 8) out[(size_t)(bx + y + i) * R + by + x] = f2b(t[x][y + i]);
}

// ---------------- w3 transpose pair: z selects branch, out stride 768*64
__global__ __launch_bounds__(256) void transpose_w3_pair(const float* __restrict__ pw3,
                                                         const float* __restrict__ aw3,
                                                         unsigned short* __restrict__ w3T) {
  __shared__ float t[32][33];
  const float* in = blockIdx.z ? aw3 : pw3;
  unsigned short* out = w3T + (size_t)blockIdx.z * 768 * 64;
  int R = 64, C = 768;
  int bx = blockIdx.x * 32, by = blockIdx.y * 32;
  int x = threadIdx.x, y = threadIdx.y;
#pragma unroll
  for (int i = 0; i < 32; i += 8) t[y + i][x] = in[(size_t)(by + y + i) * C + bx + x];
  __syncthreads();
#pragma unroll
  for (int i = 0; i < 32; i += 8) out[(size_t)(bx + y + i) * R + by + x] = f2b(t[x][y + i]);
}

// ------------------- prep: fold LN of the point MLP into closed-form consts
// blockIdx.x = branch (0=pos,1=aff); 64 threads.
__global__ void prep_pointnet2(const float* __restrict__ w1p, const float* __restrict__ b1p,
                               const float* __restrict__ g1p,
                               const float* __restrict__ w1a, const float* __restrict__ b1a,
                               const float* __restrict__ g1a,
                               float* __restrict__ G2, float* __restrict__ Mq2) {
  int br = blockIdx.x;
  const float* w1 = br ? w1a : w1p;
  const float* b1 = br ? b1a : b1p;
  const float* g1 = br ? g1a : g1p;
  float* G = G2 + br * 256;
  float* Mq = Mq2 + br * 16;
  int k = threadIdx.x;
  float c[4] = {w1[k], w1[64 + k], w1[128 + k], b1[k]};
#pragma unroll
  for (int a = 0; a < 4; a++) {
    float s = c[a];
#pragma unroll
    for (int off = 32; off > 0; off >>= 1) s += __shfl_xor(s, off, 64);
    c[a] -= s * (1.f / 64.f);
  }
  float g = g1[k];
#pragma unroll
  for (int a = 0; a < 4; a++) G[a * 64 + k] = c[a] * g;
  const int AA[10] = {0, 1, 2, 3, 0, 0, 0, 1, 1, 2};
  const int BB[10] = {0, 1, 2, 3, 1, 2, 3, 2, 3, 3};
#pragma unroll
  for (int t = 0; t < 10; t++) {
    float s = c[AA[t]] * c[BB[t]];
#pragma unroll
    for (int off = 32; off > 0; off >>= 1) s += __shfl_xor(s, off, 64);
    s *= (1.f / 64.f);
    if (t >= 4) s *= 2.f;
    if (k == 0) Mq[t] = s;
  }
}

// ------------------------------------------- histogram, both branches (y)
__global__ __launch_bounds__(256) void hist2(const int* __restrict__ pos_idx,
                                             const int* __restrict__ aff_idx, int P,
                                             unsigned* __restrict__ cntB) {
  const int* idx = blockIdx.y ? aff_idx : pos_idx;
  unsigned* cnt = cntB + blockIdx.y * NN;
  int stride = gridDim.x * blockDim.x;
  for (int i = blockIdx.x * blockDim.x + threadIdx.x; i < P; i += stride)
    atomicAdd(&cnt[idx[i]], 1u);
}

// ---------------------- exclusive scan of 16384 counters; blockIdx.x = branch
__global__ __launch_bounds__(1024) void scan2(const unsigned* __restrict__ cntB,
                                              unsigned* __restrict__ offsB,
                                              unsigned* __restrict__ curB) {
  int br = blockIdx.x;
  const unsigned* cnt = cntB + br * NN;
  unsigned* offs = offsB + br * (NN + 1);
  unsigned* cursor = curB + br * NN;
  __shared__ unsigned ps[1024];
  int t = threadIdx.x;
  unsigned v[16];
  unsigned s = 0;
#pragma unroll
  for (int i = 0; i < 16; i++) { v[i] = cnt[t * 16 + i]; s += v[i]; }
  ps[t] = s;
  __syncthreads();
  for (int off = 1; off < 1024; off <<= 1) {
    unsigned add = (t >= off) ? ps[t - off] : 0u;
    __syncthreads();
    ps[t] += add;
    __syncthreads();
  }
  unsigned base = (t > 0) ? ps[t - 1] : 0u;
#pragma unroll
  for (int i = 0; i < 16; i++) {
    offs[t * 16 + i] = base;
    cursor[t * 16 + i] = base;
    base += v[i];
  }
  if (t == 1023) offs[NN] = base;
}

// ------------------------------- scatter into node order, both branches (y)
__global__ __launch_bounds__(256) void scatter2(const float* __restrict__ x_pos,
                                                const float* __restrict__ x_aff,
                                                const int* __restrict__ pos_idx,
                                                const int* __restrict__ aff_idx, int P,
                                                unsigned* __restrict__ curB,
                                                float4* __restrict__ sortedB) {
  int br = blockIdx.y;
  const float* x = br ? x_aff : x_pos;
  const int* idx = br ? aff_idx : pos_idx;
  unsigned* cursor = curB + br * NN;
  float4* sorted = sortedB + (size_t)br * P;
  int stride = gridDim.x * blockDim.x;
  for (int i = blockIdx.x * blockDim.x + threadIdx.x; i < P; i += stride) {
    int nd = idx[i];
    unsigned pos = atomicAdd(&cursor[nd], 1u);
    float4 v;
    v.x = x[3 * i]; v.y = x[3 * i + 1]; v.z = x[3 * i + 2]; v.w = 0.f;
    sorted[pos] = v;
  }
}

// ----------------- per-node: folded-LN MLP + MFMA 64x64 + in-register max
// wave per node, both branches via blockIdx.y. XOR-swizzled 64-short LDS rows
// (8KB/wave, no w2 staging) -> 32KB/block -> 5 blocks/CU.
__global__ __launch_bounds__(256, 5) void node_mlp2(
    const float4* __restrict__ sortedB, const unsigned* __restrict__ offsB,
    const float* __restrict__ G2, const float* __restrict__ Mq2,
    const float* __restrict__ be1p, const float* __restrict__ be1a,
    const float* __restrict__ w2p, const float* __restrict__ w2a,
    const float* __restrict__ b2p, const float* __restrict__ b2a,
    unsigned short* __restrict__ xgB, int P) {
  int br = blockIdx.y;
  const float4* sorted = sortedB + (size_t)br * P;
  const unsigned* offs = offsB + br * (NN + 1);
  const float* G = G2 + br * 256;
  const float* Mq = Mq2 + br * 16;
  const float* be1 = br ? be1a : be1p;
  const float* w2 = br ? w2a : w2p;
  const float* b2 = br ? b2a : b2p;
  unsigned short* out = xgB + (size_t)br * NN * 64;

  __shared__ __align__(16) unsigned short hs[4][64 * 64];  // 8KB/wave
  int tid = threadIdx.x;
  int lane = tid & 63, w = tid >> 6;
  int lr = lane & 15, quad = lane >> 4;
  int l7 = lane & 7;

  // B frags straight from global (w2 is 16KB, L2-hot): bfr[j][s][e] = w2[k][n]
  bf16x8 bfr[4][2];
#pragma unroll
  for (int j = 0; j < 4; j++)
#pragma unroll
    for (int s = 0; s < 2; s++) {
      bf16x8 f;
#pragma unroll
      for (int e = 0; e < 8; e++)
        f[e] = (__bf16)w2[(s * 32 + quad * 8 + e) * 64 + j * 16 + lr];
      bfr[j][s] = f;
    }
  float b2v = b2[lane];
  float M00 = Mq[0], M11 = Mq[1], M22 = Mq[2], M33 = Mq[3];
  float T01 = Mq[4], T02 = Mq[5], T03 = Mq[6], T12 = Mq[7], T13 = Mq[8], T23 = Mq[9];

  unsigned short* hrow = &hs[w][0];
  int gw = blockIdx.x * 4 + w;
  int nwv = gridDim.x * 4;
  for (int node = gw; node < NN; node += nwv) {
    unsigned seg0 = offs[node], seg1 = offs[node + 1];
    int cnt = (int)(seg1 - seg0);
    if (cnt == 0) { out[(size_t)node * 64 + lane] = 0; continue; }

    float lmax[4] = {NEG_HUGE, NEG_HUGE, NEG_HUGE, NEG_HUGE};
    for (int t0 = 0; t0 < cnt; t0 += 64) {
      int pi = t0 + lane;
      if (pi >= cnt) pi = cnt - 1;  // duplicate a real point: max-neutral
      float4 xv = sorted[seg0 + pi];
      float x0 = xv.x, x1 = xv.y, x2 = xv.z;
      float var = M33 + x0 * fmaf(M00, x0, fmaf(T01, x1, fmaf(T02, x2, T03)))
                      + x1 * fmaf(M11, x1, fmaf(T12, x2, T13))
                      + x2 * fmaf(M22, x2, T23);
      float rstd = rsqrtf(var + EPS);
      float x0r = x0 * rstd, x1r = x1 * rstd, x2r = x2 * rstd;
#pragma unroll
      for (int c = 0; c < 8; c++) {
        bf16x8 hv;
#pragma unroll
        for (int e = 0; e < 8; e++) {
          int k = c * 8 + e;
          float y = fmaf(x0r, G[k], fmaf(x1r, G[64 + k],
                    fmaf(x2r, G[128 + k], fmaf(rstd, G[192 + k], be1[k]))));
          hv[e] = (__bf16)fmaxf(y, 0.f);
        }
        *reinterpret_cast<bf16x8*>(&hrow[lane * 64 + ((c ^ l7) << 3)]) = hv;
      }
      asm volatile("s_waitcnt lgkmcnt(0)" ::: "memory");
      floatx4 acc[4][4] = {};
#pragma unroll
      for (int i = 0; i < 4; i++) {
        int row = i * 16 + lr;
        bf16x8 a0 = *reinterpret_cast<const bf16x8*>(&hrow[row * 64 + ((quad ^ l7) << 3)]);
        bf16x8 a1 = *reinterpret_cast<const bf16x8*>(&hrow[row * 64 + (((4 + quad) ^ l7) << 3)]);
#pragma unroll
        for (int j = 0; j < 4; j++) {
          acc[i][j] = __builtin_amdgcn_mfma_f32_16x16x32_bf16(a0, bfr[j][0], acc[i][j], 0, 0, 0);
          acc[i][j] = __builtin_amdgcn_mfma_f32_16x16x32_bf16(a1, bfr[j][1], acc[i][j], 0, 0, 0);
        }
      }
      // unmasked running max (all rows are valid points by construction)
#pragma unroll
      for (int i = 0; i < 4; i++)
#pragma unroll
        for (int j = 0; j < 4; j++) {
          floatx4 a = acc[i][j];
          lmax[j] = fmaxf(lmax[j], fmaxf(fmaxf(a[0], a[1]), fmaxf(a[2], a[3])));
        }
    }
#pragma unroll
    for (int j = 0; j < 4; j++) {
      lmax[j] = fmaxf(lmax[j], __shfl_xor(lmax[j], 16, 64));
      lmax[j] = fmaxf(lmax[j], __shfl_xor(lmax[j], 32, 64));
    }
    out[(size_t)node * 64 + lane] = f2b(lmax[quad] + b2v);
  }
}

// ------------------------------------------------------------- GEMM core
__device__ __forceinline__ void gemm_core(
    const unsigned short* __restrict__ A, int lda,
    const unsigned short* __restrict__ BT, int ldb,
    const float* __restrict__ bias,
    unsigned short* __restrict__ C, int ldc, int colOff, int K,
    int m0, int n0) {
  __shared__ __align__(16) unsigned short As[128 * 32];
  __shared__ __align__(16) unsigned short Bs[128 * 32];
  int tid = threadIdx.x;
  int lane = tid & 63, w = tid >> 6;
  int wm = (w >> 1) * 64, wn = (w & 1) * 64;
  int lr = lane & 15, quad = lane >> 4;
  floatx4 acc[4][4] = {};

  for (int k0 = 0; k0 < K; k0 += 32) {
    __syncthreads();
#pragma unroll
    for (int s = 0; s < 2; s++) {
      int cc = tid + s * 256;
      int row = cc >> 2, kc = (cc & 3) << 3;
      *reinterpret_cast<uint4*>(&As[row * 32 + kc]) =
          *reinterpret_cast<const uint4*>(&A[(size_t)(m0 + row) * lda + k0 + kc]);
      *reinterpret_cast<uint4*>(&Bs[row * 32 + kc]) =
          *reinterpret_cast<const uint4*>(&BT[(size_t)(n0 + row) * ldb + k0 + kc]);
    }
    __syncthreads();
    bf16x8 a[4], b[4];
#pragma unroll
    for (int i = 0; i < 4; i++)
      a[i] = *reinterpret_cast<const bf16x8*>(&As[(wm + i * 16 + lr) * 32 + quad * 8]);
#pragma unroll
    for (int j = 0; j < 4; j++)
      b[j] = *reinterpret_cast<const bf16x8*>(&Bs[(wn + j * 16 + lr) * 32 + quad * 8]);
#pragma unroll
    for (int i = 0; i < 4; i++)
#pragma unroll
      for (int j = 0; j < 4; j++)
        acc[i][j] = __builtin_amdgcn_mfma_f32_16x16x32_bf16(a[i], b[j], acc[i][j], 0, 0, 0);
  }
#pragma unroll
  for (int j = 0; j < 4; j++) {
    int gcol = n0 + wn + j * 16 + lr;
    float bv = bias ? bias[gcol] : 0.0f;
#pragma unroll
    for (int i = 0; i < 4; i++) {
#pragma unroll
      for (int r = 0; r < 4; r++) {
        int grow = m0 + wm + i * 16 + quad * 4 + r;
        C[(size_t)grow * ldc + colOff + gcol] = f2b(acc[i][j][r] + bv);
      }
    }
  }
}

// fold GEMMs: z=0 pos-w4, z=1 aff-w4, z=2 sem (N=512 -> skip bx>=4)
__global__ __launch_bounds__(256) void gemm_fold(const unsigned short* __restrict__ fusT,
                                                 const unsigned short* __restrict__ wB,
                                                 unsigned short* __restrict__ BTcat) {
  int z = blockIdx.z;
  if (z == 2 && blockIdx.x >= 4) return;
  gemm_core(fusT + z * 768, 2304, wB + (size_t)z * 589824, 768, nullptr,
            BTcat, 2048, z * 768, 768, blockIdx.y * 128, blockIdx.x * 128);
}

// w3 GEMM pair: z = branch
__global__ __launch_bounds__(256) void gemm_w3(const unsigned short* __restrict__ xgB,
                                               const unsigned short* __restrict__ w3T,
                                               const float* __restrict__ pb3,
                                               const float* __restrict__ ab3,
                                               unsigned short* __restrict__ t) {
  int z = blockIdx.z;
  gemm_core(xgB + (size_t)z * NN * 64, 64, w3T + (size_t)z * 768 * 64, 64,
            z ? ab3 : pb3, t + (size_t)z * NN * 768, 768, 0, 64,
            blockIdx.y * 128, blockIdx.x * 128);
}

// ----------------------- fused final GEMM: virtual K=2048 over 3 A sources
__global__ __launch_bounds__(256) void gemm_fuse3(
    const unsigned short* __restrict__ A0, const unsigned short* __restrict__ A1,
    const float* __restrict__ A2f, const unsigned short* __restrict__ BT,
    const float* __restrict__ bias, unsigned short* __restrict__ C) {
  __shared__ __align__(16) unsigned short As[128 * 32];
  __shared__ __align__(16) unsigned short Bs[128 * 32];
  int tid = threadIdx.x;
  int m0 = blockIdx.y * 128, n0 = blockIdx.x * 128;
  int lane = tid & 63, w = tid >> 6;
  int wm = (w >> 1) * 64, wn = (w & 1) * 64;
  int lr = lane & 15, quad = lane >> 4;
  floatx4 acc[4][4] = {};

  for (int k0 = 0; k0 < 2048; k0 += 32) {
    __syncthreads();
    if (k0 < 1536) {
      const unsigned short* Ap = (k0 < 768) ? A0 : A1;
      int kk = (k0 < 768) ? k0 : (k0 - 768);
#pragma unroll
      for (int s = 0; s < 2; s++) {
        int cc = tid + s * 256;
        int row = cc >> 2, kc = (cc & 3) << 3;
        *reinterpret_cast<uint4*>(&As[row * 32 + kc]) =
            *reinterpret_cast<const uint4*>(&Ap[(size_t)(m0 + row) * 768 + kk + kc]);
      }
    } else {
      int kk = k0 - 1536;
#pragma unroll
      for (int s = 0; s < 2; s++) {
        int cc = tid + s * 256;
        int row = cc >> 2, kc = (cc & 3) << 3;
        const float* src = &A2f[(size_t)(m0 + row) * 512 + kk + kc];
        float4 fa = *reinterpret_cast<const float4*>(src);
        float4 fb = *reinterpret_cast<const float4*>(src + 4);
        uint4 pk;
        pk.x = (unsigned)f2b(fa.x) | ((unsigned)f2b(fa.y) << 16);
        pk.y = (unsigned)f2b(fa.z) | ((unsigned)f2b(fa.w) << 16);
        pk.z = (unsigned)f2b(fb.x) | ((unsigned)f2b(fb.y) << 16);
        pk.w = (unsigned)f2b(fb.z) | ((unsigned)f2b(fb.w) << 16);
        *reinterpret_cast<uint4*>(&As[row * 32 + kc]) = pk;
      }
    }
#pragma unroll
    for (int s = 0; s < 2; s++) {
      int cc = tid + s * 256;
      int row = cc >> 2, kc = (cc & 3) << 3;
      *reinterpret_cast<uint4*>(&Bs[row * 32 + kc]) =
          *reinterpret_cast<const uint4*>(&BT[(size_t)(n0 + row) * 2048 + k0 + kc]);
    }
    __syncthreads();
    bf16x8 a[4], b[4];
#pragma unroll
    for (int i = 0; i < 4; i++)
      a[i] = *reinterpret_cast<const bf16x8*>(&As[(wm + i * 16 + lr) * 32 + quad * 8]);
#pragma unroll
    for (int j = 0; j < 4; j++)
      b[j] = *reinterpret_cast<const bf16x8*>(&Bs[(wn + j * 16 + lr) * 32 + quad * 8]);
#pragma unroll
    for (int i = 0; i < 4; i++)
#pragma unroll
      for (int j = 0; j < 4; j++)
        acc[i][j] = __builtin_amdgcn_mfma_f32_16x16x32_bf16(a[i], b[j], acc[i][j], 0, 0, 0);
  }
#pragma unroll
  for (int j = 0; j < 4; j++) {
    int gcol = n0 + wn + j * 16 + lr;
    float bv = bias[gcol];
#pragma unroll
    for (int i = 0; i < 4; i++) {
#pragma unroll
      for (int r = 0; r < 4; r++) {
        int grow = m0 + wm + i * 16 + quad * 4 + r;
        C[(size_t)grow * 768 + gcol] = f2b(acc[i][j][r] + bv);
      }
    }
  }
}

// ------------- fold all upstream biases into the fusion bias (f32 in/out)
__global__ __launch_bounds__(256) void fuse_bias(
    const float* __restrict__ fus_b, const float* __restrict__ fus_w,
    const float* __restrict__ pb4, const float* __restrict__ ab4,
    const float* __restrict__ semb, float* __restrict__ bias_tot) {
  int c = blockIdx.x;
  int tid = threadIdx.x;
  float s = 0.f;
  for (int j = tid; j < 768; j += 256) {
    s = fmaf(pb4[j],  fus_w[(size_t)j * 768 + c], s);
    s = fmaf(ab4[j],  fus_w[(size_t)(768 + j) * 768 + c], s);
    s = fmaf(semb[j], fus_w[(size_t)(1536 + j) * 768 + c], s);
  }
#pragma unroll
  for (int off = 32; off > 0; off >>= 1) s += __shfl_xor(s, off, 64);
  __shared__ float sm[4];
  if ((tid & 63) == 0) sm[tid >> 6] = s;
  __syncthreads();
  if (tid == 0) bias_tot[c] = sm[0] + sm[1] + sm[2] + sm[3] + fus_b[c];
}

// ----------------------- rowwise LN(768)+ReLU pair, bf16 in/out, y = branch
__global__ __launch_bounds__(256) void ln2(unsigned short* __restrict__ tB,
                                           const float* __restrict__ pg2,
                                           const float* __restrict__ pbe2,
                                           const float* __restrict__ ag2,
                                           const float* __restrict__ abe2) {
  int br = blockIdx.y;
  unsigned short* X = tB + (size_t)br * NN * 768;
  const float* g = br ? ag2 : pg2;
  const float* be = br ? abe2 : pbe2;
  int row = blockIdx.x, tid = threadIdx.x;
  size_t base = (size_t)row * 768;
  float xv[3];
#pragma unroll
  for (int i = 0; i < 3; i++) xv[i] = b2f(X[base + tid + i * 256]);
  float s = xv[0] + xv[1] + xv[2];
  float q = xv[0] * xv[0] + xv[1] * xv[1] + xv[2] * xv[2];
#pragma unroll
  for (int off = 32; off > 0; off >>= 1) {
    s += __shfl_xor(s, off, 64);
    q += __shfl_xor(q, off, 64);
  }
  __shared__ float ss[4], qq[4];
  int w = tid >> 6, lane = tid & 63;
  if (lane == 0) { ss[w] = s; qq[w] = q; }
  __syncthreads();
  s = ss[0] + ss[1] + ss[2] + ss[3];
  q = qq[0] + qq[1] + qq[2] + qq[3];
  float m = s * (1.0f / 768.0f);
  float v = fmaf(-m, m, q * (1.0f / 768.0f));
  float rstd = rsqrtf(v + EPS);
#pragma unroll
  for (int i = 0; i < 3; i++) {
    int c = tid + i * 256;
    float y = (xv[i] - m) * rstd * g[c] + be[c];
    X[base + c] = f2b(fmaxf(y, 0.0f));
  }
}

// ------------------------------------- rowwise LN(768)+ReLU, bf16 in/f32 out
__global__ __launch_bounds__(256) void ln_relu_768_f32(
    const unsigned short* __restrict__ X, const float* __restrict__ g,
    const float* __restrict__ be, float* __restrict__ Y) {
  int row = blockIdx.x, tid = threadIdx.x;
  size_t base = (size_t)row * 768;
  float xv[3];
#pragma unroll
  for (int i = 0; i < 3; i++) xv[i] = b2f(X[base + tid + i * 256]);
  float s = xv[0] + xv[1] + xv[2];
  float q = xv[0] * xv[0] + xv[1] * xv[1] + xv[2] * xv[2];
#pragma unroll
  for (int off = 32; off > 0; off >>= 1) {
    s += __shfl_xor(s, off, 64);
    q += __shfl_xor(q, off, 64);
  }
  __shared__ float ss[4], qq[4];
  int w = tid >> 6, lane = tid & 63;
  if (lane == 0) { ss[w] = s; qq[w] = q; }
  __syncthreads();
  s = ss[0] + ss[1] + ss[2] + ss[3];
  q = qq[0] + qq[1] + qq[2] + qq[3];
  float m = s * (1.0f / 768.0f);
  float v = fmaf(-m, m, q * (1.0f / 768.0f));
  float rstd = rsqrtf(v + EPS);
#pragma unroll
  for (int i = 0; i < 3; i++) {
    int c = tid + i * 256;
    float y = (xv[i] - m) * rstd * g[c] + be[c];
    Y[base + c] = fmaxf(y, 0.0f);
  }
}

extern "C" void kernel_launch(void* const* d_in, const int* in_sizes, int n_in,
                              void* d_out, int out_size, void* d_ws, size_t ws_size,
                              hipStream_t stream) {
  typedef const float* cf;
  cf x_pos = (cf)d_in[0];
  const int* pos_idx = (const int*)d_in[1];
  cf x_aff = (cf)d_in[2];
  const int* aff_idx = (const int*)d_in[3];
  cf x_sem = (cf)d_in[4];
  cf pw1 = (cf)d_in[6],  pb1 = (cf)d_in[7],  pg1 = (cf)d_in[8],  pbe1 = (cf)d_in[9];
  cf pw2 = (cf)d_in[10], pb2 = (cf)d_in[11];
  cf pw3 = (cf)d_in[12], pb3 = (cf)d_in[13], pg2 = (cf)d_in[14], pbe2 = (cf)d_in[15];
  cf pw4 = (cf)d_in[16], pb4 = (cf)d_in[17];
  cf aw1 = (cf)d_in[18], ab1 = (cf)d_in[19], ag1 = (cf)d_in[20], abe1 = (cf)d_in[21];
  cf aw2 = (cf)d_in[22], ab2 = (cf)d_in[23];
  cf aw3 = (cf)d_in[24], ab3 = (cf)d_in[25], ag2 = (cf)d_in[26], abe2 = (cf)d_in[27];
  cf aw4 = (cf)d_in[28], ab4 = (cf)d_in[29];
  cf semw = (cf)d_in[30], semb = (cf)d_in[31];
  cf fusw = (cf)d_in[32], fusb = (cf)d_in[33], fusg = (cf)d_in[34], fusbe = (cf)d_in[35];

  int P = in_sizes[0] / 3;

  char* wsb = (char*)d_ws;
  size_t off = 0;
  auto carve = [&](size_t bytes) -> void* {
    void* p = wsb + off;
    off = (off + bytes + 255) & ~(size_t)255;
    return p;
  };
  unsigned short* xgB   = (unsigned short*)carve((size_t)2 * NN * 64 * 2);   // 4 MiB
  unsigned short* t     = (unsigned short*)carve((size_t)2 * NN * 768 * 2);  // 48 MiB
  float4* sorted        = (float4*)carve((size_t)2 * P * 16);                // 32 MiB
  unsigned short* F = (unsigned short*)sorted;  // alias: sorted dead before fuse3
  unsigned short* w3T   = (unsigned short*)carve((size_t)2 * 768 * 64 * 2);
  unsigned short* fusT  = (unsigned short*)carve((size_t)768 * 2304 * 2);
  unsigned short* wB    = (unsigned short*)carve((size_t)1572864 * 2);       // pw4B|aw4B|semwB
  unsigned short* BTcat = (unsigned short*)carve((size_t)768 * 2048 * 2);
  float* bias_tot = (float*)carve((size_t)768 * 4);
  float* G2  = (float*)carve((size_t)512 * 4);
  float* Mq2 = (float*)carve((size_t)32 * 4);
  unsigned* cnt  = (unsigned*)carve((size_t)2 * NN * 4);
  unsigned* offs = (unsigned*)carve((size_t)2 * (NN + 1) * 4);
  unsigned* cur  = (unsigned*)carve((size_t)2 * NN * 4);
  // total ~94 MiB (same as validated R5 footprint)

  zero_u32<<<(2 * NN + 255) / 256, 256, 0, stream>>>(cnt, 2 * NN);

  dim3 tb(32, 8);
  transpose_w3_pair<<<dim3(24, 2, 2), tb, 0, stream>>>(pw3, aw3, w3T);
  transpose_f32_b16<<<dim3(24, 72), tb, 0, stream>>>(fusw, fusT, 2304, 768);
  convert3<<<(1572864 + 255) / 256, 256, 0, stream>>>(pw4, 589824, aw4, 589824,
                                                      semw, 393216, wB);
  prep_pointnet2<<<2, 64, 0, stream>>>(pw1, pb1, pg1, aw1, ab1, ag1, G2, Mq2);

  gemm_fold<<<dim3(6, 6, 3), 256, 0, stream>>>(fusT, wB, BTcat);
  fuse_bias<<<768, 256, 0, stream>>>(fusb, fusw, pb4, ab4, semb, bias_tot);

  hist2<<<dim3(1024, 2), 256, 0, stream>>>(pos_idx, aff_idx, P, cnt);
  scan2<<<2, 1024, 0, stream>>>(cnt, offs, cur);
  scatter2<<<dim3(1024, 2), 256, 0, stream>>>(x_pos, x_aff, pos_idx, aff_idx, P, cur, sorted);
  node_mlp2<<<dim3(2048, 2), 256, 0, stream>>>(sorted, offs, G2, Mq2, pbe1, abe1,
                                               pw2, aw2, pb2, ab2, xgB, P);

  gemm_w3<<<dim3(6, NN / 128, 2), 256, 0, stream>>>(xgB, w3T, pb3, ab3, t);
  ln2<<<dim3(NN, 2), 256, 0, stream>>>(t, pg2, pbe2, ag2, abe2);

  gemm_fuse3<<<dim3(6, NN / 128), 256, 0, stream>>>(t, t + (size_t)NN * 768, x_sem,
                                                    BTcat, bias_tot, F);
  ln_relu_768_f32<<<NN, 256, 0, stream>>>(F, fusg, fusbe, (float*)d_out);
}

// Round 7
// 751.346 us; speedup vs baseline: 1.3579x; 1.1047x over previous
//
#include <hip/hip_runtime.h>

typedef __attribute__((ext_vector_type(8))) __bf16 bf16x8;
typedef __attribute__((ext_vector_type(4))) float floatx4;

#define NN 16384
#define EPS 1e-5f
#define NEG_HUGE -3.402823466e38f

__device__ __forceinline__ unsigned short f2b(float f) {
  unsigned u = __float_as_uint(f);
  u += 0x7fffu + ((u >> 16) & 1u);
  return (unsigned short)(u >> 16);
}
__device__ __forceinline__ float b2f(unsigned short u) {
  return __uint_as_float(((unsigned)u) << 16);
}

// kept for harness symbol expectations; never launched
__global__ void RoboNodeEncoder_88424786690347_kernel() {}

// ---------------------------------------------------------------- zero init
__global__ __launch_bounds__(256) void zero_u32(unsigned* __restrict__ p, int n) {
  int i = blockIdx.x * blockDim.x + threadIdx.x;
  if (i < n) p[i] = 0u;
}

// --------------------------- merged f32->bf16 casts (3 sources, contiguous dst)
__global__ __launch_bounds__(256) void convert3(const float* __restrict__ a, int na,
                                                const float* __restrict__ b, int nb,
                                                const float* __restrict__ c, int nc,
                                                unsigned short* __restrict__ out) {
  int i = blockIdx.x * 256 + threadIdx.x;
  int total = na + nb + nc;
  if (i >= total) return;
  float v;
  if (i < na) v = a[i];
  else if (i < na + nb) v = b[i - na];
  else v = c[i - na - nb];
  out[i] = f2b(v);
}

// --------------------------------------------------- f32 -> bf16 transpose
__global__ __launch_bounds__(256) void transpose_f32_b16(const float* __restrict__ in,
                                                         unsigned short* __restrict__ out,
                                                         int R, int C) {
  __shared__ float t[32][33];
  int bx = blockIdx.x * 32, by = blockIdx.y * 32;
  int x = threadIdx.x, y = threadIdx.y;
#pragma unroll
  for (int i = 0; i < 32; i += 8) t[y + i][x] = in[(size_t)(by + y + i) * C + bx + x];
  __syncthreads();
#pragma unroll
  for (int i = 0; i < 32; i += 8) out[(size_t)(bx + y + i) * R + by + x] = f2b(t[x][y + i]);
}

// ---------------- w3 transpose pair: z selects branch, out stride 768*64
__global__ __launch_bounds__(256) void transpose_w3_pair(const float* __restrict__ pw3,
                                                         const float* __restrict__ aw3,
                                                         unsigned short* __restrict__ w3T) {
  __shared__ float t[32][33];
  const float* in = blockIdx.z ? aw3 : pw3;
  unsigned short* out = w3T + (size_t)blockIdx.z * 768 * 64;
  int R = 64, C = 768;
  int bx = blockIdx.x * 32, by = blockIdx.y * 32;
  int x = threadIdx.x, y = threadIdx.y;
#pragma unroll
  for (int i = 0; i < 32; i += 8) t[y + i][x] = in[(size_t)(by + y + i) * C + bx + x];
  __syncthreads();
#pragma unroll
  for (int i = 0; i < 32; i += 8) out[(size_t)(bx + y + i) * R + by + x] = f2b(t[x][y + i]);
}

// ------------------- prep: fold LN of the point MLP into closed-form consts
// blockIdx.x = branch (0=pos,1=aff); 64 threads. Also emits bf16 w2^T
// (w2T[n*64+k] = w2[k][n]) so node_mlp2 B-frags are coalesced b128 loads.
__global__ void prep_pointnet2(const float* __restrict__ w1p, const float* __restrict__ b1p,
                               const float* __restrict__ g1p,
                               const float* __restrict__ w1a, const float* __restrict__ b1a,
                               const float* __restrict__ g1a,
                               const float* __restrict__ w2p, const float* __restrict__ w2a,
                               float* __restrict__ G2, float* __restrict__ Mq2,
                               unsigned short* __restrict__ w2T) {
  int br = blockIdx.x;
  const float* w1 = br ? w1a : w1p;
  const float* b1 = br ? b1a : b1p;
  const float* g1 = br ? g1a : g1p;
  const float* w2 = br ? w2a : w2p;
  float* G = G2 + br * 256;
  float* Mq = Mq2 + br * 16;
  unsigned short* w2t = w2T + br * 4096;
  int k = threadIdx.x;
  // w2 transpose to bf16: w2t[n][k] = w2[k][n]
#pragma unroll
  for (int n = 0; n < 64; n++) w2t[n * 64 + k] = f2b(w2[k * 64 + n]);
  float c[4] = {w1[k], w1[64 + k], w1[128 + k], b1[k]};
#pragma unroll
  for (int a = 0; a < 4; a++) {
    float s = c[a];
#pragma unroll
    for (int off = 32; off > 0; off >>= 1) s += __shfl_xor(s, off, 64);
    c[a] -= s * (1.f / 64.f);
  }
  float g = g1[k];
#pragma unroll
  for (int a = 0; a < 4; a++) G[a * 64 + k] = c[a] * g;
  const int AA[10] = {0, 1, 2, 3, 0, 0, 0, 1, 1, 2};
  const int BB[10] = {0, 1, 2, 3, 1, 2, 3, 2, 3, 3};
#pragma unroll
  for (int t = 0; t < 10; t++) {
    float s = c[AA[t]] * c[BB[t]];
#pragma unroll
    for (int off = 32; off > 0; off >>= 1) s += __shfl_xor(s, off, 64);
    s *= (1.f / 64.f);
    if (t >= 4) s *= 2.f;
    if (k == 0) Mq[t] = s;
  }
}

// ------------------------------------------- histogram, both branches (y)
__global__ __launch_bounds__(256) void hist2(const int* __restrict__ pos_idx,
                                             const int* __restrict__ aff_idx, int P,
                                             unsigned* __restrict__ cntB) {
  const int* idx = blockIdx.y ? aff_idx : pos_idx;
  unsigned* cnt = cntB + blockIdx.y * NN;
  int stride = gridDim.x * blockDim.x;
  for (int i = blockIdx.x * blockDim.x + threadIdx.x; i < P; i += stride)
    atomicAdd(&cnt[idx[i]], 1u);
}

// ---------------------- exclusive scan of 16384 counters; blockIdx.x = branch
__global__ __launch_bounds__(1024) void scan2(const unsigned* __restrict__ cntB,
                                              unsigned* __restrict__ offsB,
                                              unsigned* __restrict__ curB) {
  int br = blockIdx.x;
  const unsigned* cnt = cntB + br * NN;
  unsigned* offs = offsB + br * (NN + 1);
  unsigned* cursor = curB + br * NN;
  __shared__ unsigned ps[1024];
  int t = threadIdx.x;
  unsigned v[16];
  unsigned s = 0;
#pragma unroll
  for (int i = 0; i < 16; i++) { v[i] = cnt[t * 16 + i]; s += v[i]; }
  ps[t] = s;
  __syncthreads();
  for (int off = 1; off < 1024; off <<= 1) {
    unsigned add = (t >= off) ? ps[t - off] : 0u;
    __syncthreads();
    ps[t] += add;
    __syncthreads();
  }
  unsigned base = (t > 0) ? ps[t - 1] : 0u;
#pragma unroll
  for (int i = 0; i < 16; i++) {
    offs[t * 16 + i] = base;
    cursor[t * 16 + i] = base;
    base += v[i];
  }
  if (t == 1023) offs[NN] = base;
}

// ------------------------------- scatter into node order, both branches (y)
__global__ __launch_bounds__(256) void scatter2(const float* __restrict__ x_pos,
                                                const float* __restrict__ x_aff,
                                                const int* __restrict__ pos_idx,
                                                const int* __restrict__ aff_idx, int P,
                                                unsigned* __restrict__ curB,
                                                float4* __restrict__ sortedB) {
  int br = blockIdx.y;
  const float* x = br ? x_aff : x_pos;
  const int* idx = br ? aff_idx : pos_idx;
  unsigned* cursor = curB + br * NN;
  float4* sorted = sortedB + (size_t)br * P;
  int stride = gridDim.x * blockDim.x;
  for (int i = blockIdx.x * blockDim.x + threadIdx.x; i < P; i += stride) {
    int nd = idx[i];
    unsigned pos = atomicAdd(&cursor[nd], 1u);
    float4 v;
    v.x = x[3 * i]; v.y = x[3 * i + 1]; v.z = x[3 * i + 2]; v.w = 0.f;
    sorted[pos] = v;
  }
}

// ----------------- per-node: folded-LN MLP + MFMA 64x64 + in-register max
// wave per node, both branches via blockIdx.y. XOR-swizzled 64-short LDS rows
// (8KB/wave) -> 32KB/block. launch_bounds(256,4): <=128 VGPR, no spill.
__global__ __launch_bounds__(256, 4) void node_mlp2(
    const float4* __restrict__ sortedB, const unsigned* __restrict__ offsB,
    const float* __restrict__ G2, const float* __restrict__ Mq2,
    const float* __restrict__ be1p, const float* __restrict__ be1a,
    const unsigned short* __restrict__ w2T,
    const float* __restrict__ b2p, const float* __restrict__ b2a,
    unsigned short* __restrict__ xgB, int P) {
  int br = blockIdx.y;
  const float4* sorted = sortedB + (size_t)br * P;
  const unsigned* offs = offsB + br * (NN + 1);
  const float* G = G2 + br * 256;
  const float* Mq = Mq2 + br * 16;
  const float* be1 = br ? be1a : be1p;
  const unsigned short* w2t = w2T + br * 4096;
  const float* b2 = br ? b2a : b2p;
  unsigned short* out = xgB + (size_t)br * NN * 64;

  __shared__ __align__(16) unsigned short hs[4][64 * 64];  // 8KB/wave
  int tid = threadIdx.x;
  int lane = tid & 63, w = tid >> 6;
  int lr = lane & 15, quad = lane >> 4;
  int l7 = lane & 7;

  // B frags: coalesced b128 loads from pre-transposed bf16 w2T (L2-hot)
  bf16x8 bfr[4][2];
#pragma unroll
  for (int j = 0; j < 4; j++)
#pragma unroll
    for (int s = 0; s < 2; s++)
      bfr[j][s] = *reinterpret_cast<const bf16x8*>(&w2t[(j * 16 + lr) * 64 + s * 32 + quad * 8]);
  float b2v = b2[lane];
  float M00 = Mq[0], M11 = Mq[1], M22 = Mq[2], M33 = Mq[3];
  float T01 = Mq[4], T02 = Mq[5], T03 = Mq[6], T12 = Mq[7], T13 = Mq[8], T23 = Mq[9];

  unsigned short* hrow = &hs[w][0];
  int gw = blockIdx.x * 4 + w;
  int nwv = gridDim.x * 4;
  for (int node = gw; node < NN; node += nwv) {
    unsigned seg0 = offs[node], seg1 = offs[node + 1];
    int cnt = (int)(seg1 - seg0);
    if (cnt == 0) { out[(size_t)node * 64 + lane] = 0; continue; }

    float lmax[4] = {NEG_HUGE, NEG_HUGE, NEG_HUGE, NEG_HUGE};
    for (int t0 = 0; t0 < cnt; t0 += 64) {
      int pi = t0 + lane;
      if (pi >= cnt) pi = cnt - 1;  // duplicate a real point: max-neutral
      float4 xv = sorted[seg0 + pi];
      float x0 = xv.x, x1 = xv.y, x2 = xv.z;
      float var = M33 + x0 * fmaf(M00, x0, fmaf(T01, x1, fmaf(T02, x2, T03)))
                      + x1 * fmaf(M11, x1, fmaf(T12, x2, T13))
                      + x2 * fmaf(M22, x2, T23);
      float rstd = rsqrtf(var + EPS);
      float x0r = x0 * rstd, x1r = x1 * rstd, x2r = x2 * rstd;
#pragma unroll
      for (int c = 0; c < 8; c++) {
        bf16x8 hv;
#pragma unroll
        for (int e = 0; e < 8; e++) {
          int k = c * 8 + e;
          float y = fmaf(x0r, G[k], fmaf(x1r, G[64 + k],
                    fmaf(x2r, G[128 + k], fmaf(rstd, G[192 + k], be1[k]))));
          hv[e] = (__bf16)fmaxf(y, 0.f);
        }
        *reinterpret_cast<bf16x8*>(&hrow[lane * 64 + ((c ^ l7) << 3)]) = hv;
      }
      asm volatile("s_waitcnt lgkmcnt(0)" ::: "memory");
      floatx4 acc[4][4] = {};
#pragma unroll
      for (int i = 0; i < 4; i++) {
        int row = i * 16 + lr;
        bf16x8 a0 = *reinterpret_cast<const bf16x8*>(&hrow[row * 64 + ((quad ^ l7) << 3)]);
        bf16x8 a1 = *reinterpret_cast<const bf16x8*>(&hrow[row * 64 + (((4 + quad) ^ l7) << 3)]);
#pragma unroll
        for (int j = 0; j < 4; j++) {
          acc[i][j] = __builtin_amdgcn_mfma_f32_16x16x32_bf16(a0, bfr[j][0], acc[i][j], 0, 0, 0);
          acc[i][j] = __builtin_amdgcn_mfma_f32_16x16x32_bf16(a1, bfr[j][1], acc[i][j], 0, 0, 0);
        }
      }
#pragma unroll
      for (int i = 0; i < 4; i++)
#pragma unroll
        for (int j = 0; j < 4; j++) {
          floatx4 a = acc[i][j];
          lmax[j] = fmaxf(lmax[j], fmaxf(fmaxf(a[0], a[1]), fmaxf(a[2], a[3])));
        }
    }
#pragma unroll
    for (int j = 0; j < 4; j++) {
      lmax[j] = fmaxf(lmax[j], __shfl_xor(lmax[j], 16, 64));
      lmax[j] = fmaxf(lmax[j], __shfl_xor(lmax[j], 32, 64));
    }
    out[(size_t)node * 64 + lane] = f2b(lmax[quad] + b2v);
  }
}

// ------------------------------------------------------------- GEMM core
__device__ __forceinline__ void gemm_core(
    const unsigned short* __restrict__ A, int lda,
    const unsigned short* __restrict__ BT, int ldb,
    const float* __restrict__ bias,
    unsigned short* __restrict__ C, int ldc, int colOff, int K,
    int m0, int n0) {
  __shared__ __align__(16) unsigned short As[128 * 32];
  __shared__ __align__(16) unsigned short Bs[128 * 32];
  int tid = threadIdx.x;
  int lane = tid & 63, w = tid >> 6;
  int wm = (w >> 1) * 64, wn = (w & 1) * 64;
  int lr = lane & 15, quad = lane >> 4;
  floatx4 acc[4][4] = {};

  for (int k0 = 0; k0 < K; k0 += 32) {
    __syncthreads();
#pragma unroll
    for (int s = 0; s < 2; s++) {
      int cc = tid + s * 256;
      int row = cc >> 2, kc = (cc & 3) << 3;
      *reinterpret_cast<uint4*>(&As[row * 32 + kc]) =
          *reinterpret_cast<const uint4*>(&A[(size_t)(m0 + row) * lda + k0 + kc]);
      *reinterpret_cast<uint4*>(&Bs[row * 32 + kc]) =
          *reinterpret_cast<const uint4*>(&BT[(size_t)(n0 + row) * ldb + k0 + kc]);
    }
    __syncthreads();
    bf16x8 a[4], b[4];
#pragma unroll
    for (int i = 0; i < 4; i++)
      a[i] = *reinterpret_cast<const bf16x8*>(&As[(wm + i * 16 + lr) * 32 + quad * 8]);
#pragma unroll
    for (int j = 0; j < 4; j++)
      b[j] = *reinterpret_cast<const bf16x8*>(&Bs[(wn + j * 16 + lr) * 32 + quad * 8]);
#pragma unroll
    for (int i = 0; i < 4; i++)
#pragma unroll
      for (int j = 0; j < 4; j++)
        acc[i][j] = __builtin_amdgcn_mfma_f32_16x16x32_bf16(a[i], b[j], acc[i][j], 0, 0, 0);
  }
#pragma unroll
  for (int j = 0; j < 4; j++) {
    int gcol = n0 + wn + j * 16 + lr;
    float bv = bias ? bias[gcol] : 0.0f;
#pragma unroll
    for (int i = 0; i < 4; i++) {
#pragma unroll
      for (int r = 0; r < 4; r++) {
        int grow = m0 + wm + i * 16 + quad * 4 + r;
        C[(size_t)grow * ldc + colOff + gcol] = f2b(acc[i][j][r] + bv);
      }
    }
  }
}

// fold GEMMs: z=0 pos-w4, z=1 aff-w4, z=2 sem (N=512 -> skip bx>=4)
__global__ __launch_bounds__(256) void gemm_fold(const unsigned short* __restrict__ fusT,
                                                 const unsigned short* __restrict__ wB,
                                                 unsigned short* __restrict__ BTcat) {
  int z = blockIdx.z;
  if (z == 2 && blockIdx.x >= 4) return;
  gemm_core(fusT + z * 768, 2304, wB + (size_t)z * 589824, 768, nullptr,
            BTcat, 2048, z * 768, 768, blockIdx.y * 128, blockIdx.x * 128);
}

// w3 GEMM pair: z = branch
__global__ __launch_bounds__(256) void gemm_w3(const unsigned short* __restrict__ xgB,
                                               const unsigned short* __restrict__ w3T,
                                               const float* __restrict__ pb3,
                                               const float* __restrict__ ab3,
                                               unsigned short* __restrict__ t) {
  int z = blockIdx.z;
  gemm_core(xgB + (size_t)z * NN * 64, 64, w3T + (size_t)z * 768 * 64, 64,
            z ? ab3 : pb3, t + (size_t)z * NN * 768, 768, 0, 64,
            blockIdx.y * 128, blockIdx.x * 128);
}

// ----------------------- fused final GEMM: virtual K=2048 over 3 A sources
__global__ __launch_bounds__(256) void gemm_fuse3(
    const unsigned short* __restrict__ A0, const unsigned short* __restrict__ A1,
    const float* __restrict__ A2f, const unsigned short* __restrict__ BT,
    const float* __restrict__ bias, unsigned short* __restrict__ C) {
  __shared__ __align__(16) unsigned short As[128 * 32];
  __shared__ __align__(16) unsigned short Bs[128 * 32];
  int tid = threadIdx.x;
  int m0 = blockIdx.y * 128, n0 = blockIdx.x * 128;
  int lane = tid & 63, w = tid >> 6;
  int wm = (w >> 1) * 64, wn = (w & 1) * 64;
  int lr = lane & 15, quad = lane >> 4;
  floatx4 acc[4][4] = {};

  for (int k0 = 0; k0 < 2048; k0 += 32) {
    __syncthreads();
    if (k0 < 1536) {
      const unsigned short* Ap = (k0 < 768) ? A0 : A1;
      int kk = (k0 < 768) ? k0 : (k0 - 768);
#pragma unroll
      for (int s = 0; s < 2; s++) {
        int cc = tid + s * 256;
        int row = cc >> 2, kc = (cc & 3) << 3;
        *reinterpret_cast<uint4*>(&As[row * 32 + kc]) =
            *reinterpret_cast<const uint4*>(&Ap[(size_t)(m0 + row) * 768 + kk + kc]);
      }
    } else {
      int kk = k0 - 1536;
#pragma unroll
      for (int s = 0; s < 2; s++) {
        int cc = tid + s * 256;
        int row = cc >> 2, kc = (cc & 3) << 3;
        const float* src = &A2f[(size_t)(m0 + row) * 512 + kk + kc];
        float4 fa = *reinterpret_cast<const float4*>(src);
        float4 fb = *reinterpret_cast<const float4*>(src + 4);
        uint4 pk;
        pk.x = (unsigned)f2b(fa.x) | ((unsigned)f2b(fa.y) << 16);
        pk.y = (unsigned)f2b(fa.z) | ((unsigned)f2b(fa.w) << 16);
        pk.z = (unsigned)f2b(fb.x) | ((unsigned)f2b(fb.y) << 16);
        pk.w = (unsigned)f2b(fb.z) | ((unsigned)f2b(fb.w) << 16);
        *reinterpret_cast<uint4*>(&As[row * 32 + kc]) = pk;
      }
    }
#pragma unroll
    for (int s = 0; s < 2; s++) {
      int cc = tid + s * 256;
      int row = cc >> 2, kc = (cc & 3) << 3;
      *reinterpret_cast<uint4*>(&Bs[row * 32 + kc]) =
          *reinterpret_cast<const uint4*>(&BT[(size_t)(n0 + row) * 2048 + k0 + kc]);
    }
    __syncthreads();
    bf16x8 a[4], b[4];
#pragma unroll
    for (int i = 0; i < 4; i++)
      a[i] = *reinterpret_cast<const bf16x8*>(&As[(wm + i * 16 + lr) * 32 + quad * 8]);
#pragma unroll
    for (int j = 0; j < 4; j++)
      b[j] = *reinterpret_cast<const bf16x8*>(&Bs[(wn + j * 16 + lr) * 32 + quad * 8]);
#pragma unroll
    for (int i = 0; i < 4; i++)
#pragma unroll
      for (int j = 0; j < 4; j++)
        acc[i][j] = __builtin_amdgcn_mfma_f32_16x16x32_bf16(a[i], b[j], acc[i][j], 0, 0, 0);
  }
#pragma unroll
  for (int j = 0; j < 4; j++) {
    int gcol = n0 + wn + j * 16 + lr;
    float bv = bias[gcol];
#pragma unroll
    for (int i = 0; i < 4; i++) {
#pragma unroll
      for (int r = 0; r < 4; r++) {
        int grow = m0 + wm + i * 16 + quad * 4 + r;
        C[(size_t)grow * 768 + gcol] = f2b(acc[i][j][r] + bv);
      }
    }
  }
}

// ------------- fold all upstream biases into the fusion bias (f32 in/out)
__global__ __launch_bounds__(256) void fuse_bias(
    const float* __restrict__ fus_b, const float* __restrict__ fus_w,
    const float* __restrict__ pb4, const float* __restrict__ ab4,
    const float* __restrict__ semb, float* __restrict__ bias_tot) {
  int c = blockIdx.x;
  int tid = threadIdx.x;
  float s = 0.f;
  for (int j = tid; j < 768; j += 256) {
    s = fmaf(pb4[j],  fus_w[(size_t)j * 768 + c], s);
    s = fmaf(ab4[j],  fus_w[(size_t)(768 + j) * 768 + c], s);
    s = fmaf(semb[j], fus_w[(size_t)(1536 + j) * 768 + c], s);
  }
#pragma unroll
  for (int off = 32; off > 0; off >>= 1) s += __shfl_xor(s, off, 64);
  __shared__ float sm[4];
  if ((tid & 63) == 0) sm[tid >> 6] = s;
  __syncthreads();
  if (tid == 0) bias_tot[c] = sm[0] + sm[1] + sm[2] + sm[3] + fus_b[c];
}

// ----------------------- rowwise LN(768)+ReLU pair, bf16 in/out, y = branch
__global__ __launch_bounds__(256) void ln2(unsigned short* __restrict__ tB,
                                           const float* __restrict__ pg2,
                                           const float* __restrict__ pbe2,
                                           const float* __restrict__ ag2,
                                           const float* __restrict__ abe2) {
  int br = blockIdx.y;
  unsigned short* X = tB + (size_t)br * NN * 768;
  const float* g = br ? ag2 : pg2;
  const float* be = br ? abe2 : pbe2;
  int row = blockIdx.x, tid = threadIdx.x;
  size_t base = (size_t)row * 768;
  float xv[3];
#pragma unroll
  for (int i = 0; i < 3; i++) xv[i] = b2f(X[base + tid + i * 256]);
  float s = xv[0] + xv[1] + xv[2];
  float q = xv[0] * xv[0] + xv[1] * xv[1] + xv[2] * xv[2];
#pragma unroll
  for (int off = 32; off > 0; off >>= 1) {
    s += __shfl_xor(s, off, 64);
    q += __shfl_xor(q, off, 64);
  }
  __shared__ float ss[4], qq[4];
  int w = tid >> 6, lane = tid & 63;
  if (lane == 0) { ss[w] = s; qq[w] = q; }
  __syncthreads();
  s = ss[0] + ss[1] + ss[2] + ss[3];
  q = qq[0] + qq[1] + qq[2] + qq[3];
  float m = s * (1.0f / 768.0f);
  float v = fmaf(-m, m, q * (1.0f / 768.0f));
  float rstd = rsqrtf(v + EPS);
#pragma unroll
  for (int i = 0; i < 3; i++) {
    int c = tid + i * 256;
    float y = (xv[i] - m) * rstd * g[c] + be[c];
    X[base + c] = f2b(fmaxf(y, 0.0f));
  }
}

// ------------------------------------- rowwise LN(768)+ReLU, bf16 in/f32 out
__global__ __launch_bounds__(256) void ln_relu_768_f32(
    const unsigned short* __restrict__ X, const float* __restrict__ g,
    const float* __restrict__ be, float* __restrict__ Y) {
  int row = blockIdx.x, tid = threadIdx.x;
  size_t base = (size_t)row * 768;
  float xv[3];
#pragma unroll
  for (int i = 0; i < 3; i++) xv[i] = b2f(X[base + tid + i * 256]);
  float s = xv[0] + xv[1] + xv[2];
  float q = xv[0] * xv[0] + xv[1] * xv[1] + xv[2] * xv[2];
#pragma unroll
  for (int off = 32; off > 0; off >>= 1) {
    s += __shfl_xor(s, off, 64);
    q += __shfl_xor(q, off, 64);
  }
  __shared__ float ss[4], qq[4];
  int w = tid >> 6, lane = tid & 63;
  if (lane == 0) { ss[w] = s; qq[w] = q; }
  __syncthreads();
  s = ss[0] + ss[1] + ss[2] + ss[3];
  q = qq[0] + qq[1] + qq[2] + qq[3];
  float m = s * (1.0f / 768.0f);
  float v = fmaf(-m, m, q * (1.0f / 768.0f));
  float rstd = rsqrtf(v + EPS);
#pragma unroll
  for (int i = 0; i < 3; i++) {
    int c = tid + i * 256;
    float y = (xv[i] - m) * rstd * g[c] + be[c];
    Y[base + c] = fmaxf(y, 0.0f);
  }
}

extern "C" void kernel_launch(void* const* d_in, const int* in_sizes, int n_in,
                              void* d_out, int out_size, void* d_ws, size_t ws_size,
                              hipStream_t stream) {
  typedef const float* cf;
  cf x_pos = (cf)d_in[0];
  const int* pos_idx = (const int*)d_in[1];
  cf x_aff = (cf)d_in[2];
  const int* aff_idx = (const int*)d_in[3];
  cf x_sem = (cf)d_in[4];
  cf pw1 = (cf)d_in[6],  pb1 = (cf)d_in[7],  pg1 = (cf)d_in[8],  pbe1 = (cf)d_in[9];
  cf pw2 = (cf)d_in[10], pb2 = (cf)d_in[11];
  cf pw3 = (cf)d_in[12], pb3 = (cf)d_in[13], pg2 = (cf)d_in[14], pbe2 = (cf)d_in[15];
  cf pw4 = (cf)d_in[16], pb4 = (cf)d_in[17];
  cf aw1 = (cf)d_in[18], ab1 = (cf)d_in[19], ag1 = (cf)d_in[20], abe1 = (cf)d_in[21];
  cf aw2 = (cf)d_in[22], ab2 = (cf)d_in[23];
  cf aw3 = (cf)d_in[24], ab3 = (cf)d_in[25], ag2 = (cf)d_in[26], abe2 = (cf)d_in[27];
  cf aw4 = (cf)d_in[28], ab4 = (cf)d_in[29];
  cf semw = (cf)d_in[30], semb = (cf)d_in[31];
  cf fusw = (cf)d_in[32], fusb = (cf)d_in[33], fusg = (cf)d_in[34], fusbe = (cf)d_in[35];

  int P = in_sizes[0] / 3;

  char* wsb = (char*)d_ws;
  size_t off = 0;
  auto carve = [&](size_t bytes) -> void* {
    void* p = wsb + off;
    off = (off + bytes + 255) & ~(size_t)255;
    return p;
  };
  unsigned short* xgB   = (unsigned short*)carve((size_t)2 * NN * 64 * 2);   // 4 MiB
  unsigned short* t     = (unsigned short*)carve((size_t)2 * NN * 768 * 2);  // 48 MiB
  float4* sorted        = (float4*)carve((size_t)2 * P * 16);                // 32 MiB
  unsigned short* F = (unsigned short*)sorted;  // alias: sorted dead before fuse3
  unsigned short* w3T   = (unsigned short*)carve((size_t)2 * 768 * 64 * 2);
  unsigned short* fusT  = (unsigned short*)carve((size_t)768 * 2304 * 2);
  unsigned short* wB    = (unsigned short*)carve((size_t)1572864 * 2);       // pw4B|aw4B|semwB
  unsigned short* BTcat = (unsigned short*)carve((size_t)768 * 2048 * 2);
  unsigned short* w2T   = (unsigned short*)carve((size_t)2 * 4096 * 2);
  float* bias_tot = (float*)carve((size_t)768 * 4);
  float* G2  = (float*)carve((size_t)512 * 4);
  float* Mq2 = (float*)carve((size_t)32 * 4);
  unsigned* cnt  = (unsigned*)carve((size_t)2 * NN * 4);
  unsigned* offs = (unsigned*)carve((size_t)2 * (NN + 1) * 4);
  unsigned* cur  = (unsigned*)carve((size_t)2 * NN * 4);
  // total ~94 MiB

  zero_u32<<<(2 * NN + 255) / 256, 256, 0, stream>>>(cnt, 2 * NN);

  dim3 tb(32, 8);
  transpose_w3_pair<<<dim3(24, 2, 2), tb, 0, stream>>>(pw3, aw3, w3T);
  transpose_f32_b16<<<dim3(24, 72), tb, 0, stream>>>(fusw, fusT, 2304, 768);
  convert3<<<(1572864 + 255) / 256, 256, 0, stream>>>(pw4, 589824, aw4, 589824,
                                                      semw, 393216, wB);
  prep_pointnet2<<<2, 64, 0, stream>>>(pw1, pb1, pg1, aw1, ab1, ag1, pw2, aw2,
                                       G2, Mq2, w2T);

  gemm_fold<<<dim3(6, 6, 3), 256, 0, stream>>>(fusT, wB, BTcat);
  fuse_bias<<<768, 256, 0, stream>>>(fusb, fusw, pb4, ab4, semb, bias_tot);

  hist2<<<dim3(1024, 2), 256, 0, stream>>>(pos_idx, aff_idx, P, cnt);
  scan2<<<2, 1024, 0, stream>>>(cnt, offs, cur);
  scatter2<<<dim3(1024, 2), 256, 0, stream>>>(x_pos, x_aff, pos_idx, aff_idx, P, cur, sorted);
  node_mlp2<<<dim3(2048, 2), 256, 0, stream>>>(sorted, offs, G2, Mq2, pbe1, abe1,
                                               w2T, pb2, ab2, xgB, P);

  gemm_w3<<<dim3(6, NN / 128, 2), 256, 0, stream>>>(xgB, w3T, pb3, ab3, t);
  ln2<<<dim3(NN, 2), 256, 0, stream>>>(t, pg2, pbe2, ag2, abe2);

  gemm_fuse3<<<dim3(6, NN / 128), 256, 0, stream>>>(t, t + (size_t)NN * 768, x_sem,
                                                    BTcat, bias_tot, F);
  ln_relu_768_f32<<<NN, 256, 0, stream>>>(F, fusg, fusbe, (float*)d_out);
}

// Round 8
// 734.915 us; speedup vs baseline: 1.3883x; 1.0224x over previous
//
#include <hip/hip_runtime.h>

typedef __attribute__((ext_vector_type(8))) __bf16 bf16x8;
typedef __attribute__((ext_vector_type(4))) float floatx4;

#define NN 16384
#define EPS 1e-5f
#define NEG_HUGE -3.402823466e38f

__device__ __forceinline__ unsigned short f2b(float f) {
  unsigned u = __float_as_uint(f);
  u += 0x7fffu + ((u >> 16) & 1u);
  return (unsigned short)(u >> 16);
}
__device__ __forceinline__ float b2f(unsigned short u) {
  return __uint_as_float(((unsigned)u) << 16);
}

// kept for harness symbol expectations; never launched
__global__ void RoboNodeEncoder_88424786690347_kernel() {}

// ---------------------------------------------------------------- zero init
__global__ __launch_bounds__(256) void zero_u32(unsigned* __restrict__ p, int n) {
  int i = blockIdx.x * blockDim.x + threadIdx.x;
  if (i < n) p[i] = 0u;
}

// --------------------------- merged f32->bf16 casts (3 sources, contiguous dst)
__global__ __launch_bounds__(256) void convert3(const float* __restrict__ a, int na,
                                                const float* __restrict__ b, int nb,
                                                const float* __restrict__ c, int nc,
                                                unsigned short* __restrict__ out) {
  int i = blockIdx.x * 256 + threadIdx.x;
  int total = na + nb + nc;
  if (i >= total) return;
  float v;
  if (i < na) v = a[i];
  else if (i < na + nb) v = b[i - na];
  else v = c[i - na - nb];
  out[i] = f2b(v);
}

// --------------------------------------------------- f32 -> bf16 transpose
__global__ __launch_bounds__(256) void transpose_f32_b16(const float* __restrict__ in,
                                                         unsigned short* __restrict__ out,
                                                         int R, int C) {
  __shared__ float t[32][33];
  int bx = blockIdx.x * 32, by = blockIdx.y * 32;
  int x = threadIdx.x, y = threadIdx.y;
#pragma unroll
  for (int i = 0; i < 32; i += 8) t[y + i][x] = in[(size_t)(by + y + i) * C + bx + x];
  __syncthreads();
#pragma unroll
  for (int i = 0; i < 32; i += 8) out[(size_t)(bx + y + i) * R + by + x] = f2b(t[x][y + i]);
}

// ---------------- w3 transpose pair: z selects branch, out stride 768*64
__global__ __launch_bounds__(256) void transpose_w3_pair(const float* __restrict__ pw3,
                                                         const float* __restrict__ aw3,
                                                         unsigned short* __restrict__ w3T) {
  __shared__ float t[32][33];
  const float* in = blockIdx.z ? aw3 : pw3;
  unsigned short* out = w3T + (size_t)blockIdx.z * 768 * 64;
  int R = 64, C = 768;
  int bx = blockIdx.x * 32, by = blockIdx.y * 32;
  int x = threadIdx.x, y = threadIdx.y;
#pragma unroll
  for (int i = 0; i < 32; i += 8) t[y + i][x] = in[(size_t)(by + y + i) * C + bx + x];
  __syncthreads();
#pragma unroll
  for (int i = 0; i < 32; i += 8) out[(size_t)(bx + y + i) * R + by + x] = f2b(t[x][y + i]);
}

// ------------------- prep: fold LN of the point MLP into closed-form consts
// blockIdx.x = branch (0=pos,1=aff); 64 threads. Also emits bf16 w2^T
// (w2T[n*64+k] = w2[k][n]) so node_mlp2 B-frags are coalesced b128 loads.
__global__ void prep_pointnet2(const float* __restrict__ w1p, const float* __restrict__ b1p,
                               const float* __restrict__ g1p,
                               const float* __restrict__ w1a, const float* __restrict__ b1a,
                               const float* __restrict__ g1a,
                               const float* __restrict__ w2p, const float* __restrict__ w2a,
                               float* __restrict__ G2, float* __restrict__ Mq2,
                               unsigned short* __restrict__ w2T) {
  int br = blockIdx.x;
  const float* w1 = br ? w1a : w1p;
  const float* b1 = br ? b1a : b1p;
  const float* g1 = br ? g1a : g1p;
  const float* w2 = br ? w2a : w2p;
  float* G = G2 + br * 256;
  float* Mq = Mq2 + br * 16;
  unsigned short* w2t = w2T + br * 4096;
  int k = threadIdx.x;
  // w2 transpose to bf16: w2t[n][k] = w2[k][n]
#pragma unroll
  for (int n = 0; n < 64; n++) w2t[n * 64 + k] = f2b(w2[k * 64 + n]);
  float c[4] = {w1[k], w1[64 + k], w1[128 + k], b1[k]};
#pragma unroll
  for (int a = 0; a < 4; a++) {
    float s = c[a];
#pragma unroll
    for (int off = 32; off > 0; off >>= 1) s += __shfl_xor(s, off, 64);
    c[a] -= s * (1.f / 64.f);
  }
  float g = g1[k];
#pragma unroll
  for (int a = 0; a < 4; a++) G[a * 64 + k] = c[a] * g;
  const int AA[10] = {0, 1, 2, 3, 0, 0, 0, 1, 1, 2};
  const int BB[10] = {0, 1, 2, 3, 1, 2, 3, 2, 3, 3};
#pragma unroll
  for (int t = 0; t < 10; t++) {
    float s = c[AA[t]] * c[BB[t]];
#pragma unroll
    for (int off = 32; off > 0; off >>= 1) s += __shfl_xor(s, off, 64);
    s *= (1.f / 64.f);
    if (t >= 4) s *= 2.f;
    if (k == 0) Mq[t] = s;
  }
}

// ------------------------------------------- histogram, both branches (y)
__global__ __launch_bounds__(256) void hist2(const int* __restrict__ pos_idx,
                                             const int* __restrict__ aff_idx, int P,
                                             unsigned* __restrict__ cntB) {
  const int* idx = blockIdx.y ? aff_idx : pos_idx;
  unsigned* cnt = cntB + blockIdx.y * NN;
  int stride = gridDim.x * blockDim.x;
  for (int i = blockIdx.x * blockDim.x + threadIdx.x; i < P; i += stride)
    atomicAdd(&cnt[idx[i]], 1u);
}

// ---------------------- exclusive scan of 16384 counters; blockIdx.x = branch
__global__ __launch_bounds__(1024) void scan2(const unsigned* __restrict__ cntB,
                                              unsigned* __restrict__ offsB,
                                              unsigned* __restrict__ curB) {
  int br = blockIdx.x;
  const unsigned* cnt = cntB + br * NN;
  unsigned* offs = offsB + br * (NN + 1);
  unsigned* cursor = curB + br * NN;
  __shared__ unsigned ps[1024];
  int t = threadIdx.x;
  unsigned v[16];
  unsigned s = 0;
#pragma unroll
  for (int i = 0; i < 16; i++) { v[i] = cnt[t * 16 + i]; s += v[i]; }
  ps[t] = s;
  __syncthreads();
  for (int off = 1; off < 1024; off <<= 1) {
    unsigned add = (t >= off) ? ps[t - off] : 0u;
    __syncthreads();
    ps[t] += add;
    __syncthreads();
  }
  unsigned base = (t > 0) ? ps[t - 1] : 0u;
#pragma unroll
  for (int i = 0; i < 16; i++) {
    offs[t * 16 + i] = base;
    cursor[t * 16 + i] = base;
    base += v[i];
  }
  if (t == 1023) offs[NN] = base;
}

// ------------------------------- scatter into node order, both branches (y)
__global__ __launch_bounds__(256) void scatter2(const float* __restrict__ x_pos,
                                                const float* __restrict__ x_aff,
                                                const int* __restrict__ pos_idx,
                                                const int* __restrict__ aff_idx, int P,
                                                unsigned* __restrict__ curB,
                                                float4* __restrict__ sortedB) {
  int br = blockIdx.y;
  const float* x = br ? x_aff : x_pos;
  const int* idx = br ? aff_idx : pos_idx;
  unsigned* cursor = curB + br * NN;
  float4* sorted = sortedB + (size_t)br * P;
  int stride = gridDim.x * blockDim.x;
  for (int i = blockIdx.x * blockDim.x + threadIdx.x; i < P; i += stride) {
    int nd = idx[i];
    unsigned pos = atomicAdd(&cursor[nd], 1u);
    float4 v;
    v.x = x[3 * i]; v.y = x[3 * i + 1]; v.z = x[3 * i + 2]; v.w = 0.f;
    sorted[pos] = v;
  }
}

// ----------------- per-node: folded-LN MLP + MFMA 64x64 + in-register max
// wave per node, both branches via blockIdx.y. Per-row-group accumulators
// (16 regs live instead of 64) -> no spill under launch_bounds(256,4).
__global__ __launch_bounds__(256, 4) void node_mlp2(
    const float4* __restrict__ sortedB, const unsigned* __restrict__ offsB,
    const float* __restrict__ G2, const float* __restrict__ Mq2,
    const float* __restrict__ be1p, const float* __restrict__ be1a,
    const unsigned short* __restrict__ w2T,
    const float* __restrict__ b2p, const float* __restrict__ b2a,
    unsigned short* __restrict__ xgB, int P) {
  int br = blockIdx.y;
  const float4* sorted = sortedB + (size_t)br * P;
  const unsigned* offs = offsB + br * (NN + 1);
  const float* G = G2 + br * 256;
  const float* Mq = Mq2 + br * 16;
  const float* be1 = br ? be1a : be1p;
  const unsigned short* w2t = w2T + br * 4096;
  const float* b2 = br ? b2a : b2p;
  unsigned short* out = xgB + (size_t)br * NN * 64;

  __shared__ __align__(16) unsigned short hs[4][64 * 64];  // 8KB/wave
  int tid = threadIdx.x;
  int lane = tid & 63, w = tid >> 6;
  int lr = lane & 15, quad = lane >> 4;
  int l7 = lane & 7;

  // B frags: coalesced b128 loads from pre-transposed bf16 w2T (L2-hot)
  bf16x8 bfr[4][2];
#pragma unroll
  for (int j = 0; j < 4; j++)
#pragma unroll
    for (int s = 0; s < 2; s++)
      bfr[j][s] = *reinterpret_cast<const bf16x8*>(&w2t[(j * 16 + lr) * 64 + s * 32 + quad * 8]);
  float b2v = b2[lane];
  float M00 = Mq[0], M11 = Mq[1], M22 = Mq[2], M33 = Mq[3];
  float T01 = Mq[4], T02 = Mq[5], T03 = Mq[6], T12 = Mq[7], T13 = Mq[8], T23 = Mq[9];

  unsigned short* hrow = &hs[w][0];
  int gw = blockIdx.x * 4 + w;
  int nwv = gridDim.x * 4;
  for (int node = gw; node < NN; node += nwv) {
    unsigned seg0 = offs[node], seg1 = offs[node + 1];
    int cnt = (int)(seg1 - seg0);
    if (cnt == 0) { out[(size_t)node * 64 + lane] = 0; continue; }

    float lmax[4] = {NEG_HUGE, NEG_HUGE, NEG_HUGE, NEG_HUGE};
    for (int t0 = 0; t0 < cnt; t0 += 64) {
      int pi = t0 + lane;
      if (pi >= cnt) pi = cnt - 1;  // duplicate a real point: max-neutral
      float4 xv = sorted[seg0 + pi];
      float x0 = xv.x, x1 = xv.y, x2 = xv.z;
      float var = M33 + x0 * fmaf(M00, x0, fmaf(T01, x1, fmaf(T02, x2, T03)))
                      + x1 * fmaf(M11, x1, fmaf(T12, x2, T13))
                      + x2 * fmaf(M22, x2, T23);
      float rstd = rsqrtf(var + EPS);
      float x0r = x0 * rstd, x1r = x1 * rstd, x2r = x2 * rstd;
#pragma unroll
      for (int c = 0; c < 8; c++) {
        bf16x8 hv;
#pragma unroll
        for (int e = 0; e < 8; e++) {
          int k = c * 8 + e;
          float y = fmaf(x0r, G[k], fmaf(x1r, G[64 + k],
                    fmaf(x2r, G[128 + k], fmaf(rstd, G[192 + k], be1[k]))));
          hv[e] = (__bf16)fmaxf(y, 0.f);
        }
        *reinterpret_cast<bf16x8*>(&hrow[lane * 64 + ((c ^ l7) << 3)]) = hv;
      }
      asm volatile("s_waitcnt lgkmcnt(0)" ::: "memory");
      // per-row-group accumulation: only 4 floatx4 accs live at once
#pragma unroll
      for (int i = 0; i < 4; i++) {
        int row = i * 16 + lr;
        bf16x8 a0 = *reinterpret_cast<const bf16x8*>(&hrow[row * 64 + ((quad ^ l7) << 3)]);
        bf16x8 a1 = *reinterpret_cast<const bf16x8*>(&hrow[row * 64 + (((4 + quad) ^ l7) << 3)]);
        floatx4 accj[4] = {};
#pragma unroll
        for (int j = 0; j < 4; j++) {
          accj[j] = __builtin_amdgcn_mfma_f32_16x16x32_bf16(a0, bfr[j][0], accj[j], 0, 0, 0);
          accj[j] = __builtin_amdgcn_mfma_f32_16x16x32_bf16(a1, bfr[j][1], accj[j], 0, 0, 0);
        }
#pragma unroll
        for (int j = 0; j < 4; j++) {
          floatx4 a = accj[j];
          lmax[j] = fmaxf(lmax[j], fmaxf(fmaxf(a[0], a[1]), fmaxf(a[2], a[3])));
        }
      }
    }
#pragma unroll
    for (int j = 0; j < 4; j++) {
      lmax[j] = fmaxf(lmax[j], __shfl_xor(lmax[j], 16, 64));
      lmax[j] = fmaxf(lmax[j], __shfl_xor(lmax[j], 32, 64));
    }
    out[(size_t)node * 64 + lane] = f2b(lmax[quad] + b2v);
  }
}

// ------------------------------------------------------------- GEMM core
__device__ __forceinline__ void gemm_core(
    const unsigned short* __restrict__ A, int lda,
    const unsigned short* __restrict__ BT, int ldb,
    const float* __restrict__ bias,
    unsigned short* __restrict__ C, int ldc, int colOff, int K,
    int m0, int n0) {
  __shared__ __align__(16) unsigned short As[128 * 32];
  __shared__ __align__(16) unsigned short Bs[128 * 32];
  int tid = threadIdx.x;
  int lane = tid & 63, w = tid >> 6;
  int wm = (w >> 1) * 64, wn = (w & 1) * 64;
  int lr = lane & 15, quad = lane >> 4;
  floatx4 acc[4][4] = {};

  for (int k0 = 0; k0 < K; k0 += 32) {
    __syncthreads();
#pragma unroll
    for (int s = 0; s < 2; s++) {
      int cc = tid + s * 256;
      int row = cc >> 2, kc = (cc & 3) << 3;
      *reinterpret_cast<uint4*>(&As[row * 32 + kc]) =
          *reinterpret_cast<const uint4*>(&A[(size_t)(m0 + row) * lda + k0 + kc]);
      *reinterpret_cast<uint4*>(&Bs[row * 32 + kc]) =
          *reinterpret_cast<const uint4*>(&BT[(size_t)(n0 + row) * ldb + k0 + kc]);
    }
    __syncthreads();
    bf16x8 a[4], b[4];
#pragma unroll
    for (int i = 0; i < 4; i++)
      a[i] = *reinterpret_cast<const bf16x8*>(&As[(wm + i * 16 + lr) * 32 + quad * 8]);
#pragma unroll
    for (int j = 0; j < 4; j++)
      b[j] = *reinterpret_cast<const bf16x8*>(&Bs[(wn + j * 16 + lr) * 32 + quad * 8]);
#pragma unroll
    for (int i = 0; i < 4; i++)
#pragma unroll
      for (int j = 0; j < 4; j++)
        acc[i][j] = __builtin_amdgcn_mfma_f32_16x16x32_bf16(a[i], b[j], acc[i][j], 0, 0, 0);
  }
#pragma unroll
  for (int j = 0; j < 4; j++) {
    int gcol = n0 + wn + j * 16 + lr;
    float bv = bias ? bias[gcol] : 0.0f;
#pragma unroll
    for (int i = 0; i < 4; i++) {
#pragma unroll
      for (int r = 0; r < 4; r++) {
        int grow = m0 + wm + i * 16 + quad * 4 + r;
        C[(size_t)grow * ldc + colOff + gcol] = f2b(acc[i][j][r] + bv);
      }
    }
  }
}

// fold GEMMs: z=0 pos-w4, z=1 aff-w4, z=2 sem (N=512 -> skip bx>=4)
__global__ __launch_bounds__(256) void gemm_fold(const unsigned short* __restrict__ fusT,
                                                 const unsigned short* __restrict__ wB,
                                                 unsigned short* __restrict__ BTcat) {
  int z = blockIdx.z;
  if (z == 2 && blockIdx.x >= 4) return;
  gemm_core(fusT + z * 768, 2304, wB + (size_t)z * 589824, 768, nullptr,
            BTcat, 2048, z * 768, 768, blockIdx.y * 128, blockIdx.x * 128);
}

// w3 GEMM pair: z = branch
__global__ __launch_bounds__(256) void gemm_w3(const unsigned short* __restrict__ xgB,
                                               const unsigned short* __restrict__ w3T,
                                               const float* __restrict__ pb3,
                                               const float* __restrict__ ab3,
                                               unsigned short* __restrict__ t) {
  int z = blockIdx.z;
  gemm_core(xgB + (size_t)z * NN * 64, 64, w3T + (size_t)z * 768 * 64, 64,
            z ? ab3 : pb3, t + (size_t)z * NN * 768, 768, 0, 64,
            blockIdx.y * 128, blockIdx.x * 128);
}

// ----------------------- fused final GEMM: virtual K=2048 over 3 A sources
__global__ __launch_bounds__(256) void gemm_fuse3(
    const unsigned short* __restrict__ A0, const unsigned short* __restrict__ A1,
    const float* __restrict__ A2f, const unsigned short* __restrict__ BT,
    const float* __restrict__ bias, unsigned short* __restrict__ C) {
  __shared__ __align__(16) unsigned short As[128 * 32];
  __shared__ __align__(16) unsigned short Bs[128 * 32];
  int tid = threadIdx.x;
  int m0 = blockIdx.y * 128, n0 = blockIdx.x * 128;
  int lane = tid & 63, w = tid >> 6;
  int wm = (w >> 1) * 64, wn = (w & 1) * 64;
  int lr = lane & 15, quad = lane >> 4;
  floatx4 acc[4][4] = {};

  for (int k0 = 0; k0 < 2048; k0 += 32) {
    __syncthreads();
    if (k0 < 1536) {
      const unsigned short* Ap = (k0 < 768) ? A0 : A1;
      int kk = (k0 < 768) ? k0 : (k0 - 768);
#pragma unroll
      for (int s = 0; s < 2; s++) {
        int cc = tid + s * 256;
        int row = cc >> 2, kc = (cc & 3) << 3;
        *reinterpret_cast<uint4*>(&As[row * 32 + kc]) =
            *reinterpret_cast<const uint4*>(&Ap[(size_t)(m0 + row) * 768 + kk + kc]);
      }
    } else {
      int kk = k0 - 1536;
#pragma unroll
      for (int s = 0; s < 2; s++) {
        int cc = tid + s * 256;
        int row = cc >> 2, kc = (cc & 3) << 3;
        const float* src = &A2f[(size_t)(m0 + row) * 512 + kk + kc];
        float4 fa = *reinterpret_cast<const float4*>(src);
        float4 fb = *reinterpret_cast<const float4*>(src + 4);
        uint4 pk;
        pk.x = (unsigned)f2b(fa.x) | ((unsigned)f2b(fa.y) << 16);
        pk.y = (unsigned)f2b(fa.z) | ((unsigned)f2b(fa.w) << 16);
        pk.z = (unsigned)f2b(fb.x) | ((unsigned)f2b(fb.y) << 16);
        pk.w = (unsigned)f2b(fb.z) | ((unsigned)f2b(fb.w) << 16);
        *reinterpret_cast<uint4*>(&As[row * 32 + kc]) = pk;
      }
    }
#pragma unroll
    for (int s = 0; s < 2; s++) {
      int cc = tid + s * 256;
      int row = cc >> 2, kc = (cc & 3) << 3;
      *reinterpret_cast<uint4*>(&Bs[row * 32 + kc]) =
          *reinterpret_cast<const uint4*>(&BT[(size_t)(n0 + row) * 2048 + k0 + kc]);
    }
    __syncthreads();
    bf16x8 a[4], b[4];
#pragma unroll
    for (int i = 0; i < 4; i++)
      a[i] = *reinterpret_cast<const bf16x8*>(&As[(wm + i * 16 + lr) * 32 + quad * 8]);
#pragma unroll
    for (int j = 0; j < 4; j++)
      b[j] = *reinterpret_cast<const bf16x8*>(&Bs[(wn + j * 16 + lr) * 32 + quad * 8]);
#pragma unroll
    for (int i = 0; i < 4; i++)
#pragma unroll
      for (int j = 0; j < 4; j++)
        acc[i][j] = __builtin_amdgcn_mfma_f32_16x16x32_bf16(a[i], b[j], acc[i][j], 0, 0, 0);
  }
#pragma unroll
  for (int j = 0; j < 4; j++) {
    int gcol = n0 + wn + j * 16 + lr;
    float bv = bias[gcol];
#pragma unroll
    for (int i = 0; i < 4; i++) {
#pragma unroll
      for (int r = 0; r < 4; r++) {
        int grow = m0 + wm + i * 16 + quad * 4 + r;
        C[(size_t)grow * 768 + gcol] = f2b(acc[i][j][r] + bv);
      }
    }
  }
}

// ------------- fold all upstream biases into the fusion bias (f32 in/out)
__global__ __launch_bounds__(256) void fuse_bias(
    const float* __restrict__ fus_b, const float* __restrict__ fus_w,
    const float* __restrict__ pb4, const float* __restrict__ ab4,
    const float* __restrict__ semb, float* __restrict__ bias_tot) {
  int c = blockIdx.x;
  int tid = threadIdx.x;
  float s = 0.f;
  for (int j = tid; j < 768; j += 256) {
    s = fmaf(pb4[j],  fus_w[(size_t)j * 768 + c], s);
    s = fmaf(ab4[j],  fus_w[(size_t)(768 + j) * 768 + c], s);
    s = fmaf(semb[j], fus_w[(size_t)(1536 + j) * 768 + c], s);
  }
#pragma unroll
  for (int off = 32; off > 0; off >>= 1) s += __shfl_xor(s, off, 64);
  __shared__ float sm[4];
  if ((tid & 63) == 0) sm[tid >> 6] = s;
  __syncthreads();
  if (tid == 0) bias_tot[c] = sm[0] + sm[1] + sm[2] + sm[3] + fus_b[c];
}

// ----------------------- rowwise LN(768)+ReLU pair, bf16 in/out, y = branch
__global__ __launch_bounds__(256) void ln2(unsigned short* __restrict__ tB,
                                           const float* __restrict__ pg2,
                                           const float* __restrict__ pbe2,
                                           const float* __restrict__ ag2,
                                           const float* __restrict__ abe2) {
  int br = blockIdx.y;
  unsigned short* X = tB + (size_t)br * NN * 768;
  const float* g = br ? ag2 : pg2;
  const float* be = br ? abe2 : pbe2;
  int row = blockIdx.x, tid = threadIdx.x;
  size_t base = (size_t)row * 768;
  float xv[3];
#pragma unroll
  for (int i = 0; i < 3; i++) xv[i] = b2f(X[base + tid + i * 256]);
  float s = xv[0] + xv[1] + xv[2];
  float q = xv[0] * xv[0] + xv[1] * xv[1] + xv[2] * xv[2];
#pragma unroll
  for (int off = 32; off > 0; off >>= 1) {
    s += __shfl_xor(s, off, 64);
    q += __shfl_xor(q, off, 64);
  }
  __shared__ float ss[4], qq[4];
  int w = tid >> 6, lane = tid & 63;
  if (lane == 0) { ss[w] = s; qq[w] = q; }
  __syncthreads();
  s = ss[0] + ss[1] + ss[2] + ss[3];
  q = qq[0] + qq[1] + qq[2] + qq[3];
  float m = s * (1.0f / 768.0f);
  float v = fmaf(-m, m, q * (1.0f / 768.0f));
  float rstd = rsqrtf(v + EPS);
#pragma unroll
  for (int i = 0; i < 3; i++) {
    int c = tid + i * 256;
    float y = (xv[i] - m) * rstd * g[c] + be[c];
    X[base + c] = f2b(fmaxf(y, 0.0f));
  }
}

// ------------------------------------- rowwise LN(768)+ReLU, bf16 in/f32 out
__global__ __launch_bounds__(256) void ln_relu_768_f32(
    const unsigned short* __restrict__ X, const float* __restrict__ g,
    const float* __restrict__ be, float* __restrict__ Y) {
  int row = blockIdx.x, tid = threadIdx.x;
  size_t base = (size_t)row * 768;
  float xv[3];
#pragma unroll
  for (int i = 0; i < 3; i++) xv[i] = b2f(X[base + tid + i * 256]);
  float s = xv[0] + xv[1] + xv[2];
  float q = xv[0] * xv[0] + xv[1] * xv[1] + xv[2] * xv[2];
#pragma unroll
  for (int off = 32; off > 0; off >>= 1) {
    s += __shfl_xor(s, off, 64);
    q += __shfl_xor(q, off, 64);
  }
  __shared__ float ss[4], qq[4];
  int w = tid >> 6, lane = tid & 63;
  if (lane == 0) { ss[w] = s; qq[w] = q; }
  __syncthreads();
  s = ss[0] + ss[1] + ss[2] + ss[3];
  q = qq[0] + qq[1] + qq[2] + qq[3];
  float m = s * (1.0f / 768.0f);
  float v = fmaf(-m, m, q * (1.0f / 768.0f));
  float rstd = rsqrtf(v + EPS);
#pragma unroll
  for (int i = 0; i < 3; i++) {
    int c = tid + i * 256;
    float y = (xv[i] - m) * rstd * g[c] + be[c];
    Y[base + c] = fmaxf(y, 0.0f);
  }
}

extern "C" void kernel_launch(void* const* d_in, const int* in_sizes, int n_in,
                              void* d_out, int out_size, void* d_ws, size_t ws_size,
                              hipStream_t stream) {
  typedef const float* cf;
  cf x_pos = (cf)d_in[0];
  const int* pos_idx = (const int*)d_in[1];
  cf x_aff = (cf)d_in[2];
  const int* aff_idx = (const int*)d_in[3];
  cf x_sem = (cf)d_in[4];
  cf pw1 = (cf)d_in[6],  pb1 = (cf)d_in[7],  pg1 = (cf)d_in[8],  pbe1 = (cf)d_in[9];
  cf pw2 = (cf)d_in[10], pb2 = (cf)d_in[11];
  cf pw3 = (cf)d_in[12], pb3 = (cf)d_in[13], pg2 = (cf)d_in[14], pbe2 = (cf)d_in[15];
  cf pw4 = (cf)d_in[16], pb4 = (cf)d_in[17];
  cf aw1 = (cf)d_in[18], ab1 = (cf)d_in[19], ag1 = (cf)d_in[20], abe1 = (cf)d_in[21];
  cf aw2 = (cf)d_in[22], ab2 = (cf)d_in[23];
  cf aw3 = (cf)d_in[24], ab3 = (cf)d_in[25], ag2 = (cf)d_in[26], abe2 = (cf)d_in[27];
  cf aw4 = (cf)d_in[28], ab4 = (cf)d_in[29];
  cf semw = (cf)d_in[30], semb = (cf)d_in[31];
  cf fusw = (cf)d_in[32], fusb = (cf)d_in[33], fusg = (cf)d_in[34], fusbe = (cf)d_in[35];

  int P = in_sizes[0] / 3;

  char* wsb = (char*)d_ws;
  size_t off = 0;
  auto carve = [&](size_t bytes) -> void* {
    void* p = wsb + off;
    off = (off + bytes + 255) & ~(size_t)255;
    return p;
  };
  unsigned short* xgB   = (unsigned short*)carve((size_t)2 * NN * 64 * 2);   // 4 MiB
  unsigned short* t     = (unsigned short*)carve((size_t)2 * NN * 768 * 2);  // 48 MiB
  float4* sorted        = (float4*)carve((size_t)2 * P * 16);                // 32 MiB
  unsigned short* F = (unsigned short*)sorted;  // alias: sorted dead before fuse3
  unsigned short* w3T   = (unsigned short*)carve((size_t)2 * 768 * 64 * 2);
  unsigned short* fusT  = (unsigned short*)carve((size_t)768 * 2304 * 2);
  unsigned short* wB    = (unsigned short*)carve((size_t)1572864 * 2);       // pw4B|aw4B|semwB
  unsigned short* BTcat = (unsigned short*)carve((size_t)768 * 2048 * 2);
  unsigned short* w2T   = (unsigned short*)carve((size_t)2 * 4096 * 2);
  float* bias_tot = (float*)carve((size_t)768 * 4);
  float* G2  = (float*)carve((size_t)512 * 4);
  float* Mq2 = (float*)carve((size_t)32 * 4);
  unsigned* cnt  = (unsigned*)carve((size_t)2 * NN * 4);
  unsigned* offs = (unsigned*)carve((size_t)2 * (NN + 1) * 4);
  unsigned* cur  = (unsigned*)carve((size_t)2 * NN * 4);
  // total ~94 MiB

  zero_u32<<<(2 * NN + 255) / 256, 256, 0, stream>>>(cnt, 2 * NN);

  dim3 tb(32, 8);
  transpose_w3_pair<<<dim3(24, 2, 2), tb, 0, stream>>>(pw3, aw3, w3T);
  transpose_f32_b16<<<dim3(24, 72), tb, 0, stream>>>(fusw, fusT, 2304, 768);
  convert3<<<(1572864 + 255) / 256, 256, 0, stream>>>(pw4, 589824, aw4, 589824,
                                                      semw, 393216, wB);
  prep_pointnet2<<<2, 64, 0, stream>>>(pw1, pb1, pg1, aw1, ab1, ag1, pw2, aw2,
                                       G2, Mq2, w2T);

  gemm_fold<<<dim3(6, 6, 3), 256, 0, stream>>>(fusT, wB, BTcat);
  fuse_bias<<<768, 256, 0, stream>>>(fusb, fusw, pb4, ab4, semb, bias_tot);

  hist2<<<dim3(1024, 2), 256, 0, stream>>>(pos_idx, aff_idx, P, cnt);
  scan2<<<2, 1024, 0, stream>>>(cnt, offs, cur);
  scatter2<<<dim3(1024, 2), 256, 0, stream>>>(x_pos, x_aff, pos_idx, aff_idx, P, cur, sorted);
  node_mlp2<<<dim3(2048, 2), 256, 0, stream>>>(sorted, offs, G2, Mq2, pbe1, abe1,
                                               w2T, pb2, ab2, xgB, P);

  gemm_w3<<<dim3(6, NN / 128, 2), 256, 0, stream>>>(xgB, w3T, pb3, ab3, t);
  ln2<<<dim3(NN, 2), 256, 0, stream>>>(t, pg2, pbe2, ag2, abe2);

  gemm_fuse3<<<dim3(6, NN / 128), 256, 0, stream>>>(t, t + (size_t)NN * 768, x_sem,
                                                    BTcat, bias_tot, F);
  ln_relu_768_f32<<<NN, 256, 0, stream>>>(F, fusg, fusbe, (float*)d_out);
}

// Round 9
// 520.274 us; speedup vs baseline: 1.9611x; 1.4126x over previous
//
#include <hip/hip_runtime.h>

typedef __attribute__((ext_vector_type(8))) __bf16 bf16x8;
typedef __attribute__((ext_vector_type(4))) float floatx4;

#define NN 16384
#define EPS 1e-5f

__device__ __forceinline__ unsigned short f2b(float f) {
  unsigned u = __float_as_uint(f);
  u += 0x7fffu + ((u >> 16) & 1u);
  return (unsigned short)(u >> 16);
}
__device__ __forceinline__ float b2f(unsigned short u) {
  return __uint_as_float(((unsigned)u) << 16);
}

// kept for harness symbol expectations; never launched
__global__ void RoboNodeEncoder_88424786690347_kernel() {}

// ---------------------------------------------------------------- zero init
__global__ __launch_bounds__(256) void zero_u32(unsigned* __restrict__ p, int n) {
  int i = blockIdx.x * blockDim.x + threadIdx.x;
  if (i < n) p[i] = 0u;
}

// --------------------------- merged f32->bf16 casts (3 sources, contiguous dst)
__global__ __launch_bounds__(256) void convert3(const float* __restrict__ a, int na,
                                                const float* __restrict__ b, int nb,
                                                const float* __restrict__ c, int nc,
                                                unsigned short* __restrict__ out) {
  int i = blockIdx.x * 256 + threadIdx.x;
  int total = na + nb + nc;
  if (i >= total) return;
  float v;
  if (i < na) v = a[i];
  else if (i < na + nb) v = b[i - na];
  else v = c[i - na - nb];
  out[i] = f2b(v);
}

// --------------------------------------------------- f32 -> bf16 transpose
__global__ __launch_bounds__(256) void transpose_f32_b16(const float* __restrict__ in,
                                                         unsigned short* __restrict__ out,
                                                         int R, int C) {
  __shared__ float t[32][33];
  int bx = blockIdx.x * 32, by = blockIdx.y * 32;
  int x = threadIdx.x, y = threadIdx.y;
#pragma unroll
  for (int i = 0; i < 32; i += 8) t[y + i][x] = in[(size_t)(by + y + i) * C + bx + x];
  __syncthreads();
#pragma unroll
  for (int i = 0; i < 32; i += 8) out[(size_t)(bx + y + i) * R + by + x] = f2b(t[x][y + i]);
}

// ---------------- w3 transpose pair: z selects branch, out stride 768*64
__global__ __launch_bounds__(256) void transpose_w3_pair(const float* __restrict__ pw3,
                                                         const float* __restrict__ aw3,
                                                         unsigned short* __restrict__ w3T) {
  __shared__ float t[32][33];
  const float* in = blockIdx.z ? aw3 : pw3;
  unsigned short* out = w3T + (size_t)blockIdx.z * 768 * 64;
  int R = 64, C = 768;
  int bx = blockIdx.x * 32, by = blockIdx.y * 32;
  int x = threadIdx.x, y = threadIdx.y;
#pragma unroll
  for (int i = 0; i < 32; i += 8) t[y + i][x] = in[(size_t)(by + y + i) * C + bx + x];
  __syncthreads();
#pragma unroll
  for (int i = 0; i < 32; i += 8) out[(size_t)(bx + y + i) * R + by + x] = f2b(t[x][y + i]);
}

// ------------------- prep: fold LN of the point MLP into closed-form consts
// blockIdx.x = branch; 64 threads. Also emits bf16 w2^T for coalesced B-frags.
__global__ void prep_pointnet2(const float* __restrict__ w1p, const float* __restrict__ b1p,
                               const float* __restrict__ g1p,
                               const float* __restrict__ w1a, const float* __restrict__ b1a,
                               const float* __restrict__ g1a,
                               const float* __restrict__ w2p, const float* __restrict__ w2a,
                               float* __restrict__ G2, float* __restrict__ Mq2,
                               unsigned short* __restrict__ w2T) {
  int br = blockIdx.x;
  const float* w1 = br ? w1a : w1p;
  const float* b1 = br ? b1a : b1p;
  const float* g1 = br ? g1a : g1p;
  const float* w2 = br ? w2a : w2p;
  float* G = G2 + br * 256;
  float* Mq = Mq2 + br * 16;
  unsigned short* w2t = w2T + br * 4096;
  int k = threadIdx.x;
#pragma unroll
  for (int n = 0; n < 64; n++) w2t[n * 64 + k] = f2b(w2[k * 64 + n]);
  float c[4] = {w1[k], w1[64 + k], w1[128 + k], b1[k]};
#pragma unroll
  for (int a = 0; a < 4; a++) {
    float s = c[a];
#pragma unroll
    for (int off = 32; off > 0; off >>= 1) s += __shfl_xor(s, off, 64);
    c[a] -= s * (1.f / 64.f);
  }
  float g = g1[k];
#pragma unroll
  for (int a = 0; a < 4; a++) G[a * 64 + k] = c[a] * g;
  const int AA[10] = {0, 1, 2, 3, 0, 0, 0, 1, 1, 2};
  const int BB[10] = {0, 1, 2, 3, 1, 2, 3, 2, 3, 3};
#pragma unroll
  for (int t = 0; t < 10; t++) {
    float s = c[AA[t]] * c[BB[t]];
#pragma unroll
    for (int off = 32; off > 0; off >>= 1) s += __shfl_xor(s, off, 64);
    s *= (1.f / 64.f);
    if (t >= 4) s *= 2.f;
    if (k == 0) Mq[t] = s;
  }
}

// --------------------- bucket histogram (bucket = node>>5, 512 buckets/branch)
__global__ __launch_bounds__(256) void hist_bucket(const int* __restrict__ pos_idx,
                                                   const int* __restrict__ aff_idx, int P,
                                                   unsigned* __restrict__ cntB) {
  __shared__ unsigned lc[512];
  int br = blockIdx.y;
  const int* idx = br ? aff_idx : pos_idx;
  for (int i = threadIdx.x; i < 512; i += 256) lc[i] = 0u;
  __syncthreads();
  int stride = gridDim.x * blockDim.x;
  for (int i = blockIdx.x * blockDim.x + threadIdx.x; i < P; i += stride)
    atomicAdd(&lc[idx[i] >> 5], 1u);
  __syncthreads();
  for (int i = threadIdx.x; i < 512; i += 256)
    if (lc[i]) atomicAdd(&cntB[br * 512 + i], lc[i]);
}

// ------------------------- exclusive scan of 512 buckets; blockIdx.x = branch
__global__ __launch_bounds__(512) void scan_bucket(const unsigned* __restrict__ cntB,
                                                   unsigned* __restrict__ offsB,
                                                   unsigned* __restrict__ curB) {
  int br = blockIdx.x;
  __shared__ unsigned ps[512];
  int t = threadIdx.x;
  unsigned v = cntB[br * 512 + t];
  ps[t] = v;
  __syncthreads();
  for (int off = 1; off < 512; off <<= 1) {
    unsigned a = (t >= off) ? ps[t - off] : 0u;
    __syncthreads();
    ps[t] += a;
    __syncthreads();
  }
  unsigned excl = ps[t] - v;
  offsB[br * 513 + t] = excl;
  curB[br * 512 + t] = excl;
  if (t == 511) offsB[br * 513 + 512] = ps[t];
}

// ---------------- bucket scatter: per-block LDS count -> reserve -> scatter.
// Writes to a bucket from one block are contiguous -> L2 merges lines.
__global__ __launch_bounds__(256) void bucket_scatter(
    const float* __restrict__ x_pos, const float* __restrict__ x_aff,
    const int* __restrict__ pos_idx, const int* __restrict__ aff_idx, int P,
    unsigned* __restrict__ curB, float4* __restrict__ sortedB) {
  __shared__ unsigned lcnt[512], lbase[512];
  int br = blockIdx.y;
  const float* x = br ? x_aff : x_pos;
  const int* idx = br ? aff_idx : pos_idx;
  float4* sorted = sortedB + (size_t)br * P;
  int nb = gridDim.x;
  int chunk = (P + nb - 1) / nb;
  int start = blockIdx.x * chunk;
  int end = start + chunk;
  if (end > P) end = P;
  for (int i = threadIdx.x; i < 512; i += 256) lcnt[i] = 0u;
  __syncthreads();
  for (int i = start + threadIdx.x; i < end; i += 256)
    atomicAdd(&lcnt[idx[i] >> 5], 1u);
  __syncthreads();
  for (int i = threadIdx.x; i < 512; i += 256) {
    unsigned c = lcnt[i];
    lbase[i] = c ? atomicAdd(&curB[br * 512 + i], c) : 0u;
  }
  __syncthreads();
  for (int i = threadIdx.x; i < 512; i += 256) lcnt[i] = 0u;
  __syncthreads();
  for (int i = start + threadIdx.x; i < end; i += 256) {
    int nd = idx[i];
    int b = nd >> 5;
    unsigned lo = atomicAdd(&lcnt[b], 1u);
    float4 v;
    v.x = x[3 * i]; v.y = x[3 * i + 1]; v.z = x[3 * i + 2];
    v.w = __int_as_float(nd & 31);
    sorted[lbase[b] + lo] = v;
  }
}

// ---------- per-bucket: folded-LN MLP + MFMA + LDS atomicMax per node-feature
// one block per 32-node bucket; coalesced point reads; no per-node padding.
__global__ __launch_bounds__(256) void bucket_mlp_max(
    const float4* __restrict__ sortedB, const unsigned* __restrict__ offsB,
    const float* __restrict__ G2, const float* __restrict__ Mq2,
    const float* __restrict__ be1p, const float* __restrict__ be1a,
    const unsigned short* __restrict__ w2T,
    const float* __restrict__ b2p, const float* __restrict__ b2a,
    unsigned short* __restrict__ xgB, int P) {
  __shared__ __align__(16) unsigned short hs[4][64 * 64];  // 32 KB
  __shared__ int ndl[4][64];                               // 1 KB
  __shared__ unsigned nmaxU[32 * 64];                      // 8 KB
  int br = blockIdx.y;
  int bucket = blockIdx.x;
  const float4* sorted = sortedB + (size_t)br * P;
  const unsigned* offs = offsB + br * 513;
  const float* G = G2 + br * 256;
  const float* Mq = Mq2 + br * 16;
  const float* be1 = br ? be1a : be1p;
  const unsigned short* w2t = w2T + br * 4096;
  const float* b2 = br ? b2a : b2p;
  unsigned short* out = xgB + (size_t)br * NN * 64;

  int tid = threadIdx.x;
  int lane = tid & 63, w = tid >> 6;
  int lr = lane & 15, quad = lane >> 4;
  int l7 = lane & 7;

  for (int e = tid; e < 2048; e += 256) nmaxU[e] = 0u;

  bf16x8 bfr[4][2];
#pragma unroll
  for (int j = 0; j < 4; j++)
#pragma unroll
    for (int s = 0; s < 2; s++)
      bfr[j][s] = *reinterpret_cast<const bf16x8*>(&w2t[(j * 16 + lr) * 64 + s * 32 + quad * 8]);
  float M00 = Mq[0], M11 = Mq[1], M22 = Mq[2], M33 = Mq[3];
  float T01 = Mq[4], T02 = Mq[5], T03 = Mq[6], T12 = Mq[7], T13 = Mq[8], T23 = Mq[9];
  __syncthreads();

  int seg0 = (int)offs[bucket], seg1 = (int)offs[bucket + 1];
  unsigned short* hrow = &hs[w][0];
  for (int t0 = seg0 + w * 64; t0 < seg1; t0 += 256) {
    int pi = t0 + lane;
    if (pi >= seg1) pi = seg1 - 1;  // duplicate a real point: max-neutral
    float4 xv = sorted[pi];
    float x0 = xv.x, x1 = xv.y, x2 = xv.z;
    ndl[w][lane] = __float_as_int(xv.w);
    float var = M33 + x0 * fmaf(M00, x0, fmaf(T01, x1, fmaf(T02, x2, T03)))
                    + x1 * fmaf(M11, x1, fmaf(T12, x2, T13))
                    + x2 * fmaf(M22, x2, T23);
    float rstd = rsqrtf(var + EPS);
    float x0r = x0 * rstd, x1r = x1 * rstd, x2r = x2 * rstd;
#pragma unroll
    for (int c = 0; c < 8; c++) {
      bf16x8 hv;
#pragma unroll
      for (int e = 0; e < 8; e++) {
        int k = c * 8 + e;
        float y = fmaf(x0r, G[k], fmaf(x1r, G[64 + k],
                  fmaf(x2r, G[128 + k], fmaf(rstd, G[192 + k], be1[k]))));
        hv[e] = (__bf16)fmaxf(y, 0.f);
      }
      *reinterpret_cast<bf16x8*>(&hrow[lane * 64 + ((c ^ l7) << 3)]) = hv;
    }
    asm volatile("s_waitcnt lgkmcnt(0)" ::: "memory");
#pragma unroll
    for (int i = 0; i < 4; i++) {
      int row = i * 16 + lr;
      bf16x8 a0 = *reinterpret_cast<const bf16x8*>(&hrow[row * 64 + ((quad ^ l7) << 3)]);
      bf16x8 a1 = *reinterpret_cast<const bf16x8*>(&hrow[row * 64 + (((4 + quad) ^ l7) << 3)]);
      floatx4 accj[4] = {};
#pragma unroll
      for (int j = 0; j < 4; j++) {
        accj[j] = __builtin_amdgcn_mfma_f32_16x16x32_bf16(a0, bfr[j][0], accj[j], 0, 0, 0);
        accj[j] = __builtin_amdgcn_mfma_f32_16x16x32_bf16(a1, bfr[j][1], accj[j], 0, 0, 0);
      }
      int nd0 = ndl[w][i * 16 + quad * 4 + 0];
      int nd1 = ndl[w][i * 16 + quad * 4 + 1];
      int nd2 = ndl[w][i * 16 + quad * 4 + 2];
      int nd3 = ndl[w][i * 16 + quad * 4 + 3];
#pragma unroll
      for (int j = 0; j < 4; j++) {
        int col = j * 16 + lr;
#pragma unroll
        for (int r = 0; r < 4; r++) {
          unsigned u = __float_as_uint(accj[j][r]);
          unsigned ord = (u & 0x80000000u) ? ~u : (u | 0x80000000u);
          int nd = (r == 0) ? nd0 : (r == 1) ? nd1 : (r == 2) ? nd2 : nd3;
          atomicMax(&nmaxU[nd * 64 + col], ord);
        }
      }
    }
  }
  __syncthreads();
  for (int e = tid; e < 2048; e += 256) {
    unsigned u = nmaxU[e];
    int f = e & 63;
    float val;
    if (u == 0u) val = 0.f;  // empty node
    else {
      float m = (u & 0x80000000u) ? __uint_as_float(u ^ 0x80000000u) : __uint_as_float(~u);
      val = m + b2[f];
    }
    out[(size_t)(bucket * 32 + (e >> 6)) * 64 + f] = f2b(val);
  }
}

// ------------------------------------------------------------- GEMM core
__device__ __forceinline__ void gemm_core(
    const unsigned short* __restrict__ A, int lda,
    const unsigned short* __restrict__ BT, int ldb,
    const float* __restrict__ bias,
    unsigned short* __restrict__ C, int ldc, int colOff, int K,
    int m0, int n0) {
  __shared__ __align__(16) unsigned short As[128 * 32];
  __shared__ __align__(16) unsigned short Bs[128 * 32];
  int tid = threadIdx.x;
  int lane = tid & 63, w = tid >> 6;
  int wm = (w >> 1) * 64, wn = (w & 1) * 64;
  int lr = lane & 15, quad = lane >> 4;
  floatx4 acc[4][4] = {};

  for (int k0 = 0; k0 < K; k0 += 32) {
    __syncthreads();
#pragma unroll
    for (int s = 0; s < 2; s++) {
      int cc = tid + s * 256;
      int row = cc >> 2, kc = (cc & 3) << 3;
      *reinterpret_cast<uint4*>(&As[row * 32 + kc]) =
          *reinterpret_cast<const uint4*>(&A[(size_t)(m0 + row) * lda + k0 + kc]);
      *reinterpret_cast<uint4*>(&Bs[row * 32 + kc]) =
          *reinterpret_cast<const uint4*>(&BT[(size_t)(n0 + row) * ldb + k0 + kc]);
    }
    __syncthreads();
    bf16x8 a[4], b[4];
#pragma unroll
    for (int i = 0; i < 4; i++)
      a[i] = *reinterpret_cast<const bf16x8*>(&As[(wm + i * 16 + lr) * 32 + quad * 8]);
#pragma unroll
    for (int j = 0; j < 4; j++)
      b[j] = *reinterpret_cast<const bf16x8*>(&Bs[(wn + j * 16 + lr) * 32 + quad * 8]);
#pragma unroll
    for (int i = 0; i < 4; i++)
#pragma unroll
      for (int j = 0; j < 4; j++)
        acc[i][j] = __builtin_amdgcn_mfma_f32_16x16x32_bf16(a[i], b[j], acc[i][j], 0, 0, 0);
  }
#pragma unroll
  for (int j = 0; j < 4; j++) {
    int gcol = n0 + wn + j * 16 + lr;
    float bv = bias ? bias[gcol] : 0.0f;
#pragma unroll
    for (int i = 0; i < 4; i++) {
#pragma unroll
      for (int r = 0; r < 4; r++) {
        int grow = m0 + wm + i * 16 + quad * 4 + r;
        C[(size_t)grow * ldc + colOff + gcol] = f2b(acc[i][j][r] + bv);
      }
    }
  }
}

// fold GEMMs: z=0 pos-w4, z=1 aff-w4, z=2 sem (N=512 -> skip bx>=4)
__global__ __launch_bounds__(256) void gemm_fold(const unsigned short* __restrict__ fusT,
                                                 const unsigned short* __restrict__ wB,
                                                 unsigned short* __restrict__ BTcat) {
  int z = blockIdx.z;
  if (z == 2 && blockIdx.x >= 4) return;
  gemm_core(fusT + z * 768, 2304, wB + (size_t)z * 589824, 768, nullptr,
            BTcat, 2048, z * 768, 768, blockIdx.y * 128, blockIdx.x * 128);
}

// w3 GEMM pair: z = branch
__global__ __launch_bounds__(256) void gemm_w3(const unsigned short* __restrict__ xgB,
                                               const unsigned short* __restrict__ w3T,
                                               const float* __restrict__ pb3,
                                               const float* __restrict__ ab3,
                                               unsigned short* __restrict__ t) {
  int z = blockIdx.z;
  gemm_core(xgB + (size_t)z * NN * 64, 64, w3T + (size_t)z * 768 * 64, 64,
            z ? ab3 : pb3, t + (size_t)z * NN * 768, 768, 0, 64,
            blockIdx.y * 128, blockIdx.x * 128);
}

// ----------------------- fused final GEMM: virtual K=2048 over 3 A sources
__global__ __launch_bounds__(256) void gemm_fuse3(
    const unsigned short* __restrict__ A0, const unsigned short* __restrict__ A1,
    const float* __restrict__ A2f, const unsigned short* __restrict__ BT,
    const float* __restrict__ bias, unsigned short* __restrict__ C) {
  __shared__ __align__(16) unsigned short As[128 * 32];
  __shared__ __align__(16) unsigned short Bs[128 * 32];
  int tid = threadIdx.x;
  int m0 = blockIdx.y * 128, n0 = blockIdx.x * 128;
  int lane = tid & 63, w = tid >> 6;
  int wm = (w >> 1) * 64, wn = (w & 1) * 64;
  int lr = lane & 15, quad = lane >> 4;
  floatx4 acc[4][4] = {};

  for (int k0 = 0; k0 < 2048; k0 += 32) {
    __syncthreads();
    if (k0 < 1536) {
      const unsigned short* Ap = (k0 < 768) ? A0 : A1;
      int kk = (k0 < 768) ? k0 : (k0 - 768);
#pragma unroll
      for (int s = 0; s < 2; s++) {
        int cc = tid + s * 256;
        int row = cc >> 2, kc = (cc & 3) << 3;
        *reinterpret_cast<uint4*>(&As[row * 32 + kc]) =
            *reinterpret_cast<const uint4*>(&Ap[(size_t)(m0 + row) * 768 + kk + kc]);
      }
    } else {
      int kk = k0 - 1536;
#pragma unroll
      for (int s = 0; s < 2; s++) {
        int cc = tid + s * 256;
        int row = cc >> 2, kc = (cc & 3) << 3;
        const float* src = &A2f[(size_t)(m0 + row) * 512 + kk + kc];
        float4 fa = *reinterpret_cast<const float4*>(src);
        float4 fb = *reinterpret_cast<const float4*>(src + 4);
        uint4 pk;
        pk.x = (unsigned)f2b(fa.x) | ((unsigned)f2b(fa.y) << 16);
        pk.y = (unsigned)f2b(fa.z) | ((unsigned)f2b(fa.w) << 16);
        pk.z = (unsigned)f2b(fb.x) | ((unsigned)f2b(fb.y) << 16);
        pk.w = (unsigned)f2b(fb.z) | ((unsigned)f2b(fb.w) << 16);
        *reinterpret_cast<uint4*>(&As[row * 32 + kc]) = pk;
      }
    }
#pragma unroll
    for (int s = 0; s < 2; s++) {
      int cc = tid + s * 256;
      int row = cc >> 2, kc = (cc & 3) << 3;
      *reinterpret_cast<uint4*>(&Bs[row * 32 + kc]) =
          *reinterpret_cast<const uint4*>(&BT[(size_t)(n0 + row) * 2048 + k0 + kc]);
    }
    __syncthreads();
    bf16x8 a[4], b[4];
#pragma unroll
    for (int i = 0; i < 4; i++)
      a[i] = *reinterpret_cast<const bf16x8*>(&As[(wm + i * 16 + lr) * 32 + quad * 8]);
#pragma unroll
    for (int j = 0; j < 4; j++)
      b[j] = *reinterpret_cast<const bf16x8*>(&Bs[(wn + j * 16 + lr) * 32 + quad * 8]);
#pragma unroll
    for (int i = 0; i < 4; i++)
#pragma unroll
      for (int j = 0; j < 4; j++)
        acc[i][j] = __builtin_amdgcn_mfma_f32_16x16x32_bf16(a[i], b[j], acc[i][j], 0, 0, 0);
  }
#pragma unroll
  for (int j = 0; j < 4; j++) {
    int gcol = n0 + wn + j * 16 + lr;
    float bv = bias[gcol];
#pragma unroll
    for (int i = 0; i < 4; i++) {
#pragma unroll
      for (int r = 0; r < 4; r++) {
        int grow = m0 + wm + i * 16 + quad * 4 + r;
        C[(size_t)grow * 768 + gcol] = f2b(acc[i][j][r] + bv);
      }
    }
  }
}

// ------------- fold all upstream biases into the fusion bias (f32 in/out)
__global__ __launch_bounds__(256) void fuse_bias(
    const float* __restrict__ fus_b, const float* __restrict__ fus_w,
    const float* __restrict__ pb4, const float* __restrict__ ab4,
    const float* __restrict__ semb, float* __restrict__ bias_tot) {
  int c = blockIdx.x;
  int tid = threadIdx.x;
  float s = 0.f;
  for (int j = tid; j < 768; j += 256) {
    s = fmaf(pb4[j],  fus_w[(size_t)j * 768 + c], s);
    s = fmaf(ab4[j],  fus_w[(size_t)(768 + j) * 768 + c], s);
    s = fmaf(semb[j], fus_w[(size_t)(1536 + j) * 768 + c], s);
  }
#pragma unroll
  for (int off = 32; off > 0; off >>= 1) s += __shfl_xor(s, off, 64);
  __shared__ float sm[4];
  if ((tid & 63) == 0) sm[tid >> 6] = s;
  __syncthreads();
  if (tid == 0) bias_tot[c] = sm[0] + sm[1] + sm[2] + sm[3] + fus_b[c];
}

// ----------------------- rowwise LN(768)+ReLU pair, bf16 in/out, y = branch
__global__ __launch_bounds__(256) void ln2(unsigned short* __restrict__ tB,
                                           const float* __restrict__ pg2,
                                           const float* __restrict__ pbe2,
                                           const float* __restrict__ ag2,
                                           const float* __restrict__ abe2) {
  int br = blockIdx.y;
  unsigned short* X = tB + (size_t)br * NN * 768;
  const float* g = br ? ag2 : pg2;
  const float* be = br ? abe2 : pbe2;
  int row = blockIdx.x, tid = threadIdx.x;
  size_t base = (size_t)row * 768;
  float xv[3];
#pragma unroll
  for (int i = 0; i < 3; i++) xv[i] = b2f(X[base + tid + i * 256]);
  float s = xv[0] + xv[1] + xv[2];
  float q = xv[0] * xv[0] + xv[1] * xv[1] + xv[2] * xv[2];
#pragma unroll
  for (int off = 32; off > 0; off >>= 1) {
    s += __shfl_xor(s, off, 64);
    q += __shfl_xor(q, off, 64);
  }
  __shared__ float ss[4], qq[4];
  int w = tid >> 6, lane = tid & 63;
  if (lane == 0) { ss[w] = s; qq[w] = q; }
  __syncthreads();
  s = ss[0] + ss[1] + ss[2] + ss[3];
  q = qq[0] + qq[1] + qq[2] + qq[3];
  float m = s * (1.0f / 768.0f);
  float v = fmaf(-m, m, q * (1.0f / 768.0f));
  float rstd = rsqrtf(v + EPS);
#pragma unroll
  for (int i = 0; i < 3; i++) {
    int c = tid + i * 256;
    float y = (xv[i] - m) * rstd * g[c] + be[c];
    X[base + c] = f2b(fmaxf(y, 0.0f));
  }
}

// ------------------------------------- rowwise LN(768)+ReLU, bf16 in/f32 out
__global__ __launch_bounds__(256) void ln_relu_768_f32(
    const unsigned short* __restrict__ X, const float* __restrict__ g,
    const float* __restrict__ be, float* __restrict__ Y) {
  int row = blockIdx.x, tid = threadIdx.x;
  size_t base = (size_t)row * 768;
  float xv[3];
#pragma unroll
  for (int i = 0; i < 3; i++) xv[i] = b2f(X[base + tid + i * 256]);
  float s = xv[0] + xv[1] + xv[2];
  float q = xv[0] * xv[0] + xv[1] * xv[1] + xv[2] * xv[2];
#pragma unroll
  for (int off = 32; off > 0; off >>= 1) {
    s += __shfl_xor(s, off, 64);
    q += __shfl_xor(q, off, 64);
  }
  __shared__ float ss[4], qq[4];
  int w = tid >> 6, lane = tid & 63;
  if (lane == 0) { ss[w] = s; qq[w] = q; }
  __syncthreads();
  s = ss[0] + ss[1] + ss[2] + ss[3];
  q = qq[0] + qq[1] + qq[2] + qq[3];
  float m = s * (1.0f / 768.0f);
  float v = fmaf(-m, m, q * (1.0f / 768.0f));
  float rstd = rsqrtf(v + EPS);
#pragma unroll
  for (int i = 0; i < 3; i++) {
    int c = tid + i * 256;
    float y = (xv[i] - m) * rstd * g[c] + be[c];
    Y[base + c] = fmaxf(y, 0.0f);
  }
}

extern "C" void kernel_launch(void* const* d_in, const int* in_sizes, int n_in,
                              void* d_out, int out_size, void* d_ws, size_t ws_size,
                              hipStream_t stream) {
  typedef const float* cf;
  cf x_pos = (cf)d_in[0];
  const int* pos_idx = (const int*)d_in[1];
  cf x_aff = (cf)d_in[2];
  const int* aff_idx = (const int*)d_in[3];
  cf x_sem = (cf)d_in[4];
  cf pw1 = (cf)d_in[6],  pb1 = (cf)d_in[7],  pg1 = (cf)d_in[8],  pbe1 = (cf)d_in[9];
  cf pw2 = (cf)d_in[10], pb2 = (cf)d_in[11];
  cf pw3 = (cf)d_in[12], pb3 = (cf)d_in[13], pg2 = (cf)d_in[14], pbe2 = (cf)d_in[15];
  cf pw4 = (cf)d_in[16], pb4 = (cf)d_in[17];
  cf aw1 = (cf)d_in[18], ab1 = (cf)d_in[19], ag1 = (cf)d_in[20], abe1 = (cf)d_in[21];
  cf aw2 = (cf)d_in[22], ab2 = (cf)d_in[23];
  cf aw3 = (cf)d_in[24], ab3 = (cf)d_in[25], ag2 = (cf)d_in[26], abe2 = (cf)d_in[27];
  cf aw4 = (cf)d_in[28], ab4 = (cf)d_in[29];
  cf semw = (cf)d_in[30], semb = (cf)d_in[31];
  cf fusw = (cf)d_in[32], fusb = (cf)d_in[33], fusg = (cf)d_in[34], fusbe = (cf)d_in[35];

  int P = in_sizes[0] / 3;

  char* wsb = (char*)d_ws;
  size_t off = 0;
  auto carve = [&](size_t bytes) -> void* {
    void* p = wsb + off;
    off = (off + bytes + 255) & ~(size_t)255;
    return p;
  };
  unsigned short* xgB   = (unsigned short*)carve((size_t)2 * NN * 64 * 2);   // 4 MiB
  unsigned short* t     = (unsigned short*)carve((size_t)2 * NN * 768 * 2);  // 48 MiB
  float4* sorted        = (float4*)carve((size_t)2 * P * 16);                // 32 MiB
  unsigned short* F = (unsigned short*)sorted;  // alias: sorted dead before fuse3
  unsigned short* w3T   = (unsigned short*)carve((size_t)2 * 768 * 64 * 2);
  unsigned short* fusT  = (unsigned short*)carve((size_t)768 * 2304 * 2);
  unsigned short* wB    = (unsigned short*)carve((size_t)1572864 * 2);       // pw4B|aw4B|semwB
  unsigned short* BTcat = (unsigned short*)carve((size_t)768 * 2048 * 2);
  unsigned short* w2T   = (unsigned short*)carve((size_t)2 * 4096 * 2);
  float* bias_tot = (float*)carve((size_t)768 * 4);
  float* G2  = (float*)carve((size_t)512 * 4);
  float* Mq2 = (float*)carve((size_t)32 * 4);
  unsigned* bcnt  = (unsigned*)carve((size_t)2 * 512 * 4);
  unsigned* boffs = (unsigned*)carve((size_t)2 * 513 * 4);
  unsigned* bcur  = (unsigned*)carve((size_t)2 * 512 * 4);
  // total ~94 MiB

  zero_u32<<<(1024 + 255) / 256, 256, 0, stream>>>(bcnt, 1024);

  dim3 tb(32, 8);
  transpose_w3_pair<<<dim3(24, 2, 2), tb, 0, stream>>>(pw3, aw3, w3T);
  transpose_f32_b16<<<dim3(24, 72), tb, 0, stream>>>(fusw, fusT, 2304, 768);
  convert3<<<(1572864 + 255) / 256, 256, 0, stream>>>(pw4, 589824, aw4, 589824,
                                                      semw, 393216, wB);
  prep_pointnet2<<<2, 64, 0, stream>>>(pw1, pb1, pg1, aw1, ab1, ag1, pw2, aw2,
                                       G2, Mq2, w2T);

  gemm_fold<<<dim3(6, 6, 3), 256, 0, stream>>>(fusT, wB, BTcat);
  fuse_bias<<<768, 256, 0, stream>>>(fusb, fusw, pb4, ab4, semb, bias_tot);

  // bucket counting sort (32 nodes/bucket) + per-bucket MFMA reduce
  hist_bucket<<<dim3(64, 2), 256, 0, stream>>>(pos_idx, aff_idx, P, bcnt);
  scan_bucket<<<2, 512, 0, stream>>>(bcnt, boffs, bcur);
  bucket_scatter<<<dim3(256, 2), 256, 0, stream>>>(x_pos, x_aff, pos_idx, aff_idx,
                                                   P, bcur, sorted);
  bucket_mlp_max<<<dim3(512, 2), 256, 0, stream>>>(sorted, boffs, G2, Mq2, pbe1, abe1,
                                                   w2T, pb2, ab2, xgB, P);

  gemm_w3<<<dim3(6, NN / 128, 2), 256, 0, stream>>>(xgB, w3T, pb3, ab3, t);
  ln2<<<dim3(NN, 2), 256, 0, stream>>>(t, pg2, pbe2, ag2, abe2);

  gemm_fuse3<<<dim3(6, NN / 128), 256, 0, stream>>>(t, t + (size_t)NN * 768, x_sem,
                                                    BTcat, bias_tot, F);
  ln_relu_768_f32<<<NN, 256, 0, stream>>>(F, fusg, fusbe, (float*)d_out);
}

// Round 10
// 518.184 us; speedup vs baseline: 1.9690x; 1.0040x over previous
//
#include <hip/hip_runtime.h>

typedef __attribute__((ext_vector_type(8))) __bf16 bf16x8;
typedef __attribute__((ext_vector_type(4))) float floatx4;

#define NN 16384
#define EPS 1e-5f

__device__ __forceinline__ unsigned short f2b(float f) {
  unsigned u = __float_as_uint(f);
  u += 0x7fffu + ((u >> 16) & 1u);
  return (unsigned short)(u >> 16);
}
__device__ __forceinline__ float b2f(unsigned short u) {
  return __uint_as_float(((unsigned)u) << 16);
}

// kept for harness symbol expectations; never launched
__global__ void RoboNodeEncoder_88424786690347_kernel() {}

// ---------------------------------------------------------------- zero init
__global__ __launch_bounds__(256) void zero_u32(unsigned* __restrict__ p, int n) {
  int i = blockIdx.x * blockDim.x + threadIdx.x;
  if (i < n) p[i] = 0u;
}

// --------------------------- merged f32->bf16 casts (3 sources, contiguous dst)
__global__ __launch_bounds__(256) void convert3(const float* __restrict__ a, int na,
                                                const float* __restrict__ b, int nb,
                                                const float* __restrict__ c, int nc,
                                                unsigned short* __restrict__ out) {
  int i = blockIdx.x * 256 + threadIdx.x;
  int total = na + nb + nc;
  if (i >= total) return;
  float v;
  if (i < na) v = a[i];
  else if (i < na + nb) v = b[i - na];
  else v = c[i - na - nb];
  out[i] = f2b(v);
}

// --------------------------------------------------- f32 -> bf16 transpose
__global__ __launch_bounds__(256) void transpose_f32_b16(const float* __restrict__ in,
                                                         unsigned short* __restrict__ out,
                                                         int R, int C) {
  __shared__ float t[32][33];
  int bx = blockIdx.x * 32, by = blockIdx.y * 32;
  int x = threadIdx.x, y = threadIdx.y;
#pragma unroll
  for (int i = 0; i < 32; i += 8) t[y + i][x] = in[(size_t)(by + y + i) * C + bx + x];
  __syncthreads();
#pragma unroll
  for (int i = 0; i < 32; i += 8) out[(size_t)(bx + y + i) * R + by + x] = f2b(t[x][y + i]);
}

// ---------------- w3 transpose pair: z selects branch, out stride 768*64
__global__ __launch_bounds__(256) void transpose_w3_pair(const float* __restrict__ pw3,
                                                         const float* __restrict__ aw3,
                                                         unsigned short* __restrict__ w3T) {
  __shared__ float t[32][33];
  const float* in = blockIdx.z ? aw3 : pw3;
  unsigned short* out = w3T + (size_t)blockIdx.z * 768 * 64;
  int R = 64, C = 768;
  int bx = blockIdx.x * 32, by = blockIdx.y * 32;
  int x = threadIdx.x, y = threadIdx.y;
#pragma unroll
  for (int i = 0; i < 32; i += 8) t[y + i][x] = in[(size_t)(by + y + i) * C + bx + x];
  __syncthreads();
#pragma unroll
  for (int i = 0; i < 32; i += 8) out[(size_t)(bx + y + i) * R + by + x] = f2b(t[x][y + i]);
}

// ------------------- prep: fold LN of the point MLP into closed-form consts
__global__ void prep_pointnet2(const float* __restrict__ w1p, const float* __restrict__ b1p,
                               const float* __restrict__ g1p,
                               const float* __restrict__ w1a, const float* __restrict__ b1a,
                               const float* __restrict__ g1a,
                               const float* __restrict__ w2p, const float* __restrict__ w2a,
                               float* __restrict__ G2, float* __restrict__ Mq2,
                               unsigned short* __restrict__ w2T) {
  int br = blockIdx.x;
  const float* w1 = br ? w1a : w1p;
  const float* b1 = br ? b1a : b1p;
  const float* g1 = br ? g1a : g1p;
  const float* w2 = br ? w2a : w2p;
  float* G = G2 + br * 256;
  float* Mq = Mq2 + br * 16;
  unsigned short* w2t = w2T + br * 4096;
  int k = threadIdx.x;
#pragma unroll
  for (int n = 0; n < 64; n++) w2t[n * 64 + k] = f2b(w2[k * 64 + n]);
  float c[4] = {w1[k], w1[64 + k], w1[128 + k], b1[k]};
#pragma unroll
  for (int a = 0; a < 4; a++) {
    float s = c[a];
#pragma unroll
    for (int off = 32; off > 0; off >>= 1) s += __shfl_xor(s, off, 64);
    c[a] -= s * (1.f / 64.f);
  }
  float g = g1[k];
#pragma unroll
  for (int a = 0; a < 4; a++) G[a * 64 + k] = c[a] * g;
  const int AA[10] = {0, 1, 2, 3, 0, 0, 0, 1, 1, 2};
  const int BB[10] = {0, 1, 2, 3, 1, 2, 3, 2, 3, 3};
#pragma unroll
  for (int t = 0; t < 10; t++) {
    float s = c[AA[t]] * c[BB[t]];
#pragma unroll
    for (int off = 32; off > 0; off >>= 1) s += __shfl_xor(s, off, 64);
    s *= (1.f / 64.f);
    if (t >= 4) s *= 2.f;
    if (k == 0) Mq[t] = s;
  }
}

// --------------------- bucket histogram (bucket = node>>5, 512 buckets/branch)
__global__ __launch_bounds__(256) void hist_bucket(const int* __restrict__ pos_idx,
                                                   const int* __restrict__ aff_idx, int P,
                                                   unsigned* __restrict__ cntB) {
  __shared__ unsigned lc[512];
  int br = blockIdx.y;
  const int* idx = br ? aff_idx : pos_idx;
  for (int i = threadIdx.x; i < 512; i += 256) lc[i] = 0u;
  __syncthreads();
  int stride = gridDim.x * blockDim.x;
  for (int i = blockIdx.x * blockDim.x + threadIdx.x; i < P; i += stride)
    atomicAdd(&lc[idx[i] >> 5], 1u);
  __syncthreads();
  for (int i = threadIdx.x; i < 512; i += 256)
    if (lc[i]) atomicAdd(&cntB[br * 512 + i], lc[i]);
}

// ------------------------- exclusive scan of 512 buckets; blockIdx.x = branch
__global__ __launch_bounds__(512) void scan_bucket(const unsigned* __restrict__ cntB,
                                                   unsigned* __restrict__ offsB,
                                                   unsigned* __restrict__ curB) {
  int br = blockIdx.x;
  __shared__ unsigned ps[512];
  int t = threadIdx.x;
  unsigned v = cntB[br * 512 + t];
  ps[t] = v;
  __syncthreads();
  for (int off = 1; off < 512; off <<= 1) {
    unsigned a = (t >= off) ? ps[t - off] : 0u;
    __syncthreads();
    ps[t] += a;
    __syncthreads();
  }
  unsigned excl = ps[t] - v;
  offsB[br * 513 + t] = excl;
  curB[br * 512 + t] = excl;
  if (t == 511) offsB[br * 513 + 512] = ps[t];
}

// ---------------- bucket scatter: per-block LDS count -> reserve -> scatter.
__global__ __launch_bounds__(256) void bucket_scatter(
    const float* __restrict__ x_pos, const float* __restrict__ x_aff,
    const int* __restrict__ pos_idx, const int* __restrict__ aff_idx, int P,
    unsigned* __restrict__ curB, float4* __restrict__ sortedB) {
  __shared__ unsigned lcnt[512], lbase[512];
  int br = blockIdx.y;
  const float* x = br ? x_aff : x_pos;
  const int* idx = br ? aff_idx : pos_idx;
  float4* sorted = sortedB + (size_t)br * P;
  int nb = gridDim.x;
  int chunk = (P + nb - 1) / nb;
  int start = blockIdx.x * chunk;
  int end = start + chunk;
  if (end > P) end = P;
  for (int i = threadIdx.x; i < 512; i += 256) lcnt[i] = 0u;
  __syncthreads();
  for (int i = start + threadIdx.x; i < end; i += 256)
    atomicAdd(&lcnt[idx[i] >> 5], 1u);
  __syncthreads();
  for (int i = threadIdx.x; i < 512; i += 256) {
    unsigned c = lcnt[i];
    lbase[i] = c ? atomicAdd(&curB[br * 512 + i], c) : 0u;
  }
  __syncthreads();
  for (int i = threadIdx.x; i < 512; i += 256) lcnt[i] = 0u;
  __syncthreads();
  for (int i = start + threadIdx.x; i < end; i += 256) {
    int nd = idx[i];
    int b = nd >> 5;
    unsigned lo = atomicAdd(&lcnt[b], 1u);
    float4 v;
    v.x = x[3 * i]; v.y = x[3 * i + 1]; v.z = x[3 * i + 2];
    v.w = __int_as_float(nd & 31);
    sorted[lbase[b] + lo] = v;
  }
}

// ---------- per-bucket: folded-LN MLP + MFMA + LDS atomicMax per node-feature
__global__ __launch_bounds__(256) void bucket_mlp_max(
    const float4* __restrict__ sortedB, const unsigned* __restrict__ offsB,
    const float* __restrict__ G2, const float* __restrict__ Mq2,
    const float* __restrict__ be1p, const float* __restrict__ be1a,
    const unsigned short* __restrict__ w2T,
    const float* __restrict__ b2p, const float* __restrict__ b2a,
    unsigned short* __restrict__ xgB, int P) {
  __shared__ __align__(16) unsigned short hs[4][64 * 64];  // 32 KB
  __shared__ int ndl[4][64];                               // 1 KB
  __shared__ unsigned nmaxU[32 * 64];                      // 8 KB
  int br = blockIdx.y;
  int bucket = blockIdx.x;
  const float4* sorted = sortedB + (size_t)br * P;
  const unsigned* offs = offsB + br * 513;
  const float* G = G2 + br * 256;
  const float* Mq = Mq2 + br * 16;
  const float* be1 = br ? be1a : be1p;
  const unsigned short* w2t = w2T + br * 4096;
  const float* b2 = br ? b2a : b2p;
  unsigned short* out = xgB + (size_t)br * NN * 64;

  int tid = threadIdx.x;
  int lane = tid & 63, w = tid >> 6;
  int lr = lane & 15, quad = lane >> 4;
  int l7 = lane & 7;

  for (int e = tid; e < 2048; e += 256) nmaxU[e] = 0u;

  bf16x8 bfr[4][2];
#pragma unroll
  for (int j = 0; j < 4; j++)
#pragma unroll
    for (int s = 0; s < 2; s++)
      bfr[j][s] = *reinterpret_cast<const bf16x8*>(&w2t[(j * 16 + lr) * 64 + s * 32 + quad * 8]);
  float M00 = Mq[0], M11 = Mq[1], M22 = Mq[2], M33 = Mq[3];
  float T01 = Mq[4], T02 = Mq[5], T03 = Mq[6], T12 = Mq[7], T13 = Mq[8], T23 = Mq[9];
  __syncthreads();

  int seg0 = (int)offs[bucket], seg1 = (int)offs[bucket + 1];
  unsigned short* hrow = &hs[w][0];
  for (int t0 = seg0 + w * 64; t0 < seg1; t0 += 256) {
    int pi = t0 + lane;
    if (pi >= seg1) pi = seg1 - 1;  // duplicate a real point: max-neutral
    float4 xv = sorted[pi];
    float x0 = xv.x, x1 = xv.y, x2 = xv.z;
    ndl[w][lane] = __float_as_int(xv.w);
    float var = M33 + x0 * fmaf(M00, x0, fmaf(T01, x1, fmaf(T02, x2, T03)))
                    + x1 * fmaf(M11, x1, fmaf(T12, x2, T13))
                    + x2 * fmaf(M22, x2, T23);
    float rstd = rsqrtf(var + EPS);
    float x0r = x0 * rstd, x1r = x1 * rstd, x2r = x2 * rstd;
#pragma unroll
    for (int c = 0; c < 8; c++) {
      bf16x8 hv;
#pragma unroll
      for (int e = 0; e < 8; e++) {
        int k = c * 8 + e;
        float y = fmaf(x0r, G[k], fmaf(x1r, G[64 + k],
                  fmaf(x2r, G[128 + k], fmaf(rstd, G[192 + k], be1[k]))));
        hv[e] = (__bf16)fmaxf(y, 0.f);
      }
      *reinterpret_cast<bf16x8*>(&hrow[lane * 64 + ((c ^ l7) << 3)]) = hv;
    }
    asm volatile("s_waitcnt lgkmcnt(0)" ::: "memory");
#pragma unroll
    for (int i = 0; i < 4; i++) {
      int row = i * 16 + lr;
      bf16x8 a0 = *reinterpret_cast<const bf16x8*>(&hrow[row * 64 + ((quad ^ l7) << 3)]);
      bf16x8 a1 = *reinterpret_cast<const bf16x8*>(&hrow[row * 64 + (((4 + quad) ^ l7) << 3)]);
      floatx4 accj[4] = {};
#pragma unroll
      for (int j = 0; j < 4; j++) {
        accj[j] = __builtin_amdgcn_mfma_f32_16x16x32_bf16(a0, bfr[j][0], accj[j], 0, 0, 0);
        accj[j] = __builtin_amdgcn_mfma_f32_16x16x32_bf16(a1, bfr[j][1], accj[j], 0, 0, 0);
      }
      int nd0 = ndl[w][i * 16 + quad * 4 + 0];
      int nd1 = ndl[w][i * 16 + quad * 4 + 1];
      int nd2 = ndl[w][i * 16 + quad * 4 + 2];
      int nd3 = ndl[w][i * 16 + quad * 4 + 3];
#pragma unroll
      for (int j = 0; j < 4; j++) {
        int col = j * 16 + lr;
#pragma unroll
        for (int r = 0; r < 4; r++) {
          unsigned u = __float_as_uint(accj[j][r]);
          unsigned ord = (u & 0x80000000u) ? ~u : (u | 0x80000000u);
          int nd = (r == 0) ? nd0 : (r == 1) ? nd1 : (r == 2) ? nd2 : nd3;
          atomicMax(&nmaxU[nd * 64 + col], ord);
        }
      }
    }
  }
  __syncthreads();
  for (int e = tid; e < 2048; e += 256) {
    unsigned u = nmaxU[e];
    int f = e & 63;
    float val;
    if (u == 0u) val = 0.f;  // empty node
    else {
      float m = (u & 0x80000000u) ? __uint_as_float(u ^ 0x80000000u) : __uint_as_float(~u);
      val = m + b2[f];
    }
    out[(size_t)(bucket * 32 + (e >> 6)) * 64 + f] = f2b(val);
  }
}

// ------------------------------------------------------------- GEMM core
__device__ __forceinline__ void gemm_core(
    const unsigned short* __restrict__ A, int lda,
    const unsigned short* __restrict__ BT, int ldb,
    const float* __restrict__ bias,
    unsigned short* __restrict__ C, int ldc, int colOff, int K,
    int m0, int n0) {
  __shared__ __align__(16) unsigned short As[128 * 32];
  __shared__ __align__(16) unsigned short Bs[128 * 32];
  int tid = threadIdx.x;
  int lane = tid & 63, w = tid >> 6;
  int wm = (w >> 1) * 64, wn = (w & 1) * 64;
  int lr = lane & 15, quad = lane >> 4;
  floatx4 acc[4][4] = {};

  for (int k0 = 0; k0 < K; k0 += 32) {
    __syncthreads();
#pragma unroll
    for (int s = 0; s < 2; s++) {
      int cc = tid + s * 256;
      int row = cc >> 2, kc = (cc & 3) << 3;
      *reinterpret_cast<uint4*>(&As[row * 32 + kc]) =
          *reinterpret_cast<const uint4*>(&A[(size_t)(m0 + row) * lda + k0 + kc]);
      *reinterpret_cast<uint4*>(&Bs[row * 32 + kc]) =
          *reinterpret_cast<const uint4*>(&BT[(size_t)(n0 + row) * ldb + k0 + kc]);
    }
    __syncthreads();
    bf16x8 a[4], b[4];
#pragma unroll
    for (int i = 0; i < 4; i++)
      a[i] = *reinterpret_cast<const bf16x8*>(&As[(wm + i * 16 + lr) * 32 + quad * 8]);
#pragma unroll
    for (int j = 0; j < 4; j++)
      b[j] = *reinterpret_cast<const bf16x8*>(&Bs[(wn + j * 16 + lr) * 32 + quad * 8]);
#pragma unroll
    for (int i = 0; i < 4; i++)
#pragma unroll
      for (int j = 0; j < 4; j++)
        acc[i][j] = __builtin_amdgcn_mfma_f32_16x16x32_bf16(a[i], b[j], acc[i][j], 0, 0, 0);
  }
#pragma unroll
  for (int j = 0; j < 4; j++) {
    int gcol = n0 + wn + j * 16 + lr;
    float bv = bias ? bias[gcol] : 0.0f;
#pragma unroll
    for (int i = 0; i < 4; i++) {
#pragma unroll
      for (int r = 0; r < 4; r++) {
        int grow = m0 + wm + i * 16 + quad * 4 + r;
        C[(size_t)grow * ldc + colOff + gcol] = f2b(acc[i][j][r] + bv);
      }
    }
  }
}

// fold GEMMs: z=0 pos-w4, z=1 aff-w4, z=2 sem (N=512 -> skip bx>=4)
__global__ __launch_bounds__(256) void gemm_fold(const unsigned short* __restrict__ fusT,
                                                 const unsigned short* __restrict__ wB,
                                                 unsigned short* __restrict__ BTcat) {
  int z = blockIdx.z;
  if (z == 2 && blockIdx.x >= 4) return;
  gemm_core(fusT + z * 768, 2304, wB + (size_t)z * 589824, 768, nullptr,
            BTcat, 2048, z * 768, 768, blockIdx.y * 128, blockIdx.x * 128);
}

// w3 GEMM pair: z = branch
__global__ __launch_bounds__(256) void gemm_w3(const unsigned short* __restrict__ xgB,
                                               const unsigned short* __restrict__ w3T,
                                               const float* __restrict__ pb3,
                                               const float* __restrict__ ab3,
                                               unsigned short* __restrict__ t) {
  int z = blockIdx.z;
  gemm_core(xgB + (size_t)z * NN * 64, 64, w3T + (size_t)z * 768 * 64, 64,
            z ? ab3 : pb3, t + (size_t)z * NN * 768, 768, 0, 64,
            blockIdx.y * 128, blockIdx.x * 128);
}

// --------------- fused final GEMM: virtual K=2048, 128x256 tile, 512 thr.
// XCD swizzle: blocks sharing an m-tile are 8 apart in dispatch order so the
// %8 round-robin puts them on one XCD -> A-tile served from that XCD's L2.
// LDS row stride 40 shorts (80B) keeps 16B alignment and kills the 8-way
// bank aliasing of the 32-short stride.
__global__ __launch_bounds__(512) void gemm_fuse3(
    const unsigned short* __restrict__ A0, const unsigned short* __restrict__ A1,
    const float* __restrict__ A2f, const unsigned short* __restrict__ BT,
    const float* __restrict__ bias, unsigned short* __restrict__ C) {
  __shared__ __align__(16) unsigned short As[128 * 40];  // 10 KB
  __shared__ __align__(16) unsigned short Bs[256 * 40];  // 20 KB
  int tid = threadIdx.x;
  int lid = blockIdx.x;            // 0..383
  int sg = lid / 24, rem = lid % 24;
  int n_t = rem >> 3;              // 0..2
  int m_t = sg * 8 + (rem & 7);    // 0..127
  int m0 = m_t * 128, n0 = n_t * 256;
  int lane = tid & 63, w = tid >> 6;          // 8 waves
  int wm = (w >> 2) * 64, wn = (w & 3) * 64;  // 2m x 4n
  int lr = lane & 15, quad = lane >> 4;
  floatx4 acc[4][4] = {};

  for (int k0 = 0; k0 < 2048; k0 += 32) {
    __syncthreads();
    {  // As: 128 rows, 1 uint4 per thread
      int row = tid >> 2, kc = (tid & 3) << 3;
      if (k0 < 1536) {
        const unsigned short* Ap = (k0 < 768) ? A0 : A1;
        int kk = (k0 < 768) ? k0 : (k0 - 768);
        *reinterpret_cast<uint4*>(&As[row * 40 + kc]) =
            *reinterpret_cast<const uint4*>(&Ap[(size_t)(m0 + row) * 768 + kk + kc]);
      } else {
        const float* src = &A2f[(size_t)(m0 + row) * 512 + (k0 - 1536) + kc];
        float4 fa = *reinterpret_cast<const float4*>(src);
        float4 fb = *reinterpret_cast<const float4*>(src + 4);
        uint4 pk;
        pk.x = (unsigned)f2b(fa.x) | ((unsigned)f2b(fa.y) << 16);
        pk.y = (unsigned)f2b(fa.z) | ((unsigned)f2b(fa.w) << 16);
        pk.z = (unsigned)f2b(fb.x) | ((unsigned)f2b(fb.y) << 16);
        pk.w = (unsigned)f2b(fb.z) | ((unsigned)f2b(fb.w) << 16);
        *reinterpret_cast<uint4*>(&As[row * 40 + kc]) = pk;
      }
    }
#pragma unroll
    for (int s = 0; s < 2; s++) {  // Bs: 256 rows, 2 uint4 per thread
      int cc = tid + s * 512;
      int row = cc >> 2, kc = (cc & 3) << 3;
      *reinterpret_cast<uint4*>(&Bs[row * 40 + kc]) =
          *reinterpret_cast<const uint4*>(&BT[(size_t)(n0 + row) * 2048 + k0 + kc]);
    }
    __syncthreads();
    bf16x8 a[4], b[4];
#pragma unroll
    for (int i = 0; i < 4; i++)
      a[i] = *reinterpret_cast<const bf16x8*>(&As[(wm + i * 16 + lr) * 40 + quad * 8]);
#pragma unroll
    for (int j = 0; j < 4; j++)
      b[j] = *reinterpret_cast<const bf16x8*>(&Bs[(wn + j * 16 + lr) * 40 + quad * 8]);
#pragma unroll
    for (int i = 0; i < 4; i++)
#pragma unroll
      for (int j = 0; j < 4; j++)
        acc[i][j] = __builtin_amdgcn_mfma_f32_16x16x32_bf16(a[i], b[j], acc[i][j], 0, 0, 0);
  }
#pragma unroll
  for (int j = 0; j < 4; j++) {
    int gcol = n0 + wn + j * 16 + lr;
    float bv = bias[gcol];
#pragma unroll
    for (int i = 0; i < 4; i++) {
#pragma unroll
      for (int r = 0; r < 4; r++) {
        int grow = m0 + wm + i * 16 + quad * 4 + r;
        C[(size_t)grow * 768 + gcol] = f2b(acc[i][j][r] + bv);
      }
    }
  }
}

// ------------- fold all upstream biases into the fusion bias (f32 in/out)
__global__ __launch_bounds__(256) void fuse_bias(
    const float* __restrict__ fus_b, const float* __restrict__ fus_w,
    const float* __restrict__ pb4, const float* __restrict__ ab4,
    const float* __restrict__ semb, float* __restrict__ bias_tot) {
  int c = blockIdx.x;
  int tid = threadIdx.x;
  float s = 0.f;
  for (int j = tid; j < 768; j += 256) {
    s = fmaf(pb4[j],  fus_w[(size_t)j * 768 + c], s);
    s = fmaf(ab4[j],  fus_w[(size_t)(768 + j) * 768 + c], s);
    s = fmaf(semb[j], fus_w[(size_t)(1536 + j) * 768 + c], s);
  }
#pragma unroll
  for (int off = 32; off > 0; off >>= 1) s += __shfl_xor(s, off, 64);
  __shared__ float sm[4];
  if ((tid & 63) == 0) sm[tid >> 6] = s;
  __syncthreads();
  if (tid == 0) bias_tot[c] = sm[0] + sm[1] + sm[2] + sm[3] + fus_b[c];
}

// ----------------------- rowwise LN(768)+ReLU pair, bf16 in/out, y = branch
__global__ __launch_bounds__(256) void ln2(unsigned short* __restrict__ tB,
                                           const float* __restrict__ pg2,
                                           const float* __restrict__ pbe2,
                                           const float* __restrict__ ag2,
                                           const float* __restrict__ abe2) {
  int br = blockIdx.y;
  unsigned short* X = tB + (size_t)br * NN * 768;
  const float* g = br ? ag2 : pg2;
  const float* be = br ? abe2 : pbe2;
  int row = blockIdx.x, tid = threadIdx.x;
  size_t base = (size_t)row * 768;
  float xv[3];
#pragma unroll
  for (int i = 0; i < 3; i++) xv[i] = b2f(X[base + tid + i * 256]);
  float s = xv[0] + xv[1] + xv[2];
  float q = xv[0] * xv[0] + xv[1] * xv[1] + xv[2] * xv[2];
#pragma unroll
  for (int off = 32; off > 0; off >>= 1) {
    s += __shfl_xor(s, off, 64);
    q += __shfl_xor(q, off, 64);
  }
  __shared__ float ss[4], qq[4];
  int w = tid >> 6, lane = tid & 63;
  if (lane == 0) { ss[w] = s; qq[w] = q; }
  __syncthreads();
  s = ss[0] + ss[1] + ss[2] + ss[3];
  q = qq[0] + qq[1] + qq[2] + qq[3];
  float m = s * (1.0f / 768.0f);
  float v = fmaf(-m, m, q * (1.0f / 768.0f));
  float rstd = rsqrtf(v + EPS);
#pragma unroll
  for (int i = 0; i < 3; i++) {
    int c = tid + i * 256;
    float y = (xv[i] - m) * rstd * g[c] + be[c];
    X[base + c] = f2b(fmaxf(y, 0.0f));
  }
}

// ------------------------------------- rowwise LN(768)+ReLU, bf16 in/f32 out
__global__ __launch_bounds__(256) void ln_relu_768_f32(
    const unsigned short* __restrict__ X, const float* __restrict__ g,
    const float* __restrict__ be, float* __restrict__ Y) {
  int row = blockIdx.x, tid = threadIdx.x;
  size_t base = (size_t)row * 768;
  float xv[3];
#pragma unroll
  for (int i = 0; i < 3; i++) xv[i] = b2f(X[base + tid + i * 256]);
  float s = xv[0] + xv[1] + xv[2];
  float q = xv[0] * xv[0] + xv[1] * xv[1] + xv[2] * xv[2];
#pragma unroll
  for (int off = 32; off > 0; off >>= 1) {
    s += __shfl_xor(s, off, 64);
    q += __shfl_xor(q, off, 64);
  }
  __shared__ float ss[4], qq[4];
  int w = tid >> 6, lane = tid & 63;
  if (lane == 0) { ss[w] = s; qq[w] = q; }
  __syncthreads();
  s = ss[0] + ss[1] + ss[2] + ss[3];
  q = qq[0] + qq[1] + qq[2] + qq[3];
  float m = s * (1.0f / 768.0f);
  float v = fmaf(-m, m, q * (1.0f / 768.0f));
  float rstd = rsqrtf(v + EPS);
#pragma unroll
  for (int i = 0; i < 3; i++) {
    int c = tid + i * 256;
    float y = (xv[i] - m) * rstd * g[c] + be[c];
    Y[base + c] = fmaxf(y, 0.0f);
  }
}

extern "C" void kernel_launch(void* const* d_in, const int* in_sizes, int n_in,
                              void* d_out, int out_size, void* d_ws, size_t ws_size,
                              hipStream_t stream) {
  typedef const float* cf;
  cf x_pos = (cf)d_in[0];
  const int* pos_idx = (const int*)d_in[1];
  cf x_aff = (cf)d_in[2];
  const int* aff_idx = (const int*)d_in[3];
  cf x_sem = (cf)d_in[4];
  cf pw1 = (cf)d_in[6],  pb1 = (cf)d_in[7],  pg1 = (cf)d_in[8],  pbe1 = (cf)d_in[9];
  cf pw2 = (cf)d_in[10], pb2 = (cf)d_in[11];
  cf pw3 = (cf)d_in[12], pb3 = (cf)d_in[13], pg2 = (cf)d_in[14], pbe2 = (cf)d_in[15];
  cf pw4 = (cf)d_in[16], pb4 = (cf)d_in[17];
  cf aw1 = (cf)d_in[18], ab1 = (cf)d_in[19], ag1 = (cf)d_in[20], abe1 = (cf)d_in[21];
  cf aw2 = (cf)d_in[22], ab2 = (cf)d_in[23];
  cf aw3 = (cf)d_in[24], ab3 = (cf)d_in[25], ag2 = (cf)d_in[26], abe2 = (cf)d_in[27];
  cf aw4 = (cf)d_in[28], ab4 = (cf)d_in[29];
  cf semw = (cf)d_in[30], semb = (cf)d_in[31];
  cf fusw = (cf)d_in[32], fusb = (cf)d_in[33], fusg = (cf)d_in[34], fusbe = (cf)d_in[35];

  int P = in_sizes[0] / 3;

  char* wsb = (char*)d_ws;
  size_t off = 0;
  auto carve = [&](size_t bytes) -> void* {
    void* p = wsb + off;
    off = (off + bytes + 255) & ~(size_t)255;
    return p;
  };
  unsigned short* xgB   = (unsigned short*)carve((size_t)2 * NN * 64 * 2);   // 4 MiB
  unsigned short* t     = (unsigned short*)carve((size_t)2 * NN * 768 * 2);  // 48 MiB
  float4* sorted        = (float4*)carve((size_t)2 * P * 16);                // 32 MiB
  unsigned short* F = (unsigned short*)sorted;  // alias: sorted dead before fuse3
  unsigned short* w3T   = (unsigned short*)carve((size_t)2 * 768 * 64 * 2);
  unsigned short* fusT  = (unsigned short*)carve((size_t)768 * 2304 * 2);
  unsigned short* wB    = (unsigned short*)carve((size_t)1572864 * 2);       // pw4B|aw4B|semwB
  unsigned short* BTcat = (unsigned short*)carve((size_t)768 * 2048 * 2);
  unsigned short* w2T   = (unsigned short*)carve((size_t)2 * 4096 * 2);
  float* bias_tot = (float*)carve((size_t)768 * 4);
  float* G2  = (float*)carve((size_t)512 * 4);
  float* Mq2 = (float*)carve((size_t)32 * 4);
  unsigned* bcnt  = (unsigned*)carve((size_t)2 * 512 * 4);
  unsigned* boffs = (unsigned*)carve((size_t)2 * 513 * 4);
  unsigned* bcur  = (unsigned*)carve((size_t)2 * 512 * 4);
  // total ~94 MiB

  zero_u32<<<(1024 + 255) / 256, 256, 0, stream>>>(bcnt, 1024);

  dim3 tb(32, 8);
  transpose_w3_pair<<<dim3(24, 2, 2), tb, 0, stream>>>(pw3, aw3, w3T);
  transpose_f32_b16<<<dim3(24, 72), tb, 0, stream>>>(fusw, fusT, 2304, 768);
  convert3<<<(1572864 + 255) / 256, 256, 0, stream>>>(pw4, 589824, aw4, 589824,
                                                      semw, 393216, wB);
  prep_pointnet2<<<2, 64, 0, stream>>>(pw1, pb1, pg1, aw1, ab1, ag1, pw2, aw2,
                                       G2, Mq2, w2T);

  gemm_fold<<<dim3(6, 6, 3), 256, 0, stream>>>(fusT, wB, BTcat);
  fuse_bias<<<768, 256, 0, stream>>>(fusb, fusw, pb4, ab4, semb, bias_tot);

  // bucket counting sort (32 nodes/bucket) + per-bucket MFMA reduce
  hist_bucket<<<dim3(64, 2), 256, 0, stream>>>(pos_idx, aff_idx, P, bcnt);
  scan_bucket<<<2, 512, 0, stream>>>(bcnt, boffs, bcur);
  bucket_scatter<<<dim3(256, 2), 256, 0, stream>>>(x_pos, x_aff, pos_idx, aff_idx,
                                                   P, bcur, sorted);
  bucket_mlp_max<<<dim3(512, 2), 256, 0, stream>>>(sorted, boffs, G2, Mq2, pbe1, abe1,
                                                   w2T, pb2, ab2, xgB, P);

  gemm_w3<<<dim3(6, NN / 128, 2), 256, 0, stream>>>(xgB, w3T, pb3, ab3, t);
  ln2<<<dim3(NN, 2), 256, 0, stream>>>(t, pg2, pbe2, ag2, abe2);

  gemm_fuse3<<<384, 512, 0, stream>>>(t, t + (size_t)NN * 768, x_sem,
                                      BTcat, bias_tot, F);
  ln_relu_768_f32<<<NN, 256, 0, stream>>>(F, fusg, fusbe, (float*)d_out);
}

// Round 11
// 513.681 us; speedup vs baseline: 1.9862x; 1.0088x over previous
//
#include <hip/hip_runtime.h>

typedef __attribute__((ext_vector_type(8))) __bf16 bf16x8;
typedef __attribute__((ext_vector_type(4))) float floatx4;

#define NN 16384
#define EPS 1e-5f

__device__ __forceinline__ unsigned short f2b(float f) {
  unsigned u = __float_as_uint(f);
  u += 0x7fffu + ((u >> 16) & 1u);
  return (unsigned short)(u >> 16);
}
__device__ __forceinline__ float b2f(unsigned short u) {
  return __uint_as_float(((unsigned)u) << 16);
}

// kept for harness symbol expectations; never launched
__global__ void RoboNodeEncoder_88424786690347_kernel() {}

// ---------------------------------------------------------------- zero init
__global__ __launch_bounds__(256) void zero_u32(unsigned* __restrict__ p, int n) {
  int i = blockIdx.x * blockDim.x + threadIdx.x;
  if (i < n) p[i] = 0u;
}

// --------------------------- merged f32->bf16 casts (3 sources, contiguous dst)
__global__ __launch_bounds__(256) void convert3(const float* __restrict__ a, int na,
                                                const float* __restrict__ b, int nb,
                                                const float* __restrict__ c, int nc,
                                                unsigned short* __restrict__ out) {
  int i = blockIdx.x * 256 + threadIdx.x;
  int total = na + nb + nc;
  if (i >= total) return;
  float v;
  if (i < na) v = a[i];
  else if (i < na + nb) v = b[i - na];
  else v = c[i - na - nb];
  out[i] = f2b(v);
}

// --------------------------------------------------- f32 -> bf16 transpose
__global__ __launch_bounds__(256) void transpose_f32_b16(const float* __restrict__ in,
                                                         unsigned short* __restrict__ out,
                                                         int R, int C) {
  __shared__ float t[32][33];
  int bx = blockIdx.x * 32, by = blockIdx.y * 32;
  int x = threadIdx.x, y = threadIdx.y;
#pragma unroll
  for (int i = 0; i < 32; i += 8) t[y + i][x] = in[(size_t)(by + y + i) * C + bx + x];
  __syncthreads();
#pragma unroll
  for (int i = 0; i < 32; i += 8) out[(size_t)(bx + y + i) * R + by + x] = f2b(t[x][y + i]);
}

// ---------------- w3 transpose pair: z selects branch, out stride 768*64
__global__ __launch_bounds__(256) void transpose_w3_pair(const float* __restrict__ pw3,
                                                         const float* __restrict__ aw3,
                                                         unsigned short* __restrict__ w3T) {
  __shared__ float t[32][33];
  const float* in = blockIdx.z ? aw3 : pw3;
  unsigned short* out = w3T + (size_t)blockIdx.z * 768 * 64;
  int R = 64, C = 768;
  int bx = blockIdx.x * 32, by = blockIdx.y * 32;
  int x = threadIdx.x, y = threadIdx.y;
#pragma unroll
  for (int i = 0; i < 32; i += 8) t[y + i][x] = in[(size_t)(by + y + i) * C + bx + x];
  __syncthreads();
#pragma unroll
  for (int i = 0; i < 32; i += 8) out[(size_t)(bx + y + i) * R + by + x] = f2b(t[x][y + i]);
}

// ------------------- prep: fold LN of the point MLP into closed-form consts
__global__ void prep_pointnet2(const float* __restrict__ w1p, const float* __restrict__ b1p,
                               const float* __restrict__ g1p,
                               const float* __restrict__ w1a, const float* __restrict__ b1a,
                               const float* __restrict__ g1a,
                               const float* __restrict__ w2p, const float* __restrict__ w2a,
                               float* __restrict__ G2, float* __restrict__ Mq2,
                               unsigned short* __restrict__ w2T) {
  int br = blockIdx.x;
  const float* w1 = br ? w1a : w1p;
  const float* b1 = br ? b1a : b1p;
  const float* g1 = br ? g1a : g1p;
  const float* w2 = br ? w2a : w2p;
  float* G = G2 + br * 256;
  float* Mq = Mq2 + br * 16;
  unsigned short* w2t = w2T + br * 4096;
  int k = threadIdx.x;
#pragma unroll
  for (int n = 0; n < 64; n++) w2t[n * 64 + k] = f2b(w2[k * 64 + n]);
  float c[4] = {w1[k], w1[64 + k], w1[128 + k], b1[k]};
#pragma unroll
  for (int a = 0; a < 4; a++) {
    float s = c[a];
#pragma unroll
    for (int off = 32; off > 0; off >>= 1) s += __shfl_xor(s, off, 64);
    c[a] -= s * (1.f / 64.f);
  }
  float g = g1[k];
#pragma unroll
  for (int a = 0; a < 4; a++) G[a * 64 + k] = c[a] * g;
  const int AA[10] = {0, 1, 2, 3, 0, 0, 0, 1, 1, 2};
  const int BB[10] = {0, 1, 2, 3, 1, 2, 3, 2, 3, 3};
#pragma unroll
  for (int t = 0; t < 10; t++) {
    float s = c[AA[t]] * c[BB[t]];
#pragma unroll
    for (int off = 32; off > 0; off >>= 1) s += __shfl_xor(s, off, 64);
    s *= (1.f / 64.f);
    if (t >= 4) s *= 2.f;
    if (k == 0) Mq[t] = s;
  }
}

// --------------------- bucket histogram (bucket = node>>5, 512 buckets/branch)
__global__ __launch_bounds__(256) void hist_bucket(const int* __restrict__ pos_idx,
                                                   const int* __restrict__ aff_idx, int P,
                                                   unsigned* __restrict__ cntB) {
  __shared__ unsigned lc[512];
  int br = blockIdx.y;
  const int* idx = br ? aff_idx : pos_idx;
  for (int i = threadIdx.x; i < 512; i += 256) lc[i] = 0u;
  __syncthreads();
  int stride = gridDim.x * blockDim.x;
  for (int i = blockIdx.x * blockDim.x + threadIdx.x; i < P; i += stride)
    atomicAdd(&lc[idx[i] >> 5], 1u);
  __syncthreads();
  for (int i = threadIdx.x; i < 512; i += 256)
    if (lc[i]) atomicAdd(&cntB[br * 512 + i], lc[i]);
}

// ------------------------- exclusive scan of 512 buckets; blockIdx.x = branch
__global__ __launch_bounds__(512) void scan_bucket(const unsigned* __restrict__ cntB,
                                                   unsigned* __restrict__ offsB,
                                                   unsigned* __restrict__ curB) {
  int br = blockIdx.x;
  __shared__ unsigned ps[512];
  int t = threadIdx.x;
  unsigned v = cntB[br * 512 + t];
  ps[t] = v;
  __syncthreads();
  for (int off = 1; off < 512; off <<= 1) {
    unsigned a = (t >= off) ? ps[t - off] : 0u;
    __syncthreads();
    ps[t] += a;
    __syncthreads();
  }
  unsigned excl = ps[t] - v;
  offsB[br * 513 + t] = excl;
  curB[br * 512 + t] = excl;
  if (t == 511) offsB[br * 513 + 512] = ps[t];
}

// ---------------- bucket scatter: per-block LDS count -> reserve -> scatter.
__global__ __launch_bounds__(256) void bucket_scatter(
    const float* __restrict__ x_pos, const float* __restrict__ x_aff,
    const int* __restrict__ pos_idx, const int* __restrict__ aff_idx, int P,
    unsigned* __restrict__ curB, float4* __restrict__ sortedB) {
  __shared__ unsigned lcnt[512], lbase[512];
  int br = blockIdx.y;
  const float* x = br ? x_aff : x_pos;
  const int* idx = br ? aff_idx : pos_idx;
  float4* sorted = sortedB + (size_t)br * P;
  int nb = gridDim.x;
  int chunk = (P + nb - 1) / nb;
  int start = blockIdx.x * chunk;
  int end = start + chunk;
  if (end > P) end = P;
  for (int i = threadIdx.x; i < 512; i += 256) lcnt[i] = 0u;
  __syncthreads();
  for (int i = start + threadIdx.x; i < end; i += 256)
    atomicAdd(&lcnt[idx[i] >> 5], 1u);
  __syncthreads();
  for (int i = threadIdx.x; i < 512; i += 256) {
    unsigned c = lcnt[i];
    lbase[i] = c ? atomicAdd(&curB[br * 512 + i], c) : 0u;
  }
  __syncthreads();
  for (int i = threadIdx.x; i < 512; i += 256) lcnt[i] = 0u;
  __syncthreads();
  for (int i = start + threadIdx.x; i < end; i += 256) {
    int nd = idx[i];
    int b = nd >> 5;
    unsigned lo = atomicAdd(&lcnt[b], 1u);
    float4 v;
    v.x = x[3 * i]; v.y = x[3 * i + 1]; v.z = x[3 * i + 2];
    v.w = __int_as_float(nd & 31);
    sorted[lbase[b] + lo] = v;
  }
}

// ---------- per-bucket: folded-LN MLP + MFMA + LDS atomicMax per node-feature
__global__ __launch_bounds__(256) void bucket_mlp_max(
    const float4* __restrict__ sortedB, const unsigned* __restrict__ offsB,
    const float* __restrict__ G2, const float* __restrict__ Mq2,
    const float* __restrict__ be1p, const float* __restrict__ be1a,
    const unsigned short* __restrict__ w2T,
    const float* __restrict__ b2p, const float* __restrict__ b2a,
    unsigned short* __restrict__ xgB, int P) {
  __shared__ __align__(16) unsigned short hs[4][64 * 64];  // 32 KB
  __shared__ int ndl[4][64];                               // 1 KB
  __shared__ unsigned nmaxU[32 * 64];                      // 8 KB
  int br = blockIdx.y;
  int bucket = blockIdx.x;
  const float4* sorted = sortedB + (size_t)br * P;
  const unsigned* offs = offsB + br * 513;
  const float* G = G2 + br * 256;
  const float* Mq = Mq2 + br * 16;
  const float* be1 = br ? be1a : be1p;
  const unsigned short* w2t = w2T + br * 4096;
  const float* b2 = br ? b2a : b2p;
  unsigned short* out = xgB + (size_t)br * NN * 64;

  int tid = threadIdx.x;
  int lane = tid & 63, w = tid >> 6;
  int lr = lane & 15, quad = lane >> 4;
  int l7 = lane & 7;

  for (int e = tid; e < 2048; e += 256) nmaxU[e] = 0u;

  bf16x8 bfr[4][2];
#pragma unroll
  for (int j = 0; j < 4; j++)
#pragma unroll
    for (int s = 0; s < 2; s++)
      bfr[j][s] = *reinterpret_cast<const bf16x8*>(&w2t[(j * 16 + lr) * 64 + s * 32 + quad * 8]);
  float M00 = Mq[0], M11 = Mq[1], M22 = Mq[2], M33 = Mq[3];
  float T01 = Mq[4], T02 = Mq[5], T03 = Mq[6], T12 = Mq[7], T13 = Mq[8], T23 = Mq[9];
  __syncthreads();

  int seg0 = (int)offs[bucket], seg1 = (int)offs[bucket + 1];
  unsigned short* hrow = &hs[w][0];
  for (int t0 = seg0 + w * 64; t0 < seg1; t0 += 256) {
    int pi = t0 + lane;
    if (pi >= seg1) pi = seg1 - 1;  // duplicate a real point: max-neutral
    float4 xv = sorted[pi];
    float x0 = xv.x, x1 = xv.y, x2 = xv.z;
    ndl[w][lane] = __float_as_int(xv.w);
    float var = M33 + x0 * fmaf(M00, x0, fmaf(T01, x1, fmaf(T02, x2, T03)))
                    + x1 * fmaf(M11, x1, fmaf(T12, x2, T13))
                    + x2 * fmaf(M22, x2, T23);
    float rstd = rsqrtf(var + EPS);
    float x0r = x0 * rstd, x1r = x1 * rstd, x2r = x2 * rstd;
#pragma unroll
    for (int c = 0; c < 8; c++) {
      bf16x8 hv;
#pragma unroll
      for (int e = 0; e < 8; e++) {
        int k = c * 8 + e;
        float y = fmaf(x0r, G[k], fmaf(x1r, G[64 + k],
                  fmaf(x2r, G[128 + k], fmaf(rstd, G[192 + k], be1[k]))));
        hv[e] = (__bf16)fmaxf(y, 0.f);
      }
      *reinterpret_cast<bf16x8*>(&hrow[lane * 64 + ((c ^ l7) << 3)]) = hv;
    }
    asm volatile("s_waitcnt lgkmcnt(0)" ::: "memory");
#pragma unroll
    for (int i = 0; i < 4; i++) {
      int row = i * 16 + lr;
      bf16x8 a0 = *reinterpret_cast<const bf16x8*>(&hrow[row * 64 + ((quad ^ l7) << 3)]);
      bf16x8 a1 = *reinterpret_cast<const bf16x8*>(&hrow[row * 64 + (((4 + quad) ^ l7) << 3)]);
      floatx4 accj[4] = {};
#pragma unroll
      for (int j = 0; j < 4; j++) {
        accj[j] = __builtin_amdgcn_mfma_f32_16x16x32_bf16(a0, bfr[j][0], accj[j], 0, 0, 0);
        accj[j] = __builtin_amdgcn_mfma_f32_16x16x32_bf16(a1, bfr[j][1], accj[j], 0, 0, 0);
      }
      int nd0 = ndl[w][i * 16 + quad * 4 + 0];
      int nd1 = ndl[w][i * 16 + quad * 4 + 1];
      int nd2 = ndl[w][i * 16 + quad * 4 + 2];
      int nd3 = ndl[w][i * 16 + quad * 4 + 3];
#pragma unroll
      for (int j = 0; j < 4; j++) {
        int col = j * 16 + lr;
#pragma unroll
        for (int r = 0; r < 4; r++) {
          unsigned u = __float_as_uint(accj[j][r]);
          unsigned ord = (u & 0x80000000u) ? ~u : (u | 0x80000000u);
          int nd = (r == 0) ? nd0 : (r == 1) ? nd1 : (r == 2) ? nd2 : nd3;
          atomicMax(&nmaxU[nd * 64 + col], ord);
        }
      }
    }
  }
  __syncthreads();
  for (int e = tid; e < 2048; e += 256) {
    unsigned u = nmaxU[e];
    int f = e & 63;
    float val;
    if (u == 0u) val = 0.f;  // empty node
    else {
      float m = (u & 0x80000000u) ? __uint_as_float(u ^ 0x80000000u) : __uint_as_float(~u);
      val = m + b2[f];
    }
    out[(size_t)(bucket * 32 + (e >> 6)) * 64 + f] = f2b(val);
  }
}

// ------------------------------------------------------------- GEMM core
__device__ __forceinline__ void gemm_core(
    const unsigned short* __restrict__ A, int lda,
    const unsigned short* __restrict__ BT, int ldb,
    const float* __restrict__ bias,
    unsigned short* __restrict__ C, int ldc, int colOff, int K,
    int m0, int n0) {
  __shared__ __align__(16) unsigned short As[128 * 32];
  __shared__ __align__(16) unsigned short Bs[128 * 32];
  int tid = threadIdx.x;
  int lane = tid & 63, w = tid >> 6;
  int wm = (w >> 1) * 64, wn = (w & 1) * 64;
  int lr = lane & 15, quad = lane >> 4;
  floatx4 acc[4][4] = {};

  for (int k0 = 0; k0 < K; k0 += 32) {
    __syncthreads();
#pragma unroll
    for (int s = 0; s < 2; s++) {
      int cc = tid + s * 256;
      int row = cc >> 2, kc = (cc & 3) << 3;
      *reinterpret_cast<uint4*>(&As[row * 32 + kc]) =
          *reinterpret_cast<const uint4*>(&A[(size_t)(m0 + row) * lda + k0 + kc]);
      *reinterpret_cast<uint4*>(&Bs[row * 32 + kc]) =
          *reinterpret_cast<const uint4*>(&BT[(size_t)(n0 + row) * ldb + k0 + kc]);
    }
    __syncthreads();
    bf16x8 a[4], b[4];
#pragma unroll
    for (int i = 0; i < 4; i++)
      a[i] = *reinterpret_cast<const bf16x8*>(&As[(wm + i * 16 + lr) * 32 + quad * 8]);
#pragma unroll
    for (int j = 0; j < 4; j++)
      b[j] = *reinterpret_cast<const bf16x8*>(&Bs[(wn + j * 16 + lr) * 32 + quad * 8]);
#pragma unroll
    for (int i = 0; i < 4; i++)
#pragma unroll
      for (int j = 0; j < 4; j++)
        acc[i][j] = __builtin_amdgcn_mfma_f32_16x16x32_bf16(a[i], b[j], acc[i][j], 0, 0, 0);
  }
#pragma unroll
  for (int j = 0; j < 4; j++) {
    int gcol = n0 + wn + j * 16 + lr;
    float bv = bias ? bias[gcol] : 0.0f;
#pragma unroll
    for (int i = 0; i < 4; i++) {
#pragma unroll
      for (int r = 0; r < 4; r++) {
        int grow = m0 + wm + i * 16 + quad * 4 + r;
        C[(size_t)grow * ldc + colOff + gcol] = f2b(acc[i][j][r] + bv);
      }
    }
  }
}

// fold GEMMs: z=0 pos-w4, z=1 aff-w4, z=2 sem (N=512 -> skip bx>=4)
__global__ __launch_bounds__(256) void gemm_fold(const unsigned short* __restrict__ fusT,
                                                 const unsigned short* __restrict__ wB,
                                                 unsigned short* __restrict__ BTcat) {
  int z = blockIdx.z;
  if (z == 2 && blockIdx.x >= 4) return;
  gemm_core(fusT + z * 768, 2304, wB + (size_t)z * 589824, 768, nullptr,
            BTcat, 2048, z * 768, 768, blockIdx.y * 128, blockIdx.x * 128);
}

// w3 GEMM pair: z = branch
__global__ __launch_bounds__(256) void gemm_w3(const unsigned short* __restrict__ xgB,
                                               const unsigned short* __restrict__ w3T,
                                               const float* __restrict__ pb3,
                                               const float* __restrict__ ab3,
                                               unsigned short* __restrict__ t) {
  int z = blockIdx.z;
  gemm_core(xgB + (size_t)z * NN * 64, 64, w3T + (size_t)z * 768 * 64, 64,
            z ? ab3 : pb3, t + (size_t)z * NN * 768, 768, 0, 64,
            blockIdx.y * 128, blockIdx.x * 128);
}

// --------------- fused final GEMM: virtual K=2048, 128x128 tile, 256 thr,
// 768 blocks (3/CU). XCD swizzle: the 6 blocks sharing an m-tile are spaced
// 8 apart in dispatch order -> same XCD -> A refetch served by that L2.
// LDS stride 40 shorts: frag reads 2-way (free).
__global__ __launch_bounds__(256) void gemm_fuse3(
    const unsigned short* __restrict__ A0, const unsigned short* __restrict__ A1,
    const float* __restrict__ A2f, const unsigned short* __restrict__ BT,
    const float* __restrict__ bias, unsigned short* __restrict__ C) {
  __shared__ __align__(16) unsigned short As[128 * 40];  // 10 KB
  __shared__ __align__(16) unsigned short Bs[128 * 40];  // 10 KB
  int tid = threadIdx.x;
  int lid = blockIdx.x;            // 0..767
  int sg = lid / 48, rem = lid % 48;
  int n_t = rem >> 3;              // 0..5
  int m_t = sg * 8 + (rem & 7);    // 0..127
  int m0 = m_t * 128, n0 = n_t * 128;
  int lane = tid & 63, w = tid >> 6;
  int wm = (w >> 1) * 64, wn = (w & 1) * 64;
  int lr = lane & 15, quad = lane >> 4;
  floatx4 acc[4][4] = {};

  for (int k0 = 0; k0 < 2048; k0 += 32) {
    __syncthreads();
    if (k0 < 1536) {
      const unsigned short* Ap = (k0 < 768) ? A0 : A1;
      int kk = (k0 < 768) ? k0 : (k0 - 768);
#pragma unroll
      for (int s = 0; s < 2; s++) {
        int cc = tid + s * 256;
        int row = cc >> 2, kc = (cc & 3) << 3;
        *reinterpret_cast<uint4*>(&As[row * 40 + kc]) =
            *reinterpret_cast<const uint4*>(&Ap[(size_t)(m0 + row) * 768 + kk + kc]);
      }
    } else {
      int kk = k0 - 1536;
#pragma unroll
      for (int s = 0; s < 2; s++) {
        int cc = tid + s * 256;
        int row = cc >> 2, kc = (cc & 3) << 3;
        const float* src = &A2f[(size_t)(m0 + row) * 512 + kk + kc];
        float4 fa = *reinterpret_cast<const float4*>(src);
        float4 fb = *reinterpret_cast<const float4*>(src + 4);
        uint4 pk;
        pk.x = (unsigned)f2b(fa.x) | ((unsigned)f2b(fa.y) << 16);
        pk.y = (unsigned)f2b(fa.z) | ((unsigned)f2b(fa.w) << 16);
        pk.z = (unsigned)f2b(fb.x) | ((unsigned)f2b(fb.y) << 16);
        pk.w = (unsigned)f2b(fb.z) | ((unsigned)f2b(fb.w) << 16);
        *reinterpret_cast<uint4*>(&As[row * 40 + kc]) = pk;
      }
    }
#pragma unroll
    for (int s = 0; s < 2; s++) {
      int cc = tid + s * 256;
      int row = cc >> 2, kc = (cc & 3) << 3;
      *reinterpret_cast<uint4*>(&Bs[row * 40 + kc]) =
          *reinterpret_cast<const uint4*>(&BT[(size_t)(n0 + row) * 2048 + k0 + kc]);
    }
    __syncthreads();
    bf16x8 a[4], b[4];
#pragma unroll
    for (int i = 0; i < 4; i++)
      a[i] = *reinterpret_cast<const bf16x8*>(&As[(wm + i * 16 + lr) * 40 + quad * 8]);
#pragma unroll
    for (int j = 0; j < 4; j++)
      b[j] = *reinterpret_cast<const bf16x8*>(&Bs[(wn + j * 16 + lr) * 40 + quad * 8]);
#pragma unroll
    for (int i = 0; i < 4; i++)
#pragma unroll
      for (int j = 0; j < 4; j++)
        acc[i][j] = __builtin_amdgcn_mfma_f32_16x16x32_bf16(a[i], b[j], acc[i][j], 0, 0, 0);
  }
#pragma unroll
  for (int j = 0; j < 4; j++) {
    int gcol = n0 + wn + j * 16 + lr;
    float bv = bias[gcol];
#pragma unroll
    for (int i = 0; i < 4; i++) {
#pragma unroll
      for (int r = 0; r < 4; r++) {
        int grow = m0 + wm + i * 16 + quad * 4 + r;
        C[(size_t)grow * 768 + gcol] = f2b(acc[i][j][r] + bv);
      }
    }
  }
}

// ------------- fold all upstream biases into the fusion bias (f32 in/out)
__global__ __launch_bounds__(256) void fuse_bias(
    const float* __restrict__ fus_b, const float* __restrict__ fus_w,
    const float* __restrict__ pb4, const float* __restrict__ ab4,
    const float* __restrict__ semb, float* __restrict__ bias_tot) {
  int c = blockIdx.x;
  int tid = threadIdx.x;
  float s = 0.f;
  for (int j = tid; j < 768; j += 256) {
    s = fmaf(pb4[j],  fus_w[(size_t)j * 768 + c], s);
    s = fmaf(ab4[j],  fus_w[(size_t)(768 + j) * 768 + c], s);
    s = fmaf(semb[j], fus_w[(size_t)(1536 + j) * 768 + c], s);
  }
#pragma unroll
  for (int off = 32; off > 0; off >>= 1) s += __shfl_xor(s, off, 64);
  __shared__ float sm[4];
  if ((tid & 63) == 0) sm[tid >> 6] = s;
  __syncthreads();
  if (tid == 0) bias_tot[c] = sm[0] + sm[1] + sm[2] + sm[3] + fus_b[c];
}

// ----------------------- rowwise LN(768)+ReLU pair, bf16 in/out, y = branch
__global__ __launch_bounds__(256) void ln2(unsigned short* __restrict__ tB,
                                           const float* __restrict__ pg2,
                                           const float* __restrict__ pbe2,
                                           const float* __restrict__ ag2,
                                           const float* __restrict__ abe2) {
  int br = blockIdx.y;
  unsigned short* X = tB + (size_t)br * NN * 768;
  const float* g = br ? ag2 : pg2;
  const float* be = br ? abe2 : pbe2;
  int row = blockIdx.x, tid = threadIdx.x;
  size_t base = (size_t)row * 768;
  float xv[3];
#pragma unroll
  for (int i = 0; i < 3; i++) xv[i] = b2f(X[base + tid + i * 256]);
  float s = xv[0] + xv[1] + xv[2];
  float q = xv[0] * xv[0] + xv[1] * xv[1] + xv[2] * xv[2];
#pragma unroll
  for (int off = 32; off > 0; off >>= 1) {
    s += __shfl_xor(s, off, 64);
    q += __shfl_xor(q, off, 64);
  }
  __shared__ float ss[4], qq[4];
  int w = tid >> 6, lane = tid & 63;
  if (lane == 0) { ss[w] = s; qq[w] = q; }
  __syncthreads();
  s = ss[0] + ss[1] + ss[2] + ss[3];
  q = qq[0] + qq[1] + qq[2] + qq[3];
  float m = s * (1.0f / 768.0f);
  float v = fmaf(-m, m, q * (1.0f / 768.0f));
  float rstd = rsqrtf(v + EPS);
#pragma unroll
  for (int i = 0; i < 3; i++) {
    int c = tid + i * 256;
    float y = (xv[i] - m) * rstd * g[c] + be[c];
    X[base + c] = f2b(fmaxf(y, 0.0f));
  }
}

// ------------------------------------- rowwise LN(768)+ReLU, bf16 in/f32 out
__global__ __launch_bounds__(256) void ln_relu_768_f32(
    const unsigned short* __restrict__ X, const float* __restrict__ g,
    const float* __restrict__ be, float* __restrict__ Y) {
  int row = blockIdx.x, tid = threadIdx.x;
  size_t base = (size_t)row * 768;
  float xv[3];
#pragma unroll
  for (int i = 0; i < 3; i++) xv[i] = b2f(X[base + tid + i * 256]);
  float s = xv[0] + xv[1] + xv[2];
  float q = xv[0] * xv[0] + xv[1] * xv[1] + xv[2] * xv[2];
#pragma unroll
  for (int off = 32; off > 0; off >>= 1) {
    s += __shfl_xor(s, off, 64);
    q += __shfl_xor(q, off, 64);
  }
  __shared__ float ss[4], qq[4];
  int w = tid >> 6, lane = tid & 63;
  if (lane == 0) { ss[w] = s; qq[w] = q; }
  __syncthreads();
  s = ss[0] + ss[1] + ss[2] + ss[3];
  q = qq[0] + qq[1] + qq[2] + qq[3];
  float m = s * (1.0f / 768.0f);
  float v = fmaf(-m, m, q * (1.0f / 768.0f));
  float rstd = rsqrtf(v + EPS);
#pragma unroll
  for (int i = 0; i < 3; i++) {
    int c = tid + i * 256;
    float y = (xv[i] - m) * rstd * g[c] + be[c];
    Y[base + c] = fmaxf(y, 0.0f);
  }
}

extern "C" void kernel_launch(void* const* d_in, const int* in_sizes, int n_in,
                              void* d_out, int out_size, void* d_ws, size_t ws_size,
                              hipStream_t stream) {
  typedef const float* cf;
  cf x_pos = (cf)d_in[0];
  const int* pos_idx = (const int*)d_in[1];
  cf x_aff = (cf)d_in[2];
  const int* aff_idx = (const int*)d_in[3];
  cf x_sem = (cf)d_in[4];
  cf pw1 = (cf)d_in[6],  pb1 = (cf)d_in[7],  pg1 = (cf)d_in[8],  pbe1 = (cf)d_in[9];
  cf pw2 = (cf)d_in[10], pb2 = (cf)d_in[11];
  cf pw3 = (cf)d_in[12], pb3 = (cf)d_in[13], pg2 = (cf)d_in[14], pbe2 = (cf)d_in[15];
  cf pw4 = (cf)d_in[16], pb4 = (cf)d_in[17];
  cf aw1 = (cf)d_in[18], ab1 = (cf)d_in[19], ag1 = (cf)d_in[20], abe1 = (cf)d_in[21];
  cf aw2 = (cf)d_in[22], ab2 = (cf)d_in[23];
  cf aw3 = (cf)d_in[24], ab3 = (cf)d_in[25], ag2 = (cf)d_in[26], abe2 = (cf)d_in[27];
  cf aw4 = (cf)d_in[28], ab4 = (cf)d_in[29];
  cf semw = (cf)d_in[30], semb = (cf)d_in[31];
  cf fusw = (cf)d_in[32], fusb = (cf)d_in[33], fusg = (cf)d_in[34], fusbe = (cf)d_in[35];

  int P = in_sizes[0] / 3;

  char* wsb = (char*)d_ws;
  size_t off = 0;
  auto carve = [&](size_t bytes) -> void* {
    void* p = wsb + off;
    off = (off + bytes + 255) & ~(size_t)255;
    return p;
  };
  unsigned short* xgB   = (unsigned short*)carve((size_t)2 * NN * 64 * 2);   // 4 MiB
  unsigned short* t     = (unsigned short*)carve((size_t)2 * NN * 768 * 2);  // 48 MiB
  float4* sorted        = (float4*)carve((size_t)2 * P * 16);                // 32 MiB
  unsigned short* F = (unsigned short*)sorted;  // alias: sorted dead before fuse3
  unsigned short* w3T   = (unsigned short*)carve((size_t)2 * 768 * 64 * 2);
  unsigned short* fusT  = (unsigned short*)carve((size_t)768 * 2304 * 2);
  unsigned short* wB    = (unsigned short*)carve((size_t)1572864 * 2);       // pw4B|aw4B|semwB
  unsigned short* BTcat = (unsigned short*)carve((size_t)768 * 2048 * 2);
  unsigned short* w2T   = (unsigned short*)carve((size_t)2 * 4096 * 2);
  float* bias_tot = (float*)carve((size_t)768 * 4);
  float* G2  = (float*)carve((size_t)512 * 4);
  float* Mq2 = (float*)carve((size_t)32 * 4);
  unsigned* bcnt  = (unsigned*)carve((size_t)2 * 512 * 4);
  unsigned* boffs = (unsigned*)carve((size_t)2 * 513 * 4);
  unsigned* bcur  = (unsigned*)carve((size_t)2 * 512 * 4);
  // total ~94 MiB

  zero_u32<<<(1024 + 255) / 256, 256, 0, stream>>>(bcnt, 1024);

  dim3 tb(32, 8);
  transpose_w3_pair<<<dim3(24, 2, 2), tb, 0, stream>>>(pw3, aw3, w3T);
  transpose_f32_b16<<<dim3(24, 72), tb, 0, stream>>>(fusw, fusT, 2304, 768);
  convert3<<<(1572864 + 255) / 256, 256, 0, stream>>>(pw4, 589824, aw4, 589824,
                                                      semw, 393216, wB);
  prep_pointnet2<<<2, 64, 0, stream>>>(pw1, pb1, pg1, aw1, ab1, ag1, pw2, aw2,
                                       G2, Mq2, w2T);

  gemm_fold<<<dim3(6, 6, 3), 256, 0, stream>>>(fusT, wB, BTcat);
  fuse_bias<<<768, 256, 0, stream>>>(fusb, fusw, pb4, ab4, semb, bias_tot);

  // bucket counting sort (32 nodes/bucket) + per-bucket MFMA reduce
  hist_bucket<<<dim3(64, 2), 256, 0, stream>>>(pos_idx, aff_idx, P, bcnt);
  scan_bucket<<<2, 512, 0, stream>>>(bcnt, boffs, bcur);
  bucket_scatter<<<dim3(256, 2), 256, 0, stream>>>(x_pos, x_aff, pos_idx, aff_idx,
                                                   P, bcur, sorted);
  bucket_mlp_max<<<dim3(512, 2), 256, 0, stream>>>(sorted, boffs, G2, Mq2, pbe1, abe1,
                                                   w2T, pb2, ab2, xgB, P);

  gemm_w3<<<dim3(6, NN / 128, 2), 256, 0, stream>>>(xgB, w3T, pb3, ab3, t);
  ln2<<<dim3(NN, 2), 256, 0, stream>>>(t, pg2, pbe2, ag2, abe2);

  gemm_fuse3<<<768, 256, 0, stream>>>(t, t + (size_t)NN * 768, x_sem,
                                      BTcat, bias_tot, F);
  ln_relu_768_f32<<<NN, 256, 0, stream>>>(F, fusg, fusbe, (float*)d_out);
}